// Round 2
// baseline (719.131 us; speedup 1.0000x reference)
//
#include <hip/hip_runtime.h>
#include <math.h>

typedef __attribute__((ext_vector_type(4))) float f32x4;
typedef __attribute__((ext_vector_type(8))) short short8;   // 8 bf16 raw bits
typedef __attribute__((ext_vector_type(4))) short short4v;  // 4 bf16 raw bits

__device__ __forceinline__ float b2f(unsigned short u) {
  unsigned int x = ((unsigned int)u) << 16;
  return __builtin_bit_cast(float, x);
}
__device__ __forceinline__ unsigned short f2b(float f) {
  unsigned int x = __builtin_bit_cast(unsigned int, f);
  x += 0x7fffu + ((x >> 16) & 1u);   // round-to-nearest-even
  return (unsigned short)(x >> 16);
}

// async global->LDS, 16B per lane. LDS dest must be lane-contiguous (wave base + lane*16).
__device__ __forceinline__ void gload16(const unsigned short* g, unsigned short* l) {
  __builtin_amdgcn_global_load_lds(
      (__attribute__((address_space(1))) void*)(unsigned long long)(const void*)g,
      (__attribute__((address_space(3))) void*)l, 16, 0, 0);
}

// ---------------------------------------------------------------------------
// f32 -> bf16 elementwise convert (x). 8 elems/thread.
// ---------------------------------------------------------------------------
__global__ __launch_bounds__(256) void cvt_kernel(const float* __restrict__ in,
                                                  unsigned short* __restrict__ out, long n8) {
  long i = (long)blockIdx.x * 256 + threadIdx.x;
  if (i >= n8) return;
  f32x4 a = ((const f32x4*)in)[i * 2];
  f32x4 b = ((const f32x4*)in)[i * 2 + 1];
  short8 o;
#pragma unroll
  for (int j = 0; j < 4; ++j) { o[j] = (short)f2b(a[j]); o[4 + j] = (short)f2b(b[j]); }
  ((short8*)out)[i] = o;
}

// ---------------------------------------------------------------------------
// Weight repack f32 -> bf16 B^T ([N][K], k-contiguous). QKV fused into one
// [3072][1024]; also builds concatenated f32 QKV bias.
// ---------------------------------------------------------------------------
__global__ __launch_bounds__(256) void repack_kernel(
    const float* __restrict__ Wq, const float* __restrict__ Wk,
    const float* __restrict__ Wv, const float* __restrict__ Wo,
    const float* __restrict__ W1, const float* __restrict__ W2,
    const float* __restrict__ bq, const float* __restrict__ bk, const float* __restrict__ bv,
    unsigned short* __restrict__ BqkvT, unsigned short* __restrict__ WoT,
    unsigned short* __restrict__ W1T, unsigned short* __restrict__ W2T,
    float* __restrict__ bqkv) {
  int nb = blockIdx.x, t = threadIdx.x;
  if (nb < 3072) {                       // Wq/Wk/Wv: (H,D,HD) -> row n = seg*1024 + h*64+e
    const float* src; int n;
    if (nb < 1024)      { src = Wq; n = nb; }
    else if (nb < 2048) { src = Wk; n = nb - 1024; }
    else                { src = Wv; n = nb - 2048; }
    int h = n >> 6, e = n & 63;
    for (int d = t; d < 1024; d += 256)
      BqkvT[(long)nb * 1024 + d] = f2b(src[(h * 1024 + d) * 64 + e]);
    if (t == 0) bqkv[nb] = (nb < 1024) ? bq[n] : (nb < 2048 ? bk[n] : bv[n]);
  } else if (nb < 4096) {                // Wo: (D,D) -> WoT[j][d] = Wo[d][j]
    int j = nb - 3072;
    for (int d = t; d < 1024; d += 256) WoT[j * 1024 + d] = f2b(Wo[d * 1024 + j]);
  } else if (nb < 4224) {                // W1: (D,128) -> W1T[f][d]
    int f = nb - 4096;
    for (int d = t; d < 1024; d += 256) W1T[f * 1024 + d] = f2b(W1[d * 128 + f]);
  } else {                               // W2: (128,D) -> W2T[j][f]
    int j = nb - 4224;
    if (t < 128) W2T[j * 128 + t] = f2b(W2[t * 1024 + j]);
  }
}

// ---------------------------------------------------------------------------
// m97-structure bf16 GEMM: C[M][N] = A[M][K] @ B, B given transposed Bt[N][K].
// 128x128 tile, BK=32, 4 waves (2x2), each wave 64x64 (4x4 frags of 16x16x32).
// EPI: 0 = +bias ; 1 = +bias + f32 resid ; 2 = tanh(+bias) ; 3 = +bias + bf16 resid
// ---------------------------------------------------------------------------
template <int EPI>
__global__ __launch_bounds__(256, 2) void gemm_bt(
    const unsigned short* __restrict__ A, int lda,
    const unsigned short* __restrict__ Bt, int ldb,
    unsigned short* __restrict__ C, int ldc,
    const float* __restrict__ bias,
    const float* __restrict__ residf,
    const unsigned short* __restrict__ residb, int ldr, int K) {
  __shared__ __align__(16) unsigned short Asm[128 * 32];
  __shared__ __align__(16) unsigned short Bsm[128 * 32];
  const int tid = threadIdx.x;
  const int lane = tid & 63, wid = tid >> 6;
  const int wr = wid >> 1, wc = wid & 1;
  const long m0 = (long)blockIdx.y * 128;
  const long n0 = (long)blockIdx.x * 128;

  f32x4 acc[4][4] = {};

  for (int kk = 0; kk < K; kk += 32) {
    __syncthreads();
#pragma unroll
    for (int i = 0; i < 2; ++i) {
      int slot = i * 256 + tid;
      int r = slot >> 2, cg = (slot & 3) * 8;
      gload16(A + (m0 + r) * (long)lda + kk + cg, &Asm[slot * 8]);
      gload16(Bt + (n0 + r) * (long)ldb + kk + cg, &Bsm[slot * 8]);
    }
    __syncthreads();   // compiler emits vmcnt(0) drain before the barrier
    short8 af[4], bfr[4];
#pragma unroll
    for (int mt = 0; mt < 4; ++mt)
      af[mt] = *(const short8*)&Asm[(wr * 64 + mt * 16 + (lane & 15)) * 32 + (lane >> 4) * 8];
#pragma unroll
    for (int nt = 0; nt < 4; ++nt)
      bfr[nt] = *(const short8*)&Bsm[(wc * 64 + nt * 16 + (lane & 15)) * 32 + (lane >> 4) * 8];
#pragma unroll
    for (int mt = 0; mt < 4; ++mt)
#pragma unroll
      for (int nt = 0; nt < 4; ++nt)
        acc[mt][nt] = __builtin_amdgcn_mfma_f32_16x16x32_bf16(af[mt], bfr[nt], acc[mt][nt], 0, 0, 0);
  }

  const long row0 = m0 + wr * 64 + ((lane >> 4) * 4);
  const long col0 = n0 + wc * 64 + (lane & 15);
#pragma unroll
  for (int mt = 0; mt < 4; ++mt) {
#pragma unroll
    for (int nt = 0; nt < 4; ++nt) {
      long col = col0 + nt * 16;
      float bv = bias[col];
      f32x4 v = acc[mt][nt];
#pragma unroll
      for (int r = 0; r < 4; ++r) {
        long row = row0 + mt * 16 + r;
        float o = v[r] + bv;
        if (EPI == 1) o += residf[row * (long)ldr + col];
        if (EPI == 2) o = tanhf(o);
        if (EPI == 3) o += b2f(residb[row * (long)ldr + col]);
        C[row * (long)ldc + col] = f2b(o);
      }
    }
  }
}

// ---------------------------------------------------------------------------
// scores[b,h,k,q] = sum_s K[b,h,s,k] * Q[b,h,s,q], split over 4 s-segments.
// Q at QKV col h*64, K at QKV col 1024+h*64, row stride 3072. f32 accumulate.
// ---------------------------------------------------------------------------
__global__ __launch_bounds__(256) void scores_partial(
    const unsigned short* __restrict__ QKV, float* __restrict__ part) {
  __shared__ __align__(16) float Qc[128][64];
  __shared__ __align__(16) float Kc[128][64];
  int bh = blockIdx.x, seg = blockIdx.y;
  int b = bh >> 4, h = bh & 15;
  int tid = threadIdx.x;
  int q4 = (tid & 15) * 4, k4 = (tid >> 4) * 4;
  float acc[4][4] = {};

  for (int ch = 0; ch < 8; ++ch) {
    long s0 = (long)b * 4096 + seg * 1024 + ch * 128;
    __syncthreads();
#pragma unroll
    for (int i = 0; i < 4; ++i) {
      int idx = i * 256 + tid;
      int r = idx >> 3, c8 = (idx & 7) * 8;
      short8 qv = *(const short8*)(QKV + (s0 + r) * 3072 + h * 64 + c8);
      short8 kv = *(const short8*)(QKV + (s0 + r) * 3072 + 1024 + h * 64 + c8);
#pragma unroll
      for (int j = 0; j < 8; ++j) {
        Qc[r][c8 + j] = b2f((unsigned short)qv[j]);
        Kc[r][c8 + j] = b2f((unsigned short)kv[j]);
      }
    }
    __syncthreads();
    for (int ss = 0; ss < 128; ++ss) {
      f32x4 qv = *(const f32x4*)&Qc[ss][q4];
      f32x4 kv = *(const f32x4*)&Kc[ss][k4];
#pragma unroll
      for (int i = 0; i < 4; ++i)
#pragma unroll
        for (int j = 0; j < 4; ++j) acc[i][j] += kv[i] * qv[j];
    }
  }
  float* dst = part + (long)(bh * 4 + seg) * 4096;
#pragma unroll
  for (int i = 0; i < 4; ++i)
#pragma unroll
    for (int j = 0; j < 4; ++j) dst[(k4 + i) * 64 + q4 + j] = acc[i][j];
}

// softmax over k (per q column), scores/8; writes w^T bf16: wT[bh][q][k]
__global__ __launch_bounds__(64) void softmax_wT(
    const float* __restrict__ part, const int* __restrict__ mask,
    unsigned short* __restrict__ wT) {
  int bh = blockIdx.x, q = threadIdx.x;
  int b = bh >> 4;
  const float* p0 = part + (long)bh * 4 * 4096;
  float s[64];
#pragma unroll
  for (int k = 0; k < 64; ++k)
    s[k] = p0[k * 64 + q] + p0[4096 + k * 64 + q] + p0[8192 + k * 64 + q] + p0[12288 + k * 64 + q];
  bool live = (mask[b * 64 + q] != 0);
  float m = -1e30f;
#pragma unroll
  for (int k = 0; k < 64; ++k) m = fmaxf(m, s[k]);
  float sum = 0.0f;
#pragma unroll
  for (int k = 0; k < 64; ++k) {
    s[k] = __expf((s[k] - m) * 0.125f);
    sum += s[k];
  }
  float inv = live ? 1.0f / sum : 0.0f;
  unsigned short* o = wT + (long)bh * 4096 + q * 64;
#pragma unroll
  for (int k = 0; k < 64; ++k) o[k] = f2b(s[k] * inv);
}

// attn[tok][h*64+q] = sum_k V[tok][k] * w[k][q]; V = QKV col 2048+h*64, stride 3072.
__global__ __launch_bounds__(256) void attn_pv(
    const unsigned short* __restrict__ QKV, const unsigned short* __restrict__ wT,
    unsigned short* __restrict__ attn) {
  int tc = blockIdx.x;   // 128 chunks of 256 tokens
  int h = blockIdx.y;    // 16 heads
  int tid = threadIdx.x, lane = tid & 63, wid = tid >> 6;
  long tok0 = (long)tc * 256 + wid * 64;
  int b = (tc * 256) >> 12;
  const unsigned short* wp = wT + (long)(b * 16 + h) * 4096;
  const unsigned short* V = QKV + 2048;
  f32x4 acc[4][4] = {};
#pragma unroll
  for (int ks = 0; ks < 2; ++ks) {
    short8 bfr[4];
#pragma unroll
    for (int nt = 0; nt < 4; ++nt)
      bfr[nt] = *(const short8*)&wp[(nt * 16 + (lane & 15)) * 64 + ks * 32 + (lane >> 4) * 8];
#pragma unroll
    for (int mt = 0; mt < 4; ++mt) {
      short8 af = *(const short8*)(V + (tok0 + mt * 16 + (lane & 15)) * 3072 + h * 64 + ks * 32 + (lane >> 4) * 8);
#pragma unroll
      for (int nt = 0; nt < 4; ++nt)
        acc[mt][nt] = __builtin_amdgcn_mfma_f32_16x16x32_bf16(af, bfr[nt], acc[mt][nt], 0, 0, 0);
    }
  }
#pragma unroll
  for (int mt = 0; mt < 4; ++mt)
#pragma unroll
    for (int nt = 0; nt < 4; ++nt)
#pragma unroll
      for (int r = 0; r < 4; ++r) {
        long row = tok0 + mt * 16 + (lane >> 4) * 4 + r;
        int col = h * 64 + nt * 16 + (lane & 15);
        attn[row * 1024 + col] = f2b(acc[mt][nt][r]);
      }
}

// rmsnorm over D=1024; one block per row. bf16 in; bf16 or f32 out.
template <int OUTF>
__global__ __launch_bounds__(256) void rmsnorm_k(
    const unsigned short* __restrict__ in, const float* __restrict__ g,
    unsigned short* __restrict__ outb, float* __restrict__ outf) {
  long row = blockIdx.x;
  int tid = threadIdx.x;
  short4v u = *(const short4v*)(in + row * 1024 + tid * 4);
  float v[4];
  float ss = 0.0f;
#pragma unroll
  for (int i = 0; i < 4; ++i) {
    v[i] = b2f((unsigned short)u[i]);
    ss += v[i] * v[i];
  }
#pragma unroll
  for (int off = 32; off > 0; off >>= 1) ss += __shfl_xor(ss, off, 64);
  __shared__ float wsum[4];
  if ((tid & 63) == 0) wsum[tid >> 6] = ss;
  __syncthreads();
  float tot = wsum[0] + wsum[1] + wsum[2] + wsum[3];
  float rs = rsqrtf(tot * (1.0f / 1024.0f) + 1e-6f);
  f32x4 gv = *(const f32x4*)(g + tid * 4);
  if (OUTF) {
    f32x4 ov;
#pragma unroll
    for (int i = 0; i < 4; ++i) ov[i] = v[i] * rs * gv[i];
    *(f32x4*)(outf + row * 1024 + tid * 4) = ov;
  } else {
    short4v ov;
#pragma unroll
    for (int i = 0; i < 4; ++i) ov[i] = (short)f2b(v[i] * rs * gv[i]);
    *(short4v*)(outb + row * 1024 + tid * 4) = ov;
  }
}

// ---------------------------------------------------------------------------
extern "C" void kernel_launch(void* const* d_in, const int* in_sizes, int n_in,
                              void* d_out, int out_size, void* d_ws, size_t ws_size,
                              hipStream_t stream) {
  const float* x  = (const float*)d_in[0];
  const int* mask = (const int*)d_in[1];
  const float* Wq = (const float*)d_in[2];
  const float* bq = (const float*)d_in[3];
  const float* Wk = (const float*)d_in[4];
  const float* bk = (const float*)d_in[5];
  const float* Wv = (const float*)d_in[6];
  const float* bv = (const float*)d_in[7];
  const float* Wo = (const float*)d_in[8];
  const float* bo = (const float*)d_in[9];
  const float* W1 = (const float*)d_in[10];
  const float* b1 = (const float*)d_in[11];
  const float* W2 = (const float*)d_in[12];
  const float* b2 = (const float*)d_in[13];
  const float* g1 = (const float*)d_in[14];
  const float* g2 = (const float*)d_in[15];

  char* ws = (char*)d_ws;
  size_t off = 0;
  auto alc = [&](size_t n) { size_t o = off; off += (n + 255) & ~(size_t)255; return o; };
  unsigned short* BqkvT = (unsigned short*)(ws + alc(3072UL * 1024 * 2));
  unsigned short* WoT   = (unsigned short*)(ws + alc(1024UL * 1024 * 2));
  unsigned short* W1T   = (unsigned short*)(ws + alc(128UL * 1024 * 2));
  unsigned short* W2T   = (unsigned short*)(ws + alc(1024UL * 128 * 2));
  float*          bqkv  = (float*)(ws + alc(3072UL * 4));
  // R0: xb -> attn -> hf (sequential lifetimes)
  unsigned short* R0    = (unsigned short*)(ws + alc(32768UL * 1024 * 2));
  // R1: QKV -> h1
  unsigned short* R1    = (unsigned short*)(ws + alc(32768UL * 3072 * 2));
  unsigned short* H2b   = (unsigned short*)(ws + alc(32768UL * 1024 * 2));
  unsigned short* Tb    = (unsigned short*)(ws + alc(32768UL * 128 * 2));
  float*          SP    = (float*)(ws + alc(512UL * 4096 * 4));
  unsigned short* WTb   = (unsigned short*)(ws + alc(128UL * 4096 * 2));
  if (ws_size < off) return;  // signals as absmax == max|ref| (zero output)

  unsigned short* xb   = R0;
  unsigned short* attn = R0;
  unsigned short* HFb  = R0;
  unsigned short* QKVb = R1;
  unsigned short* H1b  = R1;
  float* outp = (float*)d_out;

  // x -> bf16
  cvt_kernel<<<16384, 256, 0, stream>>>(x, xb, 4194304);
  // weights -> bf16 B^T (+ concat QKV bias)
  repack_kernel<<<5248, 256, 0, stream>>>(Wq, Wk, Wv, Wo, W1, W2, bq, bk, bv,
                                          BqkvT, WoT, W1T, W2T, bqkv);
  // QKV = xb @ [Wq|Wk|Wv]^T + b   (one fused GEMM, N=3072)
  gemm_bt<0><<<dim3(24, 256), 256, 0, stream>>>(xb, 1024, BqkvT, 1024, QKVb, 3072,
                                                bqkv, nullptr, nullptr, 0, 1024);
  scores_partial<<<dim3(128, 4), 256, 0, stream>>>(QKVb, SP);
  softmax_wT<<<128, 64, 0, stream>>>(SP, mask, WTb);
  attn_pv<<<dim3(128, 16), 256, 0, stream>>>(QKVb, WTb, attn);
  // h1 = x + attn@WoT + bo   (f32 residual read)
  gemm_bt<1><<<dim3(8, 256), 256, 0, stream>>>(attn, 1024, WoT, 1024, H1b, 1024,
                                               bo, x, nullptr, 1024, 1024);
  // h2 = rmsnorm(h1, g1)  (bf16 out)
  rmsnorm_k<0><<<32768, 256, 0, stream>>>(H1b, g1, H2b, nullptr);
  // t = tanh(h2@W1T + b1)
  gemm_bt<2><<<dim3(1, 256), 256, 0, stream>>>(H2b, 1024, W1T, 1024, Tb, 128,
                                               b1, nullptr, nullptr, 0, 1024);
  // hf = t@W2T + b2 + h2  (bf16 residual)
  gemm_bt<3><<<dim3(8, 256), 256, 0, stream>>>(Tb, 128, W2T, 128, HFb, 1024,
                                               b2, nullptr, H2b, 1024, 128);
  // out = rmsnorm(hf, g2)  (f32 out)
  rmsnorm_k<1><<<32768, 256, 0, stream>>>(HFb, g2, nullptr, outp);
}

// Round 3
// 676.064 us; speedup vs baseline: 1.0637x; 1.0637x over previous
//
#include <hip/hip_runtime.h>
#include <math.h>

typedef __attribute__((ext_vector_type(4))) float f32x4;
typedef __attribute__((ext_vector_type(8))) short short8;   // 8 bf16 raw bits
typedef __attribute__((ext_vector_type(4))) short short4v;  // 4 bf16 raw bits
typedef unsigned short ushort_t;

__device__ __forceinline__ float b2f(unsigned short u) {
  unsigned int x = ((unsigned int)u) << 16;
  return __builtin_bit_cast(float, x);
}
__device__ __forceinline__ unsigned short f2b(float f) {
  unsigned int x = __builtin_bit_cast(unsigned int, f);
  x += 0x7fffu + ((x >> 16) & 1u);   // round-to-nearest-even
  return (unsigned short)(x >> 16);
}

// async global->LDS, 16B per lane. LDS dest must be lane-contiguous (wave base + lane*16).
__device__ __forceinline__ void gload16(const unsigned short* g, unsigned short* l) {
  __builtin_amdgcn_global_load_lds(
      (__attribute__((address_space(1))) void*)(unsigned long long)(const void*)g,
      (__attribute__((address_space(3))) void*)l, 16, 0, 0);
}

#define BARR  { __builtin_amdgcn_sched_barrier(0); __builtin_amdgcn_s_barrier(); __builtin_amdgcn_sched_barrier(0); }
#define VMW(n) { __builtin_amdgcn_sched_barrier(0); asm volatile("s_waitcnt vmcnt(" #n ")" ::: "memory"); __builtin_amdgcn_sched_barrier(0); }

// ---------------------------------------------------------------------------
// f32 -> bf16 elementwise convert (x). 8 elems/thread.
// ---------------------------------------------------------------------------
__global__ __launch_bounds__(256) void cvt_kernel(const float* __restrict__ in,
                                                  unsigned short* __restrict__ out, long n8) {
  long i = (long)blockIdx.x * 256 + threadIdx.x;
  if (i >= n8) return;
  f32x4 a = ((const f32x4*)in)[i * 2];
  f32x4 b = ((const f32x4*)in)[i * 2 + 1];
  short8 o;
#pragma unroll
  for (int j = 0; j < 4; ++j) { o[j] = (short)f2b(a[j]); o[4 + j] = (short)f2b(b[j]); }
  ((short8*)out)[i] = o;
}

// ---------------------------------------------------------------------------
// Weight repack f32 -> bf16 B^T ([N][K], k-contiguous). QKV fused into one
// [3072][1024]; also builds concatenated f32 QKV bias.
// ---------------------------------------------------------------------------
__global__ __launch_bounds__(256) void repack_kernel(
    const float* __restrict__ Wq, const float* __restrict__ Wk,
    const float* __restrict__ Wv, const float* __restrict__ Wo,
    const float* __restrict__ W1, const float* __restrict__ W2,
    const float* __restrict__ bq, const float* __restrict__ bk, const float* __restrict__ bv,
    unsigned short* __restrict__ BqkvT, unsigned short* __restrict__ WoT,
    unsigned short* __restrict__ W1T, unsigned short* __restrict__ W2T,
    float* __restrict__ bqkv) {
  int nb = blockIdx.x, t = threadIdx.x;
  if (nb < 3072) {                       // Wq/Wk/Wv: (H,D,HD) -> row n = seg*1024 + h*64+e
    const float* src; int n;
    if (nb < 1024)      { src = Wq; n = nb; }
    else if (nb < 2048) { src = Wk; n = nb - 1024; }
    else                { src = Wv; n = nb - 2048; }
    int h = n >> 6, e = n & 63;
    for (int d = t; d < 1024; d += 256)
      BqkvT[(long)nb * 1024 + d] = f2b(src[(h * 1024 + d) * 64 + e]);
    if (t == 0) bqkv[nb] = (nb < 1024) ? bq[n] : (nb < 2048 ? bk[n] : bv[n]);
  } else if (nb < 4096) {                // Wo: (D,D) -> WoT[j][d] = Wo[d][j]
    int j = nb - 3072;
    for (int d = t; d < 1024; d += 256) WoT[j * 1024 + d] = f2b(Wo[d * 1024 + j]);
  } else if (nb < 4224) {                // W1: (D,128) -> W1T[f][d]
    int f = nb - 4096;
    for (int d = t; d < 1024; d += 256) W1T[f * 1024 + d] = f2b(W1[d * 128 + f]);
  } else {                               // W2: (128,D) -> W2T[j][f]
    int j = nb - 4224;
    if (t < 128) W2T[j * 128 + t] = f2b(W2[t * 1024 + j]);
  }
}

// ---------------------------------------------------------------------------
// 256x256 8-phase bf16 GEMM (T2 st_16x32 swizzle + T3/T4 counted vmcnt + T5).
// BK=64, 8 waves (2M x 4N), 512 threads, LDS 128 KiB (2 dbuf x (A 32K + B 32K)).
// A LDS: buf*32768 + ph*16384 + wm*8192 + r*128 + cb   (ph = M-quarter, r in [0,64))
// B LDS: 65536 + buf*32768 + ph*16384 + wn*4096 + r*128 + cb  (r in [0,32))
// Swizzle: byte col ^= 32 when (row & 4)  — applied on BOTH stage-src and ds_read.
// EPI: 0 = +bias ; 1 = +bias + f32 resid.  Requires M%256==0, N%256==0, K%128==0.
// ---------------------------------------------------------------------------
__device__ __forceinline__ void rdA_f(char* smb, int buf, int ph, int wm, int lane,
                                      short8 (&afr)[4][2]) {
  const int lr = lane & 15, lc = (lane >> 4) * 16;
#pragma unroll
  for (int fr = 0; fr < 4; ++fr) {
    int row = fr * 16 + lr;
    char* base = smb + buf * 32768 + ph * 16384 + wm * 8192 + row * 128;
    int sw = (row & 4) << 3;
#pragma unroll
    for (int ks = 0; ks < 2; ++ks)
      afr[fr][ks] = *(const short8*)(base + ((ks * 64 + lc) ^ sw));
  }
}
__device__ __forceinline__ void rdB_f(char* smb, int buf, int ph, int wn, int lane,
                                      short8 (&bf)[2][2]) {
  const int lr = lane & 15, lc = (lane >> 4) * 16;
#pragma unroll
  for (int gr = 0; gr < 2; ++gr) {
    int row = gr * 16 + lr;
    char* base = smb + 65536 + buf * 32768 + ph * 16384 + wn * 4096 + row * 128;
    int sw = (row & 4) << 3;
#pragma unroll
    for (int ks = 0; ks < 2; ++ks)
      bf[gr][ks] = *(const short8*)(base + ((ks * 64 + lc) ^ sw));
  }
}
template <int BPH>
__device__ __forceinline__ void mfmaq_f(const short8 (&afr)[4][2], const short8 (&bf)[2][2],
                                        f32x4 (*ac)[4]) {
  __builtin_amdgcn_s_setprio(1);
#pragma unroll
  for (int fi = 0; fi < 4; ++fi)
#pragma unroll
    for (int gj = 0; gj < 2; ++gj)
#pragma unroll
      for (int ks = 0; ks < 2; ++ks)
        ac[fi][BPH * 2 + gj] = __builtin_amdgcn_mfma_f32_16x16x32_bf16(
            afr[fi][ks], bf[gj][ks], ac[fi][BPH * 2 + gj], 0, 0, 0);
  __builtin_amdgcn_s_setprio(0);
}

template <int EPI>
__global__ __launch_bounds__(512, 2) void gemm8p(
    const unsigned short* __restrict__ A, int lda,
    const unsigned short* __restrict__ Bt, int ldb,
    unsigned short* __restrict__ C, int ldc,
    const float* __restrict__ bias,
    const float* __restrict__ residf, int ldr,
    int K, int NBX) {
  extern __shared__ char smb[];
  const int tid = threadIdx.x;
  const int lane = tid & 63, wid = tid >> 6;
  const int wm = wid >> 2, wn = wid & 3;

  // XCD-aware swizzle (gridDim.x % 8 == 0 for all our launches)
  int nwg = gridDim.x, orig = blockIdx.x;
  int wg = ((orig & 7) * (nwg >> 3)) + (orig >> 3);
  const long m0 = (long)(wg / NBX) * 256;
  const long n0 = (long)(wg % NBX) * 256;

  const int NT = K >> 6, NI = NT >> 1;

  short8 afr[4][2];
  short8 bfr[2][2][2];
  f32x4 acc[8][4] = {};

  auto stA = [&](int buf, int ph, int kt) {
#pragma unroll
    for (int rnd = 0; rnd < 2; ++rnd) {
      int o = rnd * 8192 + tid * 16;
      int wms = o >> 13, rs = (o >> 7) & 63, cb = o & 127;
      int pcb = cb ^ ((rs & 4) << 3);                // inverse-swizzled source
      const unsigned short* src = A + (m0 + wms * 128 + ph * 64 + rs) * (long)lda + kt * 64 + (pcb >> 1);
      gload16(src, (unsigned short*)(smb + buf * 32768 + ph * 16384 + o));
    }
  };
  auto stB = [&](int buf, int ph, int kt) {
#pragma unroll
    for (int rnd = 0; rnd < 2; ++rnd) {
      int o = rnd * 8192 + tid * 16;
      int wns = (o >> 12) & 3, rs = (o >> 7) & 31, cb = o & 127;
      int pcb = cb ^ ((rs & 4) << 3);
      const unsigned short* src = Bt + (n0 + wns * 64 + ph * 32 + rs) * (long)ldb + kt * 64 + (pcb >> 1);
      gload16(src, (unsigned short*)(smb + 65536 + buf * 32768 + ph * 16384 + o));
    }
  };

  // Prologue: buf0 fully (kt 0); buf1 {A-ph0, B-ph0, B-ph1} (kt 1); A-ph1(kt1) deferred to P1.
  stA(0, 0, 0); stA(0, 1, 0); stB(0, 0, 0); stB(0, 1, 0);
  stA(1, 0, 1); stB(1, 0, 1); stB(1, 1, 1);
  VMW(6);   // 14 issued; all but newest 6 landed => buf0 complete
  BARR;

  for (int i = 0; i < NI; ++i) {
    int t2 = 2 * i + 2, t3 = 2 * i + 3;
    bool s2 = t2 < NT, s3 = t3 < NT;
    // ---- K-tile 2i (buf0) ----
    // P1: read A-ph0,B-ph0; stage buf1.A-ph1 <- kt 2i+1 (freed prev P7 / prologue gap)
    rdA_f(smb, 0, 0, wm, lane, afr);
    rdB_f(smb, 0, 0, wn, lane, bfr[0]);
    stA(1, 1, 2 * i + 1);
    BARR; mfmaq_f<0>(afr, bfr[0], &acc[0]); BARR;
    // P2: read B-ph1; stage buf0.A-ph0 <- t2 (freed P1)
    rdB_f(smb, 0, 1, wn, lane, bfr[1]);
    if (s2) stA(0, 0, t2);
    BARR; mfmaq_f<1>(afr, bfr[1], &acc[0]); BARR;
    // P3: read A-ph1; stage buf0.B-ph0 <- t2 (freed P1)
    rdA_f(smb, 0, 1, wm, lane, afr);
    if (s2) stB(0, 0, t2);
    BARR; mfmaq_f<0>(afr, bfr[0], &acc[4]); BARR;
    // P4: stage buf0.B-ph1 <- t2 (freed P2); counted vmcnt -> buf1 ready
    if (s2) stB(0, 1, t2);
    BARR; mfmaq_f<1>(afr, bfr[1], &acc[4]);
    if (s2) { VMW(6); } else { VMW(0); }
    BARR;
    // ---- K-tile 2i+1 (buf1) ----
    // P5: stage buf0.A-ph1 <- t2 (freed P3)
    rdA_f(smb, 1, 0, wm, lane, afr);
    rdB_f(smb, 1, 0, wn, lane, bfr[0]);
    if (s2) stA(0, 1, t2);
    BARR; mfmaq_f<0>(afr, bfr[0], &acc[0]); BARR;
    // P6: stage buf1.A-ph0 <- t3 (freed P5)
    rdB_f(smb, 1, 1, wn, lane, bfr[1]);
    if (s3) stA(1, 0, t3);
    BARR; mfmaq_f<1>(afr, bfr[1], &acc[0]); BARR;
    // P7: stage buf1.B-ph0 <- t3 (freed P5)
    rdA_f(smb, 1, 1, wm, lane, afr);
    if (s3) stB(1, 0, t3);
    BARR; mfmaq_f<0>(afr, bfr[0], &acc[4]); BARR;
    // P8: stage buf1.B-ph1 <- t3 (freed P6); counted vmcnt -> buf0 ready
    if (s3) stB(1, 1, t3);
    BARR; mfmaq_f<1>(afr, bfr[1], &acc[4]);
    if (s3) { VMW(6); } else { VMW(0); }
    BARR;
  }

  // Epilogue: C-write with bias (+ optional f32 residual)
#pragma unroll
  for (int f = 0; f < 8; ++f) {
#pragma unroll
    for (int g = 0; g < 4; ++g) {
      long col = n0 + wn * 64 + g * 16 + (lane & 15);
      float bv = bias[col];
#pragma unroll
      for (int r = 0; r < 4; ++r) {
        long row = m0 + wm * 128 + f * 16 + (lane >> 4) * 4 + r;
        float o = acc[f][g][r] + bv;
        if (EPI == 1) o += residf[row * (long)ldr + col];
        C[row * (long)ldc + col] = f2b(o);
      }
    }
  }
}

// ---------------------------------------------------------------------------
// m97-structure bf16 GEMM kept for the small/odd shapes (FF1 N=128, FF2 K=128).
// EPI: 2 = tanh(+bias) ; 3 = +bias + bf16 resid
// ---------------------------------------------------------------------------
template <int EPI>
__global__ __launch_bounds__(256, 2) void gemm_bt(
    const unsigned short* __restrict__ A, int lda,
    const unsigned short* __restrict__ Bt, int ldb,
    unsigned short* __restrict__ C, int ldc,
    const float* __restrict__ bias,
    const float* __restrict__ residf,
    const unsigned short* __restrict__ residb, int ldr, int K) {
  __shared__ __align__(16) unsigned short Asm[128 * 32];
  __shared__ __align__(16) unsigned short Bsm[128 * 32];
  const int tid = threadIdx.x;
  const int lane = tid & 63, wid = tid >> 6;
  const int wr = wid >> 1, wc = wid & 1;
  const long m0 = (long)blockIdx.y * 128;
  const long n0 = (long)blockIdx.x * 128;

  f32x4 acc[4][4] = {};

  for (int kk = 0; kk < K; kk += 32) {
    __syncthreads();
#pragma unroll
    for (int i = 0; i < 2; ++i) {
      int slot = i * 256 + tid;
      int r = slot >> 2, cg = (slot & 3) * 8;
      gload16(A + (m0 + r) * (long)lda + kk + cg, &Asm[slot * 8]);
      gload16(Bt + (n0 + r) * (long)ldb + kk + cg, &Bsm[slot * 8]);
    }
    __syncthreads();
    short8 af[4], bfr[4];
#pragma unroll
    for (int mt = 0; mt < 4; ++mt)
      af[mt] = *(const short8*)&Asm[(wr * 64 + mt * 16 + (lane & 15)) * 32 + (lane >> 4) * 8];
#pragma unroll
    for (int nt = 0; nt < 4; ++nt)
      bfr[nt] = *(const short8*)&Bsm[(wc * 64 + nt * 16 + (lane & 15)) * 32 + (lane >> 4) * 8];
#pragma unroll
    for (int mt = 0; mt < 4; ++mt)
#pragma unroll
      for (int nt = 0; nt < 4; ++nt)
        acc[mt][nt] = __builtin_amdgcn_mfma_f32_16x16x32_bf16(af[mt], bfr[nt], acc[mt][nt], 0, 0, 0);
  }

  const long row0 = m0 + wr * 64 + ((lane >> 4) * 4);
  const long col0 = n0 + wc * 64 + (lane & 15);
#pragma unroll
  for (int mt = 0; mt < 4; ++mt) {
#pragma unroll
    for (int nt = 0; nt < 4; ++nt) {
      long col = col0 + nt * 16;
      float bv = bias[col];
      f32x4 v = acc[mt][nt];
#pragma unroll
      for (int r = 0; r < 4; ++r) {
        long row = row0 + mt * 16 + r;
        float o = v[r] + bv;
        if (EPI == 1) o += residf[row * (long)ldr + col];
        if (EPI == 2) o = tanhf(o);
        if (EPI == 3) o += b2f(residb[row * (long)ldr + col]);
        C[row * (long)ldc + col] = f2b(o);
      }
    }
  }
}

// ---------------------------------------------------------------------------
// scores[b,h,k,q] = sum_s K[b,h,s,k] * Q[b,h,s,q], split over 4 s-segments.
// Q at QKV col h*64, K at QKV col 1024+h*64, row stride 3072. f32 accumulate.
// ---------------------------------------------------------------------------
__global__ __launch_bounds__(256) void scores_partial(
    const unsigned short* __restrict__ QKV, float* __restrict__ part) {
  __shared__ __align__(16) float Qc[128][64];
  __shared__ __align__(16) float Kc[128][64];
  int bh = blockIdx.x, seg = blockIdx.y;
  int b = bh >> 4, h = bh & 15;
  int tid = threadIdx.x;
  int q4 = (tid & 15) * 4, k4 = (tid >> 4) * 4;
  float acc[4][4] = {};

  for (int ch = 0; ch < 8; ++ch) {
    long s0 = (long)b * 4096 + seg * 1024 + ch * 128;
    __syncthreads();
#pragma unroll
    for (int i = 0; i < 4; ++i) {
      int idx = i * 256 + tid;
      int r = idx >> 3, c8 = (idx & 7) * 8;
      short8 qv = *(const short8*)(QKV + (s0 + r) * 3072 + h * 64 + c8);
      short8 kv = *(const short8*)(QKV + (s0 + r) * 3072 + 1024 + h * 64 + c8);
#pragma unroll
      for (int j = 0; j < 8; ++j) {
        Qc[r][c8 + j] = b2f((unsigned short)qv[j]);
        Kc[r][c8 + j] = b2f((unsigned short)kv[j]);
      }
    }
    __syncthreads();
    for (int ss = 0; ss < 128; ++ss) {
      f32x4 qv = *(const f32x4*)&Qc[ss][q4];
      f32x4 kv = *(const f32x4*)&Kc[ss][k4];
#pragma unroll
      for (int i = 0; i < 4; ++i)
#pragma unroll
        for (int j = 0; j < 4; ++j) acc[i][j] += kv[i] * qv[j];
    }
  }
  float* dst = part + (long)(bh * 4 + seg) * 4096;
#pragma unroll
  for (int i = 0; i < 4; ++i)
#pragma unroll
    for (int j = 0; j < 4; ++j) dst[(k4 + i) * 64 + q4 + j] = acc[i][j];
}

// softmax over k (per q column), scores/8; writes w^T bf16: wT[bh][q][k]
__global__ __launch_bounds__(64) void softmax_wT(
    const float* __restrict__ part, const int* __restrict__ mask,
    unsigned short* __restrict__ wT) {
  int bh = blockIdx.x, q = threadIdx.x;
  int b = bh >> 4;
  const float* p0 = part + (long)bh * 4 * 4096;
  float s[64];
#pragma unroll
  for (int k = 0; k < 64; ++k)
    s[k] = p0[k * 64 + q] + p0[4096 + k * 64 + q] + p0[8192 + k * 64 + q] + p0[12288 + k * 64 + q];
  bool live = (mask[b * 64 + q] != 0);
  float m = -1e30f;
#pragma unroll
  for (int k = 0; k < 64; ++k) m = fmaxf(m, s[k]);
  float sum = 0.0f;
#pragma unroll
  for (int k = 0; k < 64; ++k) {
    s[k] = __expf((s[k] - m) * 0.125f);
    sum += s[k];
  }
  float inv = live ? 1.0f / sum : 0.0f;
  unsigned short* o = wT + (long)bh * 4096 + q * 64;
#pragma unroll
  for (int k = 0; k < 64; ++k) o[k] = f2b(s[k] * inv);
}

// attn[tok][h*64+q] = sum_k V[tok][k] * w[k][q]; V = QKV col 2048+h*64, stride 3072.
__global__ __launch_bounds__(256) void attn_pv(
    const unsigned short* __restrict__ QKV, const unsigned short* __restrict__ wT,
    unsigned short* __restrict__ attn) {
  int tc = blockIdx.x;   // 128 chunks of 256 tokens
  int h = blockIdx.y;    // 16 heads
  int tid = threadIdx.x, lane = tid & 63, wid = tid >> 6;
  long tok0 = (long)tc * 256 + wid * 64;
  int b = (tc * 256) >> 12;
  const unsigned short* wp = wT + (long)(b * 16 + h) * 4096;
  const unsigned short* V = QKV + 2048;
  f32x4 acc[4][4] = {};
#pragma unroll
  for (int ks = 0; ks < 2; ++ks) {
    short8 bfr[4];
#pragma unroll
    for (int nt = 0; nt < 4; ++nt)
      bfr[nt] = *(const short8*)&wp[(nt * 16 + (lane & 15)) * 64 + ks * 32 + (lane >> 4) * 8];
#pragma unroll
    for (int mt = 0; mt < 4; ++mt) {
      short8 af = *(const short8*)(V + (tok0 + mt * 16 + (lane & 15)) * 3072 + h * 64 + ks * 32 + (lane >> 4) * 8);
#pragma unroll
      for (int nt = 0; nt < 4; ++nt)
        acc[mt][nt] = __builtin_amdgcn_mfma_f32_16x16x32_bf16(af, bfr[nt], acc[mt][nt], 0, 0, 0);
    }
  }
#pragma unroll
  for (int mt = 0; mt < 4; ++mt)
#pragma unroll
    for (int nt = 0; nt < 4; ++nt)
#pragma unroll
      for (int r = 0; r < 4; ++r) {
        long row = tok0 + mt * 16 + (lane >> 4) * 4 + r;
        int col = h * 64 + nt * 16 + (lane & 15);
        attn[row * 1024 + col] = f2b(acc[mt][nt][r]);
      }
}

// rmsnorm over D=1024; one block per row. bf16 in; bf16 or f32 out.
template <int OUTF>
__global__ __launch_bounds__(256) void rmsnorm_k(
    const unsigned short* __restrict__ in, const float* __restrict__ g,
    unsigned short* __restrict__ outb, float* __restrict__ outf) {
  long row = blockIdx.x;
  int tid = threadIdx.x;
  short4v u = *(const short4v*)(in + row * 1024 + tid * 4);
  float v[4];
  float ss = 0.0f;
#pragma unroll
  for (int i = 0; i < 4; ++i) {
    v[i] = b2f((unsigned short)u[i]);
    ss += v[i] * v[i];
  }
#pragma unroll
  for (int off = 32; off > 0; off >>= 1) ss += __shfl_xor(ss, off, 64);
  __shared__ float wsum[4];
  if ((tid & 63) == 0) wsum[tid >> 6] = ss;
  __syncthreads();
  float tot = wsum[0] + wsum[1] + wsum[2] + wsum[3];
  float rs = rsqrtf(tot * (1.0f / 1024.0f) + 1e-6f);
  f32x4 gv = *(const f32x4*)(g + tid * 4);
  if (OUTF) {
    f32x4 ov;
#pragma unroll
    for (int i = 0; i < 4; ++i) ov[i] = v[i] * rs * gv[i];
    *(f32x4*)(outf + row * 1024 + tid * 4) = ov;
  } else {
    short4v ov;
#pragma unroll
    for (int i = 0; i < 4; ++i) ov[i] = (short)f2b(v[i] * rs * gv[i]);
    *(short4v*)(outb + row * 1024 + tid * 4) = ov;
  }
}

// ---------------------------------------------------------------------------
extern "C" void kernel_launch(void* const* d_in, const int* in_sizes, int n_in,
                              void* d_out, int out_size, void* d_ws, size_t ws_size,
                              hipStream_t stream) {
  const float* x  = (const float*)d_in[0];
  const int* mask = (const int*)d_in[1];
  const float* Wq = (const float*)d_in[2];
  const float* bq = (const float*)d_in[3];
  const float* Wk = (const float*)d_in[4];
  const float* bk = (const float*)d_in[5];
  const float* Wv = (const float*)d_in[6];
  const float* bv = (const float*)d_in[7];
  const float* Wo = (const float*)d_in[8];
  const float* bo = (const float*)d_in[9];
  const float* W1 = (const float*)d_in[10];
  const float* b1 = (const float*)d_in[11];
  const float* W2 = (const float*)d_in[12];
  const float* b2 = (const float*)d_in[13];
  const float* g1 = (const float*)d_in[14];
  const float* g2 = (const float*)d_in[15];

  char* ws = (char*)d_ws;
  size_t off = 0;
  auto alc = [&](size_t n) { size_t o = off; off += (n + 255) & ~(size_t)255; return o; };
  unsigned short* BqkvT = (unsigned short*)(ws + alc(3072UL * 1024 * 2));
  unsigned short* WoT   = (unsigned short*)(ws + alc(1024UL * 1024 * 2));
  unsigned short* W1T   = (unsigned short*)(ws + alc(128UL * 1024 * 2));
  unsigned short* W2T   = (unsigned short*)(ws + alc(1024UL * 128 * 2));
  float*          bqkv  = (float*)(ws + alc(3072UL * 4));
  unsigned short* R0    = (unsigned short*)(ws + alc(32768UL * 1024 * 2));  // xb -> attn -> hf
  unsigned short* R1    = (unsigned short*)(ws + alc(32768UL * 3072 * 2));  // QKV -> h1
  unsigned short* H2b   = (unsigned short*)(ws + alc(32768UL * 1024 * 2));
  unsigned short* Tb    = (unsigned short*)(ws + alc(32768UL * 128 * 2));
  float*          SP    = (float*)(ws + alc(512UL * 4096 * 4));
  unsigned short* WTb   = (unsigned short*)(ws + alc(128UL * 4096 * 2));
  if (ws_size < off) return;

  unsigned short* xb   = R0;
  unsigned short* attn = R0;
  unsigned short* HFb  = R0;
  unsigned short* QKVb = R1;
  unsigned short* H1b  = R1;
  float* outp = (float*)d_out;

  cvt_kernel<<<16384, 256, 0, stream>>>(x, xb, 4194304);
  repack_kernel<<<5248, 256, 0, stream>>>(Wq, Wk, Wv, Wo, W1, W2, bq, bk, bv,
                                          BqkvT, WoT, W1T, W2T, bqkv);
  // QKV = xb @ [Wq|Wk|Wv]^T + b   (8-phase 256^2; grid 128x12 = 1536)
  gemm8p<0><<<1536, 512, 131072, stream>>>(xb, 1024, BqkvT, 1024, QKVb, 3072,
                                           bqkv, nullptr, 0, 1024, 12);
  scores_partial<<<dim3(128, 4), 256, 0, stream>>>(QKVb, SP);
  softmax_wT<<<128, 64, 0, stream>>>(SP, mask, WTb);
  attn_pv<<<dim3(128, 16), 256, 0, stream>>>(QKVb, WTb, attn);
  // h1 = x + attn@WoT + bo   (8-phase; grid 128x4 = 512)
  gemm8p<1><<<512, 512, 131072, stream>>>(attn, 1024, WoT, 1024, H1b, 1024,
                                          bo, x, 1024, 1024, 4);
  rmsnorm_k<0><<<32768, 256, 0, stream>>>(H1b, g1, H2b, nullptr);
  // t = tanh(h2@W1T + b1)
  gemm_bt<2><<<dim3(1, 256), 256, 0, stream>>>(H2b, 1024, W1T, 1024, Tb, 128,
                                               b1, nullptr, nullptr, 0, 1024);
  // hf = t@W2T + b2 + h2  (bf16 residual)
  gemm_bt<3><<<dim3(8, 256), 256, 0, stream>>>(Tb, 128, W2T, 128, HFb, 1024,
                                               b2, nullptr, H2b, 1024, 128);
  rmsnorm_k<1><<<32768, 256, 0, stream>>>(HFb, g2, nullptr, outp);
}

// Round 4
// 663.012 us; speedup vs baseline: 1.0846x; 1.0197x over previous
//
#include <hip/hip_runtime.h>
#include <math.h>

typedef __attribute__((ext_vector_type(4))) float f32x4;
typedef __attribute__((ext_vector_type(8))) short short8;   // 8 bf16 raw bits
typedef __attribute__((ext_vector_type(4))) short short4v;  // 4 bf16 raw bits

__device__ __forceinline__ float b2f(unsigned short u) {
  unsigned int x = ((unsigned int)u) << 16;
  return __builtin_bit_cast(float, x);
}
__device__ __forceinline__ unsigned short f2b(float f) {
  unsigned int x = __builtin_bit_cast(unsigned int, f);
  x += 0x7fffu + ((x >> 16) & 1u);   // round-to-nearest-even
  return (unsigned short)(x >> 16);
}

// async global->LDS, 16B per lane. LDS dest must be lane-contiguous (wave base + lane*16).
__device__ __forceinline__ void gload16(const unsigned short* g, unsigned short* l) {
  __builtin_amdgcn_global_load_lds(
      (__attribute__((address_space(1))) void*)(unsigned long long)(const void*)g,
      (__attribute__((address_space(3))) void*)l, 16, 0, 0);
}

#define BARR  { __builtin_amdgcn_sched_barrier(0); __builtin_amdgcn_s_barrier(); __builtin_amdgcn_sched_barrier(0); }
#define VMW(n) { __builtin_amdgcn_sched_barrier(0); asm volatile("s_waitcnt vmcnt(" #n ")" ::: "memory"); __builtin_amdgcn_sched_barrier(0); }

// ---------------------------------------------------------------------------
// f32 -> bf16 elementwise convert (x). 8 elems/thread.
// ---------------------------------------------------------------------------
__global__ __launch_bounds__(256) void cvt_kernel(const float* __restrict__ in,
                                                  unsigned short* __restrict__ out, long n8) {
  long i = (long)blockIdx.x * 256 + threadIdx.x;
  if (i >= n8) return;
  f32x4 a = ((const f32x4*)in)[i * 2];
  f32x4 b = ((const f32x4*)in)[i * 2 + 1];
  short8 o;
#pragma unroll
  for (int j = 0; j < 4; ++j) { o[j] = (short)f2b(a[j]); o[4 + j] = (short)f2b(b[j]); }
  ((short8*)out)[i] = o;
}

// ---------------------------------------------------------------------------
// Weight repack f32 -> bf16 B^T ([N][K], k-contiguous). QKV fused into one
// [3072][1024]; also builds concatenated f32 QKV bias.
// ---------------------------------------------------------------------------
__global__ __launch_bounds__(256) void repack_kernel(
    const float* __restrict__ Wq, const float* __restrict__ Wk,
    const float* __restrict__ Wv, const float* __restrict__ Wo,
    const float* __restrict__ W1, const float* __restrict__ W2,
    const float* __restrict__ bq, const float* __restrict__ bk, const float* __restrict__ bv,
    unsigned short* __restrict__ BqkvT, unsigned short* __restrict__ WoT,
    unsigned short* __restrict__ W1T, unsigned short* __restrict__ W2T,
    float* __restrict__ bqkv) {
  int nb = blockIdx.x, t = threadIdx.x;
  if (nb < 3072) {                       // Wq/Wk/Wv: (H,D,HD) -> row n = seg*1024 + h*64+e
    const float* src; int n;
    if (nb < 1024)      { src = Wq; n = nb; }
    else if (nb < 2048) { src = Wk; n = nb - 1024; }
    else                { src = Wv; n = nb - 2048; }
    int h = n >> 6, e = n & 63;
    for (int d = t; d < 1024; d += 256)
      BqkvT[(long)nb * 1024 + d] = f2b(src[(h * 1024 + d) * 64 + e]);
    if (t == 0) bqkv[nb] = (nb < 1024) ? bq[n] : (nb < 2048 ? bk[n] : bv[n]);
  } else if (nb < 4096) {                // Wo: (D,D) -> WoT[j][d] = Wo[d][j]
    int j = nb - 3072;
    for (int d = t; d < 1024; d += 256) WoT[j * 1024 + d] = f2b(Wo[d * 1024 + j]);
  } else if (nb < 4224) {                // W1: (D,128) -> W1T[f][d]
    int f = nb - 4096;
    for (int d = t; d < 1024; d += 256) W1T[f * 1024 + d] = f2b(W1[d * 128 + f]);
  } else {                               // W2: (128,D) -> W2T[j][f]
    int j = nb - 4224;
    if (t < 128) W2T[j * 128 + t] = f2b(W2[t * 1024 + j]);
  }
}

// ---------------------------------------------------------------------------
// 256x256 8-phase bf16 GEMM (T3/T4 counted vmcnt + T5 setprio).
// Swizzle: byte col ^= (row&7)<<4  (8-slot rotation; G4 pattern) on BOTH the
// global_load_lds source (inverse) and the ds_read address.
// BK=64, 8 waves (2M x 4N), 512 threads, LDS 128 KiB (2 dbuf x (A 32K + B 32K)).
// A LDS: buf*32768 + ph*16384 + wm*8192 + r*128 + cb   (ph = M-quarter, r in [0,64))
// B LDS: 65536 + buf*32768 + ph*16384 + wn*4096 + r*128 + cb  (r in [0,32))
// EPI: 0 = +bias ; 1 = +bias + f32 resid.  Requires M%256==0, N%256==0, K%128==0.
// ---------------------------------------------------------------------------
__device__ __forceinline__ void rdA_f(char* smb, int buf, int ph, int wm, int lane,
                                      short8 (&afr)[4][2]) {
  const int lr = lane & 15, lc = (lane >> 4) * 16;
#pragma unroll
  for (int fr = 0; fr < 4; ++fr) {
    int row = fr * 16 + lr;
    char* base = smb + buf * 32768 + ph * 16384 + wm * 8192 + row * 128;
    int sw = (row & 7) << 4;
#pragma unroll
    for (int ks = 0; ks < 2; ++ks)
      afr[fr][ks] = *(const short8*)(base + ((ks * 64 + lc) ^ sw));
  }
}
__device__ __forceinline__ void rdB_f(char* smb, int buf, int ph, int wn, int lane,
                                      short8 (&bf)[2][2]) {
  const int lr = lane & 15, lc = (lane >> 4) * 16;
#pragma unroll
  for (int gr = 0; gr < 2; ++gr) {
    int row = gr * 16 + lr;
    char* base = smb + 65536 + buf * 32768 + ph * 16384 + wn * 4096 + row * 128;
    int sw = (row & 7) << 4;
#pragma unroll
    for (int ks = 0; ks < 2; ++ks)
      bf[gr][ks] = *(const short8*)(base + ((ks * 64 + lc) ^ sw));
  }
}
template <int BPH>
__device__ __forceinline__ void mfmaq_f(const short8 (&afr)[4][2], const short8 (&bf)[2][2],
                                        f32x4 (*ac)[4]) {
  __builtin_amdgcn_s_setprio(1);
#pragma unroll
  for (int fi = 0; fi < 4; ++fi)
#pragma unroll
    for (int gj = 0; gj < 2; ++gj)
#pragma unroll
      for (int ks = 0; ks < 2; ++ks)
        ac[fi][BPH * 2 + gj] = __builtin_amdgcn_mfma_f32_16x16x32_bf16(
            afr[fi][ks], bf[gj][ks], ac[fi][BPH * 2 + gj], 0, 0, 0);
  __builtin_amdgcn_s_setprio(0);
}

template <int EPI>
__global__ __launch_bounds__(512, 2) void gemm8p(
    const unsigned short* __restrict__ A, int lda,
    const unsigned short* __restrict__ Bt, int ldb,
    unsigned short* __restrict__ C, int ldc,
    const float* __restrict__ bias,
    const float* __restrict__ residf, int ldr,
    int K, int NBX) {
  extern __shared__ char smb[];
  const int tid = threadIdx.x;
  const int lane = tid & 63, wid = tid >> 6;
  const int wm = wid >> 2, wn = wid & 3;

  // XCD-aware swizzle (gridDim.x % 8 == 0 for all our launches)
  int nwg = gridDim.x, orig = blockIdx.x;
  int wg = ((orig & 7) * (nwg >> 3)) + (orig >> 3);
  const long m0 = (long)(wg / NBX) * 256;
  const long n0 = (long)(wg % NBX) * 256;

  const int NT = K >> 6, NI = NT >> 1;

  short8 afr[4][2];
  short8 bfr[2][2][2];
  f32x4 acc[8][4] = {};

  auto stA = [&](int buf, int ph, int kt) {
#pragma unroll
    for (int rnd = 0; rnd < 2; ++rnd) {
      int o = rnd * 8192 + tid * 16;
      int wms = o >> 13, rs = (o >> 7) & 63, cb = o & 127;
      int pcb = cb ^ ((rs & 7) << 4);                // inverse-swizzled source
      const unsigned short* src = A + (m0 + wms * 128 + ph * 64 + rs) * (long)lda + kt * 64 + (pcb >> 1);
      gload16(src, (unsigned short*)(smb + buf * 32768 + ph * 16384 + o));
    }
  };
  auto stB = [&](int buf, int ph, int kt) {
#pragma unroll
    for (int rnd = 0; rnd < 2; ++rnd) {
      int o = rnd * 8192 + tid * 16;
      int wns = (o >> 12) & 3, rs = (o >> 7) & 31, cb = o & 127;
      int pcb = cb ^ ((rs & 7) << 4);
      const unsigned short* src = Bt + (n0 + wns * 64 + ph * 32 + rs) * (long)ldb + kt * 64 + (pcb >> 1);
      gload16(src, (unsigned short*)(smb + 65536 + buf * 32768 + ph * 16384 + o));
    }
  };

  // Prologue: buf0 fully (kt 0); buf1 {A-ph0, B-ph0, B-ph1} (kt 1); A-ph1(kt1) deferred to P1.
  stA(0, 0, 0); stA(0, 1, 0); stB(0, 0, 0); stB(0, 1, 0);
  stA(1, 0, 1); stB(1, 0, 1); stB(1, 1, 1);
  VMW(6);   // 14 issued; all but newest 6 landed => buf0 complete
  BARR;

  for (int i = 0; i < NI; ++i) {
    int t2 = 2 * i + 2, t3 = 2 * i + 3;
    bool s2 = t2 < NT, s3 = t3 < NT;
    // ---- K-tile 2i (buf0) ----
    // P1: read A-ph0,B-ph0; stage buf1.A-ph1 <- kt 2i+1 (freed prev P7 / prologue gap)
    rdA_f(smb, 0, 0, wm, lane, afr);
    rdB_f(smb, 0, 0, wn, lane, bfr[0]);
    stA(1, 1, 2 * i + 1);
    BARR; mfmaq_f<0>(afr, bfr[0], &acc[0]); BARR;
    // P2: read B-ph1; stage buf0.A-ph0 <- t2 (freed P1)
    rdB_f(smb, 0, 1, wn, lane, bfr[1]);
    if (s2) stA(0, 0, t2);
    BARR; mfmaq_f<1>(afr, bfr[1], &acc[0]); BARR;
    // P3: read A-ph1; stage buf0.B-ph0 <- t2 (freed P1)
    rdA_f(smb, 0, 1, wm, lane, afr);
    if (s2) stB(0, 0, t2);
    BARR; mfmaq_f<0>(afr, bfr[0], &acc[4]); BARR;
    // P4: stage buf0.B-ph1 <- t2 (freed P2); counted vmcnt -> buf1 ready
    if (s2) stB(0, 1, t2);
    BARR; mfmaq_f<1>(afr, bfr[1], &acc[4]);
    if (s2) { VMW(6); } else { VMW(0); }
    BARR;
    // ---- K-tile 2i+1 (buf1) ----
    // P5: stage buf0.A-ph1 <- t2 (freed P3)
    rdA_f(smb, 1, 0, wm, lane, afr);
    rdB_f(smb, 1, 0, wn, lane, bfr[0]);
    if (s2) stA(0, 1, t2);
    BARR; mfmaq_f<0>(afr, bfr[0], &acc[0]); BARR;
    // P6: stage buf1.A-ph0 <- t3 (freed P5)
    rdB_f(smb, 1, 1, wn, lane, bfr[1]);
    if (s3) stA(1, 0, t3);
    BARR; mfmaq_f<1>(afr, bfr[1], &acc[0]); BARR;
    // P7: stage buf1.B-ph0 <- t3 (freed P5)
    rdA_f(smb, 1, 1, wm, lane, afr);
    if (s3) stB(1, 0, t3);
    BARR; mfmaq_f<0>(afr, bfr[0], &acc[4]); BARR;
    // P8: stage buf1.B-ph1 <- t3 (freed P6); counted vmcnt -> buf0 ready
    if (s3) stB(1, 1, t3);
    BARR; mfmaq_f<1>(afr, bfr[1], &acc[4]);
    if (s3) { VMW(6); } else { VMW(0); }
    BARR;
  }

  // Epilogue: C-write with bias (+ optional f32 residual)
#pragma unroll
  for (int f = 0; f < 8; ++f) {
#pragma unroll
    for (int g = 0; g < 4; ++g) {
      long col = n0 + wn * 64 + g * 16 + (lane & 15);
      float bv = bias[col];
#pragma unroll
      for (int r = 0; r < 4; ++r) {
        long row = m0 + wm * 128 + f * 16 + (lane >> 4) * 4 + r;
        float o = acc[f][g][r] + bv;
        if (EPI == 1) o += residf[row * (long)ldr + col];
        C[row * (long)ldc + col] = f2b(o);
      }
    }
  }
}

// ---------------------------------------------------------------------------
// m97-structure bf16 GEMM kept for the small/odd shapes (FF1 N=128, FF2 K=128).
// EPI: 2 = tanh(+bias) ; 3 = +bias + bf16 resid
// ---------------------------------------------------------------------------
template <int EPI>
__global__ __launch_bounds__(256, 2) void gemm_bt(
    const unsigned short* __restrict__ A, int lda,
    const unsigned short* __restrict__ Bt, int ldb,
    unsigned short* __restrict__ C, int ldc,
    const float* __restrict__ bias,
    const float* __restrict__ residf,
    const unsigned short* __restrict__ residb, int ldr, int K) {
  __shared__ __align__(16) unsigned short Asm[128 * 32];
  __shared__ __align__(16) unsigned short Bsm[128 * 32];
  const int tid = threadIdx.x;
  const int lane = tid & 63, wid = tid >> 6;
  const int wr = wid >> 1, wc = wid & 1;
  const long m0 = (long)blockIdx.y * 128;
  const long n0 = (long)blockIdx.x * 128;

  f32x4 acc[4][4] = {};

  for (int kk = 0; kk < K; kk += 32) {
    __syncthreads();
#pragma unroll
    for (int i = 0; i < 2; ++i) {
      int slot = i * 256 + tid;
      int r = slot >> 2, cg = (slot & 3) * 8;
      gload16(A + (m0 + r) * (long)lda + kk + cg, &Asm[slot * 8]);
      gload16(Bt + (n0 + r) * (long)ldb + kk + cg, &Bsm[slot * 8]);
    }
    __syncthreads();
    short8 af[4], bfr[4];
#pragma unroll
    for (int mt = 0; mt < 4; ++mt)
      af[mt] = *(const short8*)&Asm[(wr * 64 + mt * 16 + (lane & 15)) * 32 + (lane >> 4) * 8];
#pragma unroll
    for (int nt = 0; nt < 4; ++nt)
      bfr[nt] = *(const short8*)&Bsm[(wc * 64 + nt * 16 + (lane & 15)) * 32 + (lane >> 4) * 8];
#pragma unroll
    for (int mt = 0; mt < 4; ++mt)
#pragma unroll
      for (int nt = 0; nt < 4; ++nt)
        acc[mt][nt] = __builtin_amdgcn_mfma_f32_16x16x32_bf16(af[mt], bfr[nt], acc[mt][nt], 0, 0, 0);
  }

  const long row0 = m0 + wr * 64 + ((lane >> 4) * 4);
  const long col0 = n0 + wc * 64 + (lane & 15);
#pragma unroll
  for (int mt = 0; mt < 4; ++mt) {
#pragma unroll
    for (int nt = 0; nt < 4; ++nt) {
      long col = col0 + nt * 16;
      float bv = bias[col];
      f32x4 v = acc[mt][nt];
#pragma unroll
      for (int r = 0; r < 4; ++r) {
        long row = row0 + mt * 16 + r;
        float o = v[r] + bv;
        if (EPI == 1) o += residf[row * (long)ldr + col];
        if (EPI == 2) o = tanhf(o);
        if (EPI == 3) o += b2f(residb[row * (long)ldr + col]);
        C[row * (long)ldc + col] = f2b(o);
      }
    }
  }
}

// ---------------------------------------------------------------------------
// scores[b,h,k,q] = sum_s K[b,h,s,k] * Q[b,h,s,q], split over 4 s-segments.
// Q at QKV col h*64, K at QKV col 1024+h*64, row stride 3072. f32 accumulate.
// ---------------------------------------------------------------------------
__global__ __launch_bounds__(256) void scores_partial(
    const unsigned short* __restrict__ QKV, float* __restrict__ part) {
  __shared__ __align__(16) float Qc[128][64];
  __shared__ __align__(16) float Kc[128][64];
  int bh = blockIdx.x, seg = blockIdx.y;
  int b = bh >> 4, h = bh & 15;
  int tid = threadIdx.x;
  int q4 = (tid & 15) * 4, k4 = (tid >> 4) * 4;
  float acc[4][4] = {};

  for (int ch = 0; ch < 8; ++ch) {
    long s0 = (long)b * 4096 + seg * 1024 + ch * 128;
    __syncthreads();
#pragma unroll
    for (int i = 0; i < 4; ++i) {
      int idx = i * 256 + tid;
      int r = idx >> 3, c8 = (idx & 7) * 8;
      short8 qv = *(const short8*)(QKV + (s0 + r) * 3072 + h * 64 + c8);
      short8 kv = *(const short8*)(QKV + (s0 + r) * 3072 + 1024 + h * 64 + c8);
#pragma unroll
      for (int j = 0; j < 8; ++j) {
        Qc[r][c8 + j] = b2f((unsigned short)qv[j]);
        Kc[r][c8 + j] = b2f((unsigned short)kv[j]);
      }
    }
    __syncthreads();
    for (int ss = 0; ss < 128; ++ss) {
      f32x4 qv = *(const f32x4*)&Qc[ss][q4];
      f32x4 kv = *(const f32x4*)&Kc[ss][k4];
#pragma unroll
      for (int i = 0; i < 4; ++i)
#pragma unroll
        for (int j = 0; j < 4; ++j) acc[i][j] += kv[i] * qv[j];
    }
  }
  float* dst = part + (long)(bh * 4 + seg) * 4096;
#pragma unroll
  for (int i = 0; i < 4; ++i)
#pragma unroll
    for (int j = 0; j < 4; ++j) dst[(k4 + i) * 64 + q4 + j] = acc[i][j];
}

// softmax over k (per q column), scores/8; writes w^T bf16: wT[bh][q][k]
__global__ __launch_bounds__(64) void softmax_wT(
    const float* __restrict__ part, const int* __restrict__ mask,
    unsigned short* __restrict__ wT) {
  int bh = blockIdx.x, q = threadIdx.x;
  int b = bh >> 4;
  const float* p0 = part + (long)bh * 4 * 4096;
  float s[64];
#pragma unroll
  for (int k = 0; k < 64; ++k)
    s[k] = p0[k * 64 + q] + p0[4096 + k * 64 + q] + p0[8192 + k * 64 + q] + p0[12288 + k * 64 + q];
  bool live = (mask[b * 64 + q] != 0);
  float m = -1e30f;
#pragma unroll
  for (int k = 0; k < 64; ++k) m = fmaxf(m, s[k]);
  float sum = 0.0f;
#pragma unroll
  for (int k = 0; k < 64; ++k) {
    s[k] = __expf((s[k] - m) * 0.125f);
    sum += s[k];
  }
  float inv = live ? 1.0f / sum : 0.0f;
  unsigned short* o = wT + (long)bh * 4096 + q * 64;
#pragma unroll
  for (int k = 0; k < 64; ++k) o[k] = f2b(s[k] * inv);
}

// attn[tok][h*64+q] = sum_k V[tok][k] * w[k][q]; V = QKV col 2048+h*64, stride 3072.
__global__ __launch_bounds__(256) void attn_pv(
    const unsigned short* __restrict__ QKV, const unsigned short* __restrict__ wT,
    unsigned short* __restrict__ attn) {
  int tc = blockIdx.x;   // 128 chunks of 256 tokens
  int h = blockIdx.y;    // 16 heads
  int tid = threadIdx.x, lane = tid & 63, wid = tid >> 6;
  long tok0 = (long)tc * 256 + wid * 64;
  int b = (tc * 256) >> 12;
  const unsigned short* wp = wT + (long)(b * 16 + h) * 4096;
  const unsigned short* V = QKV + 2048;
  f32x4 acc[4][4] = {};
#pragma unroll
  for (int ks = 0; ks < 2; ++ks) {
    short8 bfr[4];
#pragma unroll
    for (int nt = 0; nt < 4; ++nt)
      bfr[nt] = *(const short8*)&wp[(nt * 16 + (lane & 15)) * 64 + ks * 32 + (lane >> 4) * 8];
#pragma unroll
    for (int mt = 0; mt < 4; ++mt) {
      short8 af = *(const short8*)(V + (tok0 + mt * 16 + (lane & 15)) * 3072 + h * 64 + ks * 32 + (lane >> 4) * 8);
#pragma unroll
      for (int nt = 0; nt < 4; ++nt)
        acc[mt][nt] = __builtin_amdgcn_mfma_f32_16x16x32_bf16(af, bfr[nt], acc[mt][nt], 0, 0, 0);
    }
  }
#pragma unroll
  for (int mt = 0; mt < 4; ++mt)
#pragma unroll
    for (int nt = 0; nt < 4; ++nt)
#pragma unroll
      for (int r = 0; r < 4; ++r) {
        long row = tok0 + mt * 16 + (lane >> 4) * 4 + r;
        int col = h * 64 + nt * 16 + (lane & 15);
        attn[row * 1024 + col] = f2b(acc[mt][nt][r]);
      }
}

// rmsnorm over D=1024; one block per row. bf16 in; bf16 or f32 out.
template <int OUTF>
__global__ __launch_bounds__(256) void rmsnorm_k(
    const unsigned short* __restrict__ in, const float* __restrict__ g,
    unsigned short* __restrict__ outb, float* __restrict__ outf) {
  long row = blockIdx.x;
  int tid = threadIdx.x;
  short4v u = *(const short4v*)(in + row * 1024 + tid * 4);
  float v[4];
  float ss = 0.0f;
#pragma unroll
  for (int i = 0; i < 4; ++i) {
    v[i] = b2f((unsigned short)u[i]);
    ss += v[i] * v[i];
  }
#pragma unroll
  for (int off = 32; off > 0; off >>= 1) ss += __shfl_xor(ss, off, 64);
  __shared__ float wsum[4];
  if ((tid & 63) == 0) wsum[tid >> 6] = ss;
  __syncthreads();
  float tot = wsum[0] + wsum[1] + wsum[2] + wsum[3];
  float rs = rsqrtf(tot * (1.0f / 1024.0f) + 1e-6f);
  f32x4 gv = *(const f32x4*)(g + tid * 4);
  if (OUTF) {
    f32x4 ov;
#pragma unroll
    for (int i = 0; i < 4; ++i) ov[i] = v[i] * rs * gv[i];
    *(f32x4*)(outf + row * 1024 + tid * 4) = ov;
  } else {
    short4v ov;
#pragma unroll
    for (int i = 0; i < 4; ++i) ov[i] = (short)f2b(v[i] * rs * gv[i]);
    *(short4v*)(outb + row * 1024 + tid * 4) = ov;
  }
}

// ---------------------------------------------------------------------------
extern "C" void kernel_launch(void* const* d_in, const int* in_sizes, int n_in,
                              void* d_out, int out_size, void* d_ws, size_t ws_size,
                              hipStream_t stream) {
  const float* x  = (const float*)d_in[0];
  const int* mask = (const int*)d_in[1];
  const float* Wq = (const float*)d_in[2];
  const float* bq = (const float*)d_in[3];
  const float* Wk = (const float*)d_in[4];
  const float* bk = (const float*)d_in[5];
  const float* Wv = (const float*)d_in[6];
  const float* bv = (const float*)d_in[7];
  const float* Wo = (const float*)d_in[8];
  const float* bo = (const float*)d_in[9];
  const float* W1 = (const float*)d_in[10];
  const float* b1 = (const float*)d_in[11];
  const float* W2 = (const float*)d_in[12];
  const float* b2 = (const float*)d_in[13];
  const float* g1 = (const float*)d_in[14];
  const float* g2 = (const float*)d_in[15];

  char* ws = (char*)d_ws;
  size_t off = 0;
  auto alc = [&](size_t n) { size_t o = off; off += (n + 255) & ~(size_t)255; return o; };
  unsigned short* BqkvT = (unsigned short*)(ws + alc(3072UL * 1024 * 2));
  unsigned short* WoT   = (unsigned short*)(ws + alc(1024UL * 1024 * 2));
  unsigned short* W1T   = (unsigned short*)(ws + alc(128UL * 1024 * 2));
  unsigned short* W2T   = (unsigned short*)(ws + alc(1024UL * 128 * 2));
  float*          bqkv  = (float*)(ws + alc(3072UL * 4));
  unsigned short* R0    = (unsigned short*)(ws + alc(32768UL * 1024 * 2));  // xb -> attn -> hf
  unsigned short* R1    = (unsigned short*)(ws + alc(32768UL * 3072 * 2));  // QKV -> h1
  unsigned short* H2b   = (unsigned short*)(ws + alc(32768UL * 1024 * 2));
  unsigned short* Tb    = (unsigned short*)(ws + alc(32768UL * 128 * 2));
  float*          SP    = (float*)(ws + alc(512UL * 4096 * 4));
  unsigned short* WTb   = (unsigned short*)(ws + alc(128UL * 4096 * 2));
  if (ws_size < off) return;

  unsigned short* xb   = R0;
  unsigned short* attn = R0;
  unsigned short* HFb  = R0;
  unsigned short* QKVb = R1;
  unsigned short* H1b  = R1;
  float* outp = (float*)d_out;

  cvt_kernel<<<16384, 256, 0, stream>>>(x, xb, 4194304);
  repack_kernel<<<5248, 256, 0, stream>>>(Wq, Wk, Wv, Wo, W1, W2, bq, bk, bv,
                                          BqkvT, WoT, W1T, W2T, bqkv);
  // QKV = xb @ [Wq|Wk|Wv]^T + b   (8-phase 256^2; grid 128x12 = 1536)
  gemm8p<0><<<1536, 512, 131072, stream>>>(xb, 1024, BqkvT, 1024, QKVb, 3072,
                                           bqkv, nullptr, 0, 1024, 12);
  scores_partial<<<dim3(128, 4), 256, 0, stream>>>(QKVb, SP);
  softmax_wT<<<128, 64, 0, stream>>>(SP, mask, WTb);
  attn_pv<<<dim3(128, 16), 256, 0, stream>>>(QKVb, WTb, attn);
  // h1 = x + attn@WoT + bo   (8-phase; grid 128x4 = 512)
  gemm8p<1><<<512, 512, 131072, stream>>>(attn, 1024, WoT, 1024, H1b, 1024,
                                          bo, x, 1024, 1024, 4);
  rmsnorm_k<0><<<32768, 256, 0, stream>>>(H1b, g1, H2b, nullptr);
  // t = tanh(h2@W1T + b1)
  gemm_bt<2><<<dim3(1, 256), 256, 0, stream>>>(H2b, 1024, W1T, 1024, Tb, 128,
                                               b1, nullptr, nullptr, 0, 1024);
  // hf = t@W2T + b2 + h2  (bf16 residual)
  gemm_bt<3><<<dim3(8, 256), 256, 0, stream>>>(Tb, 128, W2T, 128, HFb, 1024,
                                               b2, nullptr, H2b, 1024, 128);
  rmsnorm_k<1><<<32768, 256, 0, stream>>>(HFb, g2, nullptr, outp);
}

// Round 5
// 607.377 us; speedup vs baseline: 1.1840x; 1.0916x over previous
//
#include <hip/hip_runtime.h>
#include <math.h>

typedef __attribute__((ext_vector_type(4))) float f32x4;
typedef __attribute__((ext_vector_type(8))) short short8;   // 8 bf16 raw bits
typedef __attribute__((ext_vector_type(4))) short short4v;  // 4 bf16 raw bits

__device__ __forceinline__ float b2f(unsigned short u) {
  unsigned int x = ((unsigned int)u) << 16;
  return __builtin_bit_cast(float, x);
}
__device__ __forceinline__ unsigned short f2b(float f) {
  unsigned int x = __builtin_bit_cast(unsigned int, f);
  x += 0x7fffu + ((x >> 16) & 1u);   // round-to-nearest-even
  return (unsigned short)(x >> 16);
}

// async global->LDS, 16B per lane. LDS dest must be lane-contiguous (wave base + lane*16).
__device__ __forceinline__ void gload16(const unsigned short* g, unsigned short* l) {
  __builtin_amdgcn_global_load_lds(
      (__attribute__((address_space(1))) void*)(unsigned long long)(const void*)g,
      (__attribute__((address_space(3))) void*)l, 16, 0, 0);
}

#define BARR  { __builtin_amdgcn_sched_barrier(0); __builtin_amdgcn_s_barrier(); __builtin_amdgcn_sched_barrier(0); }
#define VMW(n) { __builtin_amdgcn_sched_barrier(0); asm volatile("s_waitcnt vmcnt(" #n ")" ::: "memory"); __builtin_amdgcn_sched_barrier(0); }

// ---------------------------------------------------------------------------
// prep_kernel: fuses x->bf16 convert with all weight repacks (coalesced
// 64x64 LDS-transpose tiles, +1 pad) and the QKV bias concat. One launch.
// Grid: [0,16384) cvt ; [16384, 16384+1089) transposes/bias.
// ---------------------------------------------------------------------------
__global__ __launch_bounds__(256) void prep_kernel(
    const float* __restrict__ x, unsigned short* __restrict__ xb,
    const float* __restrict__ Wq, const float* __restrict__ Wk,
    const float* __restrict__ Wv, const float* __restrict__ Wo,
    const float* __restrict__ W1, const float* __restrict__ W2,
    const float* __restrict__ bq, const float* __restrict__ bk, const float* __restrict__ bv,
    unsigned short* __restrict__ BqkvT, unsigned short* __restrict__ WoT,
    unsigned short* __restrict__ W1T, unsigned short* __restrict__ W2T,
    float* __restrict__ bqkv) {
  __shared__ float tile[64][65];
  int nb = blockIdx.x, t = threadIdx.x;
  if (nb < 16384) {                       // x -> bf16, 8 elems/thread
    long i = (long)nb * 256 + t;
    f32x4 a = ((const f32x4*)x)[i * 2];
    f32x4 b = ((const f32x4*)x)[i * 2 + 1];
    short8 o;
#pragma unroll
    for (int j = 0; j < 4; ++j) { o[j] = (short)f2b(a[j]); o[4 + j] = (short)f2b(b[j]); }
    ((short8*)xb)[i] = o;
    return;
  }
  int n0 = nb - 16384;
  if (n0 == 1088) {                       // QKV bias concat (f32)
#pragma unroll
    for (int it = 0; it < 12; ++it) {
      int idx = it * 256 + t;
      float v = (idx < 1024) ? bq[idx] : (idx < 2048 ? bk[idx - 1024] : bv[idx - 2048]);
      bqkv[idx] = v;
    }
    return;
  }
  const float* src; unsigned short* dst; int sld, dld;
  if (n0 < 768) {                         // Wq/Wk/Wv (H,D,HD): tile d-chunk x e(64)
    int w = n0 >> 8, rem = n0 & 255, h = rem >> 4, dc = rem & 15;
    const float* W = (w == 0) ? Wq : (w == 1 ? Wk : Wv);
    src = W + ((long)h * 1024 + dc * 64) * 64;                 sld = 64;
    dst = BqkvT + (long)(w * 1024 + h * 64) * 1024 + dc * 64;  dld = 1024;
  } else if (n0 < 1024) {                 // Wo (D,D) -> WoT[j][d]
    int rem = n0 - 768, dr = rem >> 4, jc = rem & 15;
    src = Wo + (long)dr * 64 * 1024 + jc * 64;                 sld = 1024;
    dst = WoT + (long)jc * 64 * 1024 + dr * 64;                dld = 1024;
  } else if (n0 < 1056) {                 // W1 (D,128) -> W1T[f][d]
    int rem = n0 - 1024, dr = rem >> 1, fc = rem & 1;
    src = W1 + (long)dr * 64 * 128 + fc * 64;                  sld = 128;
    dst = W1T + (long)fc * 64 * 1024 + dr * 64;                dld = 1024;
  } else {                                // W2 (128,D) -> W2T[j][f]
    int rem = n0 - 1056, fr = rem >> 4, jc = rem & 15;
    src = W2 + (long)fr * 64 * 1024 + jc * 64;                 sld = 1024;
    dst = W2T + (long)jc * 64 * 128 + fr * 64;                 dld = 128;
  }
  int r = t >> 2, c0 = (t & 3) * 16;
#pragma unroll
  for (int j4 = 0; j4 < 4; ++j4) {
    f32x4 v = *(const f32x4*)(src + (long)r * sld + c0 + j4 * 4);
    tile[c0 + j4 * 4 + 0][r] = v[0];
    tile[c0 + j4 * 4 + 1][r] = v[1];
    tile[c0 + j4 * 4 + 2][r] = v[2];
    tile[c0 + j4 * 4 + 3][r] = v[3];
  }
  __syncthreads();
  short8 o0, o1;
#pragma unroll
  for (int j = 0; j < 8; ++j) {
    o0[j] = (short)f2b(tile[r][c0 + j]);
    o1[j] = (short)f2b(tile[r][c0 + 8 + j]);
  }
  *(short8*)(dst + (long)r * dld + c0) = o0;
  *(short8*)(dst + (long)r * dld + c0 + 8) = o1;
}

// ---------------------------------------------------------------------------
// 256x256 8-phase bf16 GEMM (T2 swizzle + T3/T4 counted vmcnt + T5 setprio).
// Verified round 4: SQ_LDS_BANK_CONFLICT == 0 with byte ^= (row&7)<<4 on both
// stage-source (inverse) and ds_read. EPI: 0 = +bias ; 1 = +bias + f32 resid.
// ---------------------------------------------------------------------------
__device__ __forceinline__ void rdA_f(char* smb, int buf, int ph, int wm, int lane,
                                      short8 (&afr)[4][2]) {
  const int lr = lane & 15, lc = (lane >> 4) * 16;
#pragma unroll
  for (int fr = 0; fr < 4; ++fr) {
    int row = fr * 16 + lr;
    char* base = smb + buf * 32768 + ph * 16384 + wm * 8192 + row * 128;
    int sw = (row & 7) << 4;
#pragma unroll
    for (int ks = 0; ks < 2; ++ks)
      afr[fr][ks] = *(const short8*)(base + ((ks * 64 + lc) ^ sw));
  }
}
__device__ __forceinline__ void rdB_f(char* smb, int buf, int ph, int wn, int lane,
                                      short8 (&bf)[2][2]) {
  const int lr = lane & 15, lc = (lane >> 4) * 16;
#pragma unroll
  for (int gr = 0; gr < 2; ++gr) {
    int row = gr * 16 + lr;
    char* base = smb + 65536 + buf * 32768 + ph * 16384 + wn * 4096 + row * 128;
    int sw = (row & 7) << 4;
#pragma unroll
    for (int ks = 0; ks < 2; ++ks)
      bf[gr][ks] = *(const short8*)(base + ((ks * 64 + lc) ^ sw));
  }
}
template <int BPH>
__device__ __forceinline__ void mfmaq_f(const short8 (&afr)[4][2], const short8 (&bf)[2][2],
                                        f32x4 (*ac)[4]) {
  __builtin_amdgcn_s_setprio(1);
#pragma unroll
  for (int fi = 0; fi < 4; ++fi)
#pragma unroll
    for (int gj = 0; gj < 2; ++gj)
#pragma unroll
      for (int ks = 0; ks < 2; ++ks)
        ac[fi][BPH * 2 + gj] = __builtin_amdgcn_mfma_f32_16x16x32_bf16(
            afr[fi][ks], bf[gj][ks], ac[fi][BPH * 2 + gj], 0, 0, 0);
  __builtin_amdgcn_s_setprio(0);
}

template <int EPI>
__global__ __launch_bounds__(512, 2) void gemm8p(
    const unsigned short* __restrict__ A, int lda,
    const unsigned short* __restrict__ Bt, int ldb,
    unsigned short* __restrict__ C, int ldc,
    const float* __restrict__ bias,
    const float* __restrict__ residf, int ldr,
    int K, int NBX) {
  extern __shared__ char smb[];
  const int tid = threadIdx.x;
  const int lane = tid & 63, wid = tid >> 6;
  const int wm = wid >> 2, wn = wid & 3;

  int nwg = gridDim.x, orig = blockIdx.x;
  int wg = ((orig & 7) * (nwg >> 3)) + (orig >> 3);
  const long m0 = (long)(wg / NBX) * 256;
  const long n0 = (long)(wg % NBX) * 256;

  const int NT = K >> 6, NI = NT >> 1;

  short8 afr[4][2];
  short8 bfr[2][2][2];
  f32x4 acc[8][4] = {};

  auto stA = [&](int buf, int ph, int kt) {
#pragma unroll
    for (int rnd = 0; rnd < 2; ++rnd) {
      int o = rnd * 8192 + tid * 16;
      int wms = o >> 13, rs = (o >> 7) & 63, cb = o & 127;
      int pcb = cb ^ ((rs & 7) << 4);                // inverse-swizzled source
      const unsigned short* src = A + (m0 + wms * 128 + ph * 64 + rs) * (long)lda + kt * 64 + (pcb >> 1);
      gload16(src, (unsigned short*)(smb + buf * 32768 + ph * 16384 + o));
    }
  };
  auto stB = [&](int buf, int ph, int kt) {
#pragma unroll
    for (int rnd = 0; rnd < 2; ++rnd) {
      int o = rnd * 8192 + tid * 16;
      int wns = (o >> 12) & 3, rs = (o >> 7) & 31, cb = o & 127;
      int pcb = cb ^ ((rs & 7) << 4);
      const unsigned short* src = Bt + (n0 + wns * 64 + ph * 32 + rs) * (long)ldb + kt * 64 + (pcb >> 1);
      gload16(src, (unsigned short*)(smb + 65536 + buf * 32768 + ph * 16384 + o));
    }
  };

  stA(0, 0, 0); stA(0, 1, 0); stB(0, 0, 0); stB(0, 1, 0);
  stA(1, 0, 1); stB(1, 0, 1); stB(1, 1, 1);
  VMW(6);
  BARR;

  for (int i = 0; i < NI; ++i) {
    int t2 = 2 * i + 2, t3 = 2 * i + 3;
    bool s2 = t2 < NT, s3 = t3 < NT;
    rdA_f(smb, 0, 0, wm, lane, afr);
    rdB_f(smb, 0, 0, wn, lane, bfr[0]);
    stA(1, 1, 2 * i + 1);
    BARR; mfmaq_f<0>(afr, bfr[0], &acc[0]); BARR;
    rdB_f(smb, 0, 1, wn, lane, bfr[1]);
    if (s2) stA(0, 0, t2);
    BARR; mfmaq_f<1>(afr, bfr[1], &acc[0]); BARR;
    rdA_f(smb, 0, 1, wm, lane, afr);
    if (s2) stB(0, 0, t2);
    BARR; mfmaq_f<0>(afr, bfr[0], &acc[4]); BARR;
    if (s2) stB(0, 1, t2);
    BARR; mfmaq_f<1>(afr, bfr[1], &acc[4]);
    if (s2) { VMW(6); } else { VMW(0); }
    BARR;
    rdA_f(smb, 1, 0, wm, lane, afr);
    rdB_f(smb, 1, 0, wn, lane, bfr[0]);
    if (s2) stA(0, 1, t2);
    BARR; mfmaq_f<0>(afr, bfr[0], &acc[0]); BARR;
    rdB_f(smb, 1, 1, wn, lane, bfr[1]);
    if (s3) stA(1, 0, t3);
    BARR; mfmaq_f<1>(afr, bfr[1], &acc[0]); BARR;
    rdA_f(smb, 1, 1, wm, lane, afr);
    if (s3) stB(1, 0, t3);
    BARR; mfmaq_f<0>(afr, bfr[0], &acc[4]); BARR;
    if (s3) stB(1, 1, t3);
    BARR; mfmaq_f<1>(afr, bfr[1], &acc[4]);
    if (s3) { VMW(6); } else { VMW(0); }
    BARR;
  }

#pragma unroll
  for (int f = 0; f < 8; ++f) {
#pragma unroll
    for (int g = 0; g < 4; ++g) {
      long col = n0 + wn * 64 + g * 16 + (lane & 15);
      float bv = bias[col];
#pragma unroll
      for (int r = 0; r < 4; ++r) {
        long row = m0 + wm * 128 + f * 16 + (lane >> 4) * 4 + r;
        float o = acc[f][g][r] + bv;
        if (EPI == 1) o += residf[row * (long)ldr + col];
        C[row * (long)ldc + col] = f2b(o);
      }
    }
  }
}

// ---------------------------------------------------------------------------
// m97-structure bf16 GEMM kept for the small/odd shapes (FF1 N=128, FF2 K=128).
// EPI: 2 = tanh(+bias) ; 3 = +bias + bf16 resid
// ---------------------------------------------------------------------------
template <int EPI>
__global__ __launch_bounds__(256, 2) void gemm_bt(
    const unsigned short* __restrict__ A, int lda,
    const unsigned short* __restrict__ Bt, int ldb,
    unsigned short* __restrict__ C, int ldc,
    const float* __restrict__ bias,
    const float* __restrict__ residf,
    const unsigned short* __restrict__ residb, int ldr, int K) {
  __shared__ __align__(16) unsigned short Asm[128 * 32];
  __shared__ __align__(16) unsigned short Bsm[128 * 32];
  const int tid = threadIdx.x;
  const int lane = tid & 63, wid = tid >> 6;
  const int wr = wid >> 1, wc = wid & 1;
  const long m0 = (long)blockIdx.y * 128;
  const long n0 = (long)blockIdx.x * 128;

  f32x4 acc[4][4] = {};

  for (int kk = 0; kk < K; kk += 32) {
    __syncthreads();
#pragma unroll
    for (int i = 0; i < 2; ++i) {
      int slot = i * 256 + tid;
      int r = slot >> 2, cg = (slot & 3) * 8;
      gload16(A + (m0 + r) * (long)lda + kk + cg, &Asm[slot * 8]);
      gload16(Bt + (n0 + r) * (long)ldb + kk + cg, &Bsm[slot * 8]);
    }
    __syncthreads();
    short8 af[4], bfr[4];
#pragma unroll
    for (int mt = 0; mt < 4; ++mt)
      af[mt] = *(const short8*)&Asm[(wr * 64 + mt * 16 + (lane & 15)) * 32 + (lane >> 4) * 8];
#pragma unroll
    for (int nt = 0; nt < 4; ++nt)
      bfr[nt] = *(const short8*)&Bsm[(wc * 64 + nt * 16 + (lane & 15)) * 32 + (lane >> 4) * 8];
#pragma unroll
    for (int mt = 0; mt < 4; ++mt)
#pragma unroll
      for (int nt = 0; nt < 4; ++nt)
        acc[mt][nt] = __builtin_amdgcn_mfma_f32_16x16x32_bf16(af[mt], bfr[nt], acc[mt][nt], 0, 0, 0);
  }

  const long row0 = m0 + wr * 64 + ((lane >> 4) * 4);
  const long col0 = n0 + wc * 64 + (lane & 15);
#pragma unroll
  for (int mt = 0; mt < 4; ++mt) {
#pragma unroll
    for (int nt = 0; nt < 4; ++nt) {
      long col = col0 + nt * 16;
      float bv = bias[col];
      f32x4 v = acc[mt][nt];
#pragma unroll
      for (int r = 0; r < 4; ++r) {
        long row = row0 + mt * 16 + r;
        float o = v[r] + bv;
        if (EPI == 1) o += residf[row * (long)ldr + col];
        if (EPI == 2) o = tanhf(o);
        if (EPI == 3) o += b2f(residb[row * (long)ldr + col]);
        C[row * (long)ldc + col] = f2b(o);
      }
    }
  }
}

// ---------------------------------------------------------------------------
// scores via MFMA: scores[b,h,k,q] = sum_s K[s,k]*Q[s,q].
// Stage K,Q tiles [64 e][128 s] TRANSPOSED in LDS (bank-swizzled), read
// canonical 16x16x32 fragments (kc = s). One block per (bh, seg); 4 waves,
// wave w owns m-tile (k-rows w*16..+16). Output: f32 partials, same SP layout.
// Swizzle: 16B-slot ^= (e + (e>>3)) & 7  (read claims exactly 8/bank = min).
// ---------------------------------------------------------------------------
__device__ __forceinline__ int sperm(int e) { return ((e + (e >> 3)) & 7) << 4; }

__global__ __launch_bounds__(256) void scores_mfma(
    const unsigned short* __restrict__ QKV, float* __restrict__ part) {
  __shared__ __align__(16) char lds[32768];   // Kc @0, Qc @16384, each 16KB
  int bh = blockIdx.x, seg = blockIdx.y;
  int b = bh >> 4, h = bh & 15;
  int tid = threadIdx.x, lane = tid & 63, wid = tid >> 6;
  int e0 = (tid & 7) * 8;
  int sl0 = (tid >> 3) * 4;
  const unsigned short* Qg = QKV + h * 64;
  const unsigned short* Kg = QKV + 1024 + h * 64;
  f32x4 acc[4] = {};

  for (int ch = 0; ch < 8; ++ch) {
    long S0 = (long)b * 4096 + seg * 1024 + ch * 128;
    __syncthreads();   // prior chunk's reads complete before overwrite
    short8 kv0 = *(const short8*)(Kg + (S0 + sl0 + 0) * 3072 + e0);
    short8 kv1 = *(const short8*)(Kg + (S0 + sl0 + 1) * 3072 + e0);
    short8 kv2 = *(const short8*)(Kg + (S0 + sl0 + 2) * 3072 + e0);
    short8 kv3 = *(const short8*)(Kg + (S0 + sl0 + 3) * 3072 + e0);
    short8 qv0 = *(const short8*)(Qg + (S0 + sl0 + 0) * 3072 + e0);
    short8 qv1 = *(const short8*)(Qg + (S0 + sl0 + 1) * 3072 + e0);
    short8 qv2 = *(const short8*)(Qg + (S0 + sl0 + 2) * 3072 + e0);
    short8 qv3 = *(const short8*)(Qg + (S0 + sl0 + 3) * 3072 + e0);
#pragma unroll
    for (int je = 0; je < 8; ++je) {
      int e = e0 + je;
      int sw = sperm(e);
      char* rowK = lds + e * 256;
      char* rowQ = lds + 16384 + e * 256;
      unsigned int klo = (unsigned short)kv0[je] | ((unsigned int)(unsigned short)kv1[je] << 16);
      unsigned int khi = (unsigned short)kv2[je] | ((unsigned int)(unsigned short)kv3[je] << 16);
      unsigned int qlo = (unsigned short)qv0[je] | ((unsigned int)(unsigned short)qv1[je] << 16);
      unsigned int qhi = (unsigned short)qv2[je] | ((unsigned int)(unsigned short)qv3[je] << 16);
      *(unsigned int*)(rowK + ((sl0 * 2) ^ sw)) = klo;
      *(unsigned int*)(rowK + ((sl0 * 2 + 4) ^ sw)) = khi;
      *(unsigned int*)(rowQ + ((sl0 * 2) ^ sw)) = qlo;
      *(unsigned int*)(rowQ + ((sl0 * 2 + 4) ^ sw)) = qhi;
    }
    __syncthreads();
#pragma unroll
    for (int ksi = 0; ksi < 4; ++ksi) {
      int colb = ksi * 64 + (lane >> 4) * 16;
      int erA = wid * 16 + (lane & 15);
      short8 af = *(const short8*)(lds + erA * 256 + (colb ^ sperm(erA)));
#pragma unroll
      for (int n = 0; n < 4; ++n) {
        int erB = n * 16 + (lane & 15);
        short8 bf = *(const short8*)(lds + 16384 + erB * 256 + (colb ^ sperm(erB)));
        acc[n] = __builtin_amdgcn_mfma_f32_16x16x32_bf16(af, bf, acc[n], 0, 0, 0);
      }
    }
  }
  float* dst = part + ((long)bh * 4 + seg) * 4096;
#pragma unroll
  for (int n = 0; n < 4; ++n)
#pragma unroll
    for (int r = 0; r < 4; ++r) {
      int k = wid * 16 + (lane >> 4) * 4 + r;
      int q = n * 16 + (lane & 15);
      dst[k * 64 + q] = acc[n][r];
    }
}

// softmax over k (per q column), scores/8; writes w^T bf16: wT[bh][q][k]
__global__ __launch_bounds__(64) void softmax_wT(
    const float* __restrict__ part, const int* __restrict__ mask,
    unsigned short* __restrict__ wT) {
  int bh = blockIdx.x, q = threadIdx.x;
  int b = bh >> 4;
  const float* p0 = part + (long)bh * 4 * 4096;
  float s[64];
#pragma unroll
  for (int k = 0; k < 64; ++k)
    s[k] = p0[k * 64 + q] + p0[4096 + k * 64 + q] + p0[8192 + k * 64 + q] + p0[12288 + k * 64 + q];
  bool live = (mask[b * 64 + q] != 0);
  float m = -1e30f;
#pragma unroll
  for (int k = 0; k < 64; ++k) m = fmaxf(m, s[k]);
  float sum = 0.0f;
#pragma unroll
  for (int k = 0; k < 64; ++k) {
    s[k] = __expf((s[k] - m) * 0.125f);
    sum += s[k];
  }
  float inv = live ? 1.0f / sum : 0.0f;
  unsigned short* o = wT + (long)bh * 4096 + q * 64;
#pragma unroll
  for (int k = 0; k < 64; ++k) o[k] = f2b(s[k] * inv);
}

// attn[tok][h*64+q] = sum_k V[tok][k] * w[k][q]; V = QKV col 2048+h*64, stride 3072.
__global__ __launch_bounds__(256) void attn_pv(
    const unsigned short* __restrict__ QKV, const unsigned short* __restrict__ wT,
    unsigned short* __restrict__ attn) {
  int tc = blockIdx.x;
  int h = blockIdx.y;
  int tid = threadIdx.x, lane = tid & 63, wid = tid >> 6;
  long tok0 = (long)tc * 256 + wid * 64;
  int b = (tc * 256) >> 12;
  const unsigned short* wp = wT + (long)(b * 16 + h) * 4096;
  const unsigned short* V = QKV + 2048;
  f32x4 acc[4][4] = {};
#pragma unroll
  for (int ks = 0; ks < 2; ++ks) {
    short8 bfr[4];
#pragma unroll
    for (int nt = 0; nt < 4; ++nt)
      bfr[nt] = *(const short8*)&wp[(nt * 16 + (lane & 15)) * 64 + ks * 32 + (lane >> 4) * 8];
#pragma unroll
    for (int mt = 0; mt < 4; ++mt) {
      short8 af = *(const short8*)(V + (tok0 + mt * 16 + (lane & 15)) * 3072 + h * 64 + ks * 32 + (lane >> 4) * 8);
#pragma unroll
      for (int nt = 0; nt < 4; ++nt)
        acc[mt][nt] = __builtin_amdgcn_mfma_f32_16x16x32_bf16(af, bfr[nt], acc[mt][nt], 0, 0, 0);
    }
  }
#pragma unroll
  for (int mt = 0; mt < 4; ++mt)
#pragma unroll
    for (int nt = 0; nt < 4; ++nt)
#pragma unroll
      for (int r = 0; r < 4; ++r) {
        long row = tok0 + mt * 16 + (lane >> 4) * 4 + r;
        int col = h * 64 + nt * 16 + (lane & 15);
        attn[row * 1024 + col] = f2b(acc[mt][nt][r]);
      }
}

// rmsnorm over D=1024; one block per row. bf16 in; bf16 or f32 out.
template <int OUTF>
__global__ __launch_bounds__(256) void rmsnorm_k(
    const unsigned short* __restrict__ in, const float* __restrict__ g,
    unsigned short* __restrict__ outb, float* __restrict__ outf) {
  long row = blockIdx.x;
  int tid = threadIdx.x;
  short4v u = *(const short4v*)(in + row * 1024 + tid * 4);
  float v[4];
  float ss = 0.0f;
#pragma unroll
  for (int i = 0; i < 4; ++i) {
    v[i] = b2f((unsigned short)u[i]);
    ss += v[i] * v[i];
  }
#pragma unroll
  for (int off = 32; off > 0; off >>= 1) ss += __shfl_xor(ss, off, 64);
  __shared__ float wsum[4];
  if ((tid & 63) == 0) wsum[tid >> 6] = ss;
  __syncthreads();
  float tot = wsum[0] + wsum[1] + wsum[2] + wsum[3];
  float rs = rsqrtf(tot * (1.0f / 1024.0f) + 1e-6f);
  f32x4 gv = *(const f32x4*)(g + tid * 4);
  if (OUTF) {
    f32x4 ov;
#pragma unroll
    for (int i = 0; i < 4; ++i) ov[i] = v[i] * rs * gv[i];
    *(f32x4*)(outf + row * 1024 + tid * 4) = ov;
  } else {
    short4v ov;
#pragma unroll
    for (int i = 0; i < 4; ++i) ov[i] = (short)f2b(v[i] * rs * gv[i]);
    *(short4v*)(outb + row * 1024 + tid * 4) = ov;
  }
}

// ---------------------------------------------------------------------------
extern "C" void kernel_launch(void* const* d_in, const int* in_sizes, int n_in,
                              void* d_out, int out_size, void* d_ws, size_t ws_size,
                              hipStream_t stream) {
  const float* x  = (const float*)d_in[0];
  const int* mask = (const int*)d_in[1];
  const float* Wq = (const float*)d_in[2];
  const float* bq = (const float*)d_in[3];
  const float* Wk = (const float*)d_in[4];
  const float* bk = (const float*)d_in[5];
  const float* Wv = (const float*)d_in[6];
  const float* bv = (const float*)d_in[7];
  const float* Wo = (const float*)d_in[8];
  const float* bo = (const float*)d_in[9];
  const float* W1 = (const float*)d_in[10];
  const float* b1 = (const float*)d_in[11];
  const float* W2 = (const float*)d_in[12];
  const float* b2 = (const float*)d_in[13];
  const float* g1 = (const float*)d_in[14];
  const float* g2 = (const float*)d_in[15];

  char* ws = (char*)d_ws;
  size_t off = 0;
  auto alc = [&](size_t n) { size_t o = off; off += (n + 255) & ~(size_t)255; return o; };
  unsigned short* BqkvT = (unsigned short*)(ws + alc(3072UL * 1024 * 2));
  unsigned short* WoT   = (unsigned short*)(ws + alc(1024UL * 1024 * 2));
  unsigned short* W1T   = (unsigned short*)(ws + alc(128UL * 1024 * 2));
  unsigned short* W2T   = (unsigned short*)(ws + alc(1024UL * 128 * 2));
  float*          bqkv  = (float*)(ws + alc(3072UL * 4));
  unsigned short* R0    = (unsigned short*)(ws + alc(32768UL * 1024 * 2));  // xb -> attn -> hf
  unsigned short* R1    = (unsigned short*)(ws + alc(32768UL * 3072 * 2));  // QKV -> h1
  unsigned short* H2b   = (unsigned short*)(ws + alc(32768UL * 1024 * 2));
  unsigned short* Tb    = (unsigned short*)(ws + alc(32768UL * 128 * 2));
  float*          SP    = (float*)(ws + alc(512UL * 4096 * 4));
  unsigned short* WTb   = (unsigned short*)(ws + alc(128UL * 4096 * 2));
  if (ws_size < off) return;

  unsigned short* xb   = R0;
  unsigned short* attn = R0;
  unsigned short* HFb  = R0;
  unsigned short* QKVb = R1;
  unsigned short* H1b  = R1;
  float* outp = (float*)d_out;

  // x->bf16 + all weight repacks + bias concat, one launch
  prep_kernel<<<17473, 256, 0, stream>>>(x, xb, Wq, Wk, Wv, Wo, W1, W2, bq, bk, bv,
                                         BqkvT, WoT, W1T, W2T, bqkv);
  // QKV = xb @ [Wq|Wk|Wv]^T + b   (8-phase 256^2; grid 128x12 = 1536)
  gemm8p<0><<<1536, 512, 131072, stream>>>(xb, 1024, BqkvT, 1024, QKVb, 3072,
                                           bqkv, nullptr, 0, 1024, 12);
  scores_mfma<<<dim3(128, 4), 256, 0, stream>>>(QKVb, SP);
  softmax_wT<<<128, 64, 0, stream>>>(SP, mask, WTb);
  attn_pv<<<dim3(128, 16), 256, 0, stream>>>(QKVb, WTb, attn);
  // h1 = x + attn@WoT + bo   (8-phase; grid 128x4 = 512)
  gemm8p<1><<<512, 512, 131072, stream>>>(attn, 1024, WoT, 1024, H1b, 1024,
                                          bo, x, 1024, 1024, 4);
  rmsnorm_k<0><<<32768, 256, 0, stream>>>(H1b, g1, H2b, nullptr);
  // t = tanh(h2@W1T + b1)
  gemm_bt<2><<<dim3(1, 256), 256, 0, stream>>>(H2b, 1024, W1T, 1024, Tb, 128,
                                               b1, nullptr, nullptr, 0, 1024);
  // hf = t@W2T + b2 + h2  (bf16 residual)
  gemm_bt<3><<<dim3(8, 256), 256, 0, stream>>>(Tb, 128, W2T, 128, HFb, 1024,
                                               b2, nullptr, H2b, 1024, 128);
  rmsnorm_k<1><<<32768, 256, 0, stream>>>(HFb, g2, nullptr, outp);
}

// Round 8
// 533.842 us; speedup vs baseline: 1.3471x; 1.1377x over previous
//
#include <hip/hip_runtime.h>
#include <math.h>

typedef __attribute__((ext_vector_type(4))) float f32x4;
typedef __attribute__((ext_vector_type(8))) short short8;   // 8 bf16 raw bits
typedef __attribute__((ext_vector_type(4))) short short4v;  // 4 bf16 raw bits

__device__ __forceinline__ float b2f(unsigned short u) {
  unsigned int x = ((unsigned int)u) << 16;
  return __builtin_bit_cast(float, x);
}
__device__ __forceinline__ unsigned short f2b(float f) {
  unsigned int x = __builtin_bit_cast(unsigned int, f);
  x += 0x7fffu + ((x >> 16) & 1u);   // round-to-nearest-even
  return (unsigned short)(x >> 16);
}

// async global->LDS, 16B per lane. LDS dest must be lane-contiguous (wave base + lane*16).
__device__ __forceinline__ void gload16(const unsigned short* g, unsigned short* l) {
  __builtin_amdgcn_global_load_lds(
      (__attribute__((address_space(1))) void*)(unsigned long long)(const void*)g,
      (__attribute__((address_space(3))) void*)l, 16, 0, 0);
}

#define BARR  { __builtin_amdgcn_sched_barrier(0); __builtin_amdgcn_s_barrier(); __builtin_amdgcn_sched_barrier(0); }
// phase-entry barrier: drain this wave's LDS reads, then sync.
#define LBARR { __builtin_amdgcn_sched_barrier(0); asm volatile("s_waitcnt lgkmcnt(0)" ::: "memory"); __builtin_amdgcn_s_barrier(); __builtin_amdgcn_sched_barrier(0); }
// CROSS-WAVE RULE: vmcnt gate protecting a cooperatively-staged LDS buffer sits
// BEFORE the barrier preceding the reads. BUFFER RULE (round-6/7 bug): a GEMM's
// C region must be disjoint from its A and B regions — V@WPT was writing h1
// over V rows still unread by later blocks.
#define VMW(n) { __builtin_amdgcn_sched_barrier(0); asm volatile("s_waitcnt vmcnt(" #n ")" ::: "memory"); __builtin_amdgcn_sched_barrier(0); }

// ---------------------------------------------------------------------------
// prep_kernel: x->bf16 convert + all weight repacks (64x64 LDS-transpose,
// +1 pad) + QKV bias concat. Grid: [0,16384) cvt ; [16384,16384+1089).
// ---------------------------------------------------------------------------
__global__ __launch_bounds__(256) void prep_kernel(
    const float* __restrict__ x, unsigned short* __restrict__ xb,
    const float* __restrict__ Wq, const float* __restrict__ Wk,
    const float* __restrict__ Wv, const float* __restrict__ Wo,
    const float* __restrict__ W1, const float* __restrict__ W2,
    const float* __restrict__ bq, const float* __restrict__ bk, const float* __restrict__ bv,
    unsigned short* __restrict__ BqkvT, unsigned short* __restrict__ WoT,
    unsigned short* __restrict__ W1T, unsigned short* __restrict__ W2T,
    float* __restrict__ bqkv) {
  __shared__ float tile[64][65];
  int nb = blockIdx.x, t = threadIdx.x;
  if (nb < 16384) {
    long i = (long)nb * 256 + t;
    f32x4 a = ((const f32x4*)x)[i * 2];
    f32x4 b = ((const f32x4*)x)[i * 2 + 1];
    short8 o;
#pragma unroll
    for (int j = 0; j < 4; ++j) { o[j] = (short)f2b(a[j]); o[4 + j] = (short)f2b(b[j]); }
    ((short8*)xb)[i] = o;
    return;
  }
  int n0 = nb - 16384;
  if (n0 == 1088) {
#pragma unroll
    for (int it = 0; it < 12; ++it) {
      int idx = it * 256 + t;
      float v = (idx < 1024) ? bq[idx] : (idx < 2048 ? bk[idx - 1024] : bv[idx - 2048]);
      bqkv[idx] = v;
    }
    return;
  }
  const float* src; unsigned short* dst; int sld, dld;
  if (n0 < 768) {
    int w = n0 >> 8, rem = n0 & 255, h = rem >> 4, dc = rem & 15;
    const float* W = (w == 0) ? Wq : (w == 1 ? Wk : Wv);
    src = W + ((long)h * 1024 + dc * 64) * 64;                 sld = 64;
    dst = BqkvT + (long)(w * 1024 + h * 64) * 1024 + dc * 64;  dld = 1024;
  } else if (n0 < 1024) {
    int rem = n0 - 768, dr = rem >> 4, jc = rem & 15;
    src = Wo + (long)dr * 64 * 1024 + jc * 64;                 sld = 1024;
    dst = WoT + (long)jc * 64 * 1024 + dr * 64;                dld = 1024;
  } else if (n0 < 1056) {
    int rem = n0 - 1024, dr = rem >> 1, fc = rem & 1;
    src = W1 + (long)dr * 64 * 128 + fc * 64;                  sld = 128;
    dst = W1T + (long)fc * 64 * 1024 + dr * 64;                dld = 1024;
  } else {
    int rem = n0 - 1056, fr = rem >> 4, jc = rem & 15;
    src = W2 + (long)fr * 64 * 1024 + jc * 64;                 sld = 1024;
    dst = W2T + (long)jc * 64 * 128 + fr * 64;                 dld = 128;
  }
  int r = t >> 2, c0 = (t & 3) * 16;
#pragma unroll
  for (int j4 = 0; j4 < 4; ++j4) {
    f32x4 v = *(const f32x4*)(src + (long)r * sld + c0 + j4 * 4);
    tile[c0 + j4 * 4 + 0][r] = v[0];
    tile[c0 + j4 * 4 + 1][r] = v[1];
    tile[c0 + j4 * 4 + 2][r] = v[2];
    tile[c0 + j4 * 4 + 3][r] = v[3];
  }
  __syncthreads();
  short8 o0, o1;
#pragma unroll
  for (int j = 0; j < 8; ++j) {
    o0[j] = (short)f2b(tile[r][c0 + j]);
    o1[j] = (short)f2b(tile[r][c0 + 8 + j]);
  }
  *(short8*)(dst + (long)r * dld + c0) = o0;
  *(short8*)(dst + (long)r * dld + c0 + 8) = o1;
}

// ---------------------------------------------------------------------------
// 256x256 bf16 GEMM v2.1 (unchanged from round 7): single barrier/phase +
// fragment read-ahead + imm-offset ds_reads; vmcnt gates BEFORE barriers.
// EPI: 0 = +bias ; 1 = +bias + f32 resid ; 3 = +bias + bf16 resid.
// BSEL: 1 = per-batch B (Bt += (m0>>12)*1M). M%256==0, N%256==0, K%128==0.
// ---------------------------------------------------------------------------
__device__ __forceinline__ void rdA2(short8 (&dst)[4][2], const char* paK0,
                                     const char* paK1, int off) {
#pragma unroll
  for (int fr = 0; fr < 4; ++fr) {
    dst[fr][0] = *(const short8*)(paK0 + off + fr * 2048);
    dst[fr][1] = *(const short8*)(paK1 + off + fr * 2048);
  }
}
__device__ __forceinline__ void rdB2(short8 (&dst)[2][2], const char* pbK0,
                                     const char* pbK1, int off) {
#pragma unroll
  for (int gr = 0; gr < 2; ++gr) {
    dst[gr][0] = *(const short8*)(pbK0 + off + gr * 2048);
    dst[gr][1] = *(const short8*)(pbK1 + off + gr * 2048);
  }
}
template <int BPH>
__device__ __forceinline__ void mfmaq_f(const short8 (&afr)[4][2], const short8 (&bf)[2][2],
                                        f32x4 (*ac)[4]) {
  __builtin_amdgcn_s_setprio(1);
#pragma unroll
  for (int fi = 0; fi < 4; ++fi)
#pragma unroll
    for (int gj = 0; gj < 2; ++gj)
#pragma unroll
      for (int ks = 0; ks < 2; ++ks)
        ac[fi][BPH * 2 + gj] = __builtin_amdgcn_mfma_f32_16x16x32_bf16(
            afr[fi][ks], bf[gj][ks], ac[fi][BPH * 2 + gj], 0, 0, 0);
  __builtin_amdgcn_s_setprio(0);
}

template <int EPI, int BSEL>
__global__ __launch_bounds__(512, 2) void gemm8p(
    const unsigned short* __restrict__ A, int lda,
    const unsigned short* __restrict__ Bt, int ldb,
    unsigned short* __restrict__ C, int ldc,
    const float* __restrict__ bias,
    const float* __restrict__ residf,
    const unsigned short* __restrict__ residb, int ldr,
    int K, int NBX) {
  extern __shared__ char smb[];
  const int tid = threadIdx.x;
  const int lane = tid & 63, wid = tid >> 6;
  const int wm = wid >> 2, wn = wid & 3;

  int nwg = gridDim.x, orig = blockIdx.x;
  int wg = ((orig & 7) * (nwg >> 3)) + (orig >> 3);
  const long m0 = (long)(wg / NBX) * 256;
  const long n0 = (long)(wg % NBX) * 256;
  const unsigned short* bt = BSEL ? (Bt + (m0 >> 12) * 1048576) : Bt;

  const int NT = K >> 6, NI = NT >> 1;   // NT even for all our shapes

  const int lr = lane & 15, lc = (lane >> 4) * 16;
  const int eA = lc ^ ((lr & 7) << 4);
  const char* paK0 = smb + wm * 8192 + lr * 128 + eA;
  const char* paK1 = smb + wm * 8192 + lr * 128 + (eA ^ 64);
  const char* pbK0 = smb + 65536 + wn * 4096 + lr * 128 + eA;
  const char* pbK1 = smb + 65536 + wn * 4096 + lr * 128 + (eA ^ 64);

  short8 afr0[4][2], afr1[4][2];
  short8 bfr0[2][2], bfr1[2][2];
  f32x4 acc[8][4] = {};

  auto stA = [&](int buf, int ph, int kt) {
#pragma unroll
    for (int rnd = 0; rnd < 2; ++rnd) {
      int o = rnd * 8192 + tid * 16;
      int wms = o >> 13, rs = (o >> 7) & 63, cb = o & 127;
      int pcb = cb ^ ((rs & 7) << 4);
      const unsigned short* src = A + (m0 + wms * 128 + ph * 64 + rs) * (long)lda + kt * 64 + (pcb >> 1);
      gload16(src, (unsigned short*)(smb + buf * 32768 + ph * 16384 + o));
    }
  };
  auto stB = [&](int buf, int ph, int kt) {
#pragma unroll
    for (int rnd = 0; rnd < 2; ++rnd) {
      int o = rnd * 8192 + tid * 16;
      int wns = (o >> 12) & 3, rs = (o >> 7) & 31, cb = o & 127;
      int pcb = cb ^ ((rs & 7) << 4);
      const unsigned short* src = bt + (n0 + wns * 64 + ph * 32 + rs) * (long)ldb + kt * 64 + (pcb >> 1);
      gload16(src, (unsigned short*)(smb + 65536 + buf * 32768 + ph * 16384 + o));
    }
  };

  stA(0, 0, 0); stA(0, 1, 0); stB(0, 0, 0); stB(0, 1, 0);
  stA(1, 0, 1); stA(1, 1, 1); stB(1, 0, 1); stB(1, 1, 1);
  VMW(8);
  BARR;
  rdA2(afr0, paK0, paK1, 0);
  rdB2(bfr0, pbK0, pbK1, 0);

  for (int i = 0; i < NI; ++i) {
    int t2 = 2 * i + 2, t3 = 2 * i + 3;
    bool more = t2 < NT;
    // ---- tile 2i (buf0) ----
    LBARR;
    rdB2(bfr1, pbK0, pbK1, 16384);
    mfmaq_f<0>(afr0, bfr0, &acc[0]);
    LBARR;
    rdA2(afr1, paK0, paK1, 16384);
    mfmaq_f<1>(afr0, bfr1, &acc[0]);
    LBARR;
    if (more) { stA(0, 0, t2); stA(0, 1, t2); }
    mfmaq_f<0>(afr1, bfr0, &acc[4]);
    if (more) { VMW(4); } else { VMW(0); }
    LBARR;
    rdA2(afr0, paK0, paK1, 32768);
    rdB2(bfr0, pbK0, pbK1, 32768);
    if (more) { stB(0, 0, t2); stB(0, 1, t2); }
    mfmaq_f<1>(afr1, bfr1, &acc[4]);
    // ---- tile 2i+1 (buf1) ----
    LBARR;
    rdB2(bfr1, pbK0, pbK1, 32768 + 16384);
    mfmaq_f<0>(afr0, bfr0, &acc[0]);
    LBARR;
    rdA2(afr1, paK0, paK1, 32768 + 16384);
    mfmaq_f<1>(afr0, bfr1, &acc[0]);
    LBARR;
    if (more) { stA(1, 0, t3); stA(1, 1, t3); }
    mfmaq_f<0>(afr1, bfr0, &acc[4]);
    if (more) { VMW(4); } else { VMW(0); }
    LBARR;
    if (more) { rdA2(afr0, paK0, paK1, 0); rdB2(bfr0, pbK0, pbK1, 0); }
    if (more) { stB(1, 0, t3); stB(1, 1, t3); }
    mfmaq_f<1>(afr1, bfr1, &acc[4]);
  }

#pragma unroll
  for (int f = 0; f < 8; ++f) {
#pragma unroll
    for (int g = 0; g < 4; ++g) {
      long col = n0 + wn * 64 + g * 16 + (lane & 15);
      float bv = bias[col];
#pragma unroll
      for (int r = 0; r < 4; ++r) {
        long row = m0 + wm * 128 + f * 16 + (lane >> 4) * 4 + r;
        float o = acc[f][g][r] + bv;
        if (EPI == 1) o += residf[row * (long)ldr + col];
        if (EPI == 3) o += b2f(residb[row * (long)ldr + col]);
        C[row * (long)ldc + col] = f2b(o);
      }
    }
  }
}

// ---------------------------------------------------------------------------
// m97-structure GEMM for FF1 (N=128). EPI: 2 = tanh(+bias).
// ---------------------------------------------------------------------------
template <int EPI>
__global__ __launch_bounds__(256, 2) void gemm_bt(
    const unsigned short* __restrict__ A, int lda,
    const unsigned short* __restrict__ Bt, int ldb,
    unsigned short* __restrict__ C, int ldc,
    const float* __restrict__ bias, int K) {
  __shared__ __align__(16) unsigned short Asm[128 * 32];
  __shared__ __align__(16) unsigned short Bsm[128 * 32];
  const int tid = threadIdx.x;
  const int lane = tid & 63, wid = tid >> 6;
  const int wr = wid >> 1, wc = wid & 1;
  const long m0 = (long)blockIdx.y * 128;
  const long n0 = (long)blockIdx.x * 128;

  f32x4 acc[4][4] = {};

  for (int kk = 0; kk < K; kk += 32) {
    __syncthreads();
#pragma unroll
    for (int i = 0; i < 2; ++i) {
      int slot = i * 256 + tid;
      int r = slot >> 2, cg = (slot & 3) * 8;
      gload16(A + (m0 + r) * (long)lda + kk + cg, &Asm[slot * 8]);
      gload16(Bt + (n0 + r) * (long)ldb + kk + cg, &Bsm[slot * 8]);
    }
    __syncthreads();
    short8 af[4], bfr[4];
#pragma unroll
    for (int mt = 0; mt < 4; ++mt)
      af[mt] = *(const short8*)&Asm[(wr * 64 + mt * 16 + (lane & 15)) * 32 + (lane >> 4) * 8];
#pragma unroll
    for (int nt = 0; nt < 4; ++nt)
      bfr[nt] = *(const short8*)&Bsm[(wc * 64 + nt * 16 + (lane & 15)) * 32 + (lane >> 4) * 8];
#pragma unroll
    for (int mt = 0; mt < 4; ++mt)
#pragma unroll
      for (int nt = 0; nt < 4; ++nt)
        acc[mt][nt] = __builtin_amdgcn_mfma_f32_16x16x32_bf16(af[mt], bfr[nt], acc[mt][nt], 0, 0, 0);
  }

  const long row0 = m0 + wr * 64 + ((lane >> 4) * 4);
  const long col0 = n0 + wc * 64 + (lane & 15);
#pragma unroll
  for (int mt = 0; mt < 4; ++mt) {
#pragma unroll
    for (int nt = 0; nt < 4; ++nt) {
      long col = col0 + nt * 16;
      float bv = bias[col];
      f32x4 v = acc[mt][nt];
#pragma unroll
      for (int r = 0; r < 4; ++r) {
        long row = row0 + mt * 16 + r;
        float o = v[r] + bv;
        if (EPI == 2) o = tanhf(o);
        C[row * (long)ldc + col] = f2b(o);
      }
    }
  }
}

// ---------------------------------------------------------------------------
// scores via MFMA (verified rounds 5-7).
// ---------------------------------------------------------------------------
__device__ __forceinline__ int sperm(int e) { return ((e + (e >> 3)) & 7) << 4; }

__global__ __launch_bounds__(256) void scores_mfma(
    const unsigned short* __restrict__ QKV, float* __restrict__ part) {
  __shared__ __align__(16) char lds[32768];
  int bh = blockIdx.x, seg = blockIdx.y;
  int b = bh >> 4, h = bh & 15;
  int tid = threadIdx.x, lane = tid & 63, wid = tid >> 6;
  int e0 = (tid & 7) * 8;
  int sl0 = (tid >> 3) * 4;
  const unsigned short* Qg = QKV + h * 64;
  const unsigned short* Kg = QKV + 1024 + h * 64;
  f32x4 acc[4] = {};

  for (int ch = 0; ch < 8; ++ch) {
    long S0 = (long)b * 4096 + seg * 1024 + ch * 128;
    __syncthreads();
    short8 kv0 = *(const short8*)(Kg + (S0 + sl0 + 0) * 3072 + e0);
    short8 kv1 = *(const short8*)(Kg + (S0 + sl0 + 1) * 3072 + e0);
    short8 kv2 = *(const short8*)(Kg + (S0 + sl0 + 2) * 3072 + e0);
    short8 kv3 = *(const short8*)(Kg + (S0 + sl0 + 3) * 3072 + e0);
    short8 qv0 = *(const short8*)(Qg + (S0 + sl0 + 0) * 3072 + e0);
    short8 qv1 = *(const short8*)(Qg + (S0 + sl0 + 1) * 3072 + e0);
    short8 qv2 = *(const short8*)(Qg + (S0 + sl0 + 2) * 3072 + e0);
    short8 qv3 = *(const short8*)(Qg + (S0 + sl0 + 3) * 3072 + e0);
#pragma unroll
    for (int je = 0; je < 8; ++je) {
      int e = e0 + je;
      int sw = sperm(e);
      char* rowK = lds + e * 256;
      char* rowQ = lds + 16384 + e * 256;
      unsigned int klo = (unsigned short)kv0[je] | ((unsigned int)(unsigned short)kv1[je] << 16);
      unsigned int khi = (unsigned short)kv2[je] | ((unsigned int)(unsigned short)kv3[je] << 16);
      unsigned int qlo = (unsigned short)qv0[je] | ((unsigned int)(unsigned short)qv1[je] << 16);
      unsigned int qhi = (unsigned short)qv2[je] | ((unsigned int)(unsigned short)qv3[je] << 16);
      *(unsigned int*)(rowK + ((sl0 * 2) ^ sw)) = klo;
      *(unsigned int*)(rowK + ((sl0 * 2 + 4) ^ sw)) = khi;
      *(unsigned int*)(rowQ + ((sl0 * 2) ^ sw)) = qlo;
      *(unsigned int*)(rowQ + ((sl0 * 2 + 4) ^ sw)) = qhi;
    }
    __syncthreads();
#pragma unroll
    for (int ksi = 0; ksi < 4; ++ksi) {
      int colb = ksi * 64 + (lane >> 4) * 16;
      int erA = wid * 16 + (lane & 15);
      short8 af = *(const short8*)(lds + erA * 256 + (colb ^ sperm(erA)));
#pragma unroll
      for (int n = 0; n < 4; ++n) {
        int erB = n * 16 + (lane & 15);
        short8 bf = *(const short8*)(lds + 16384 + erB * 256 + (colb ^ sperm(erB)));
        acc[n] = __builtin_amdgcn_mfma_f32_16x16x32_bf16(af, bf, acc[n], 0, 0, 0);
      }
    }
  }
  float* dst = part + ((long)bh * 4 + seg) * 4096;
#pragma unroll
  for (int n = 0; n < 4; ++n)
#pragma unroll
    for (int r = 0; r < 4; ++r) {
      int k = wid * 16 + (lane >> 4) * 4 + r;
      int q = n * 16 + (lane & 15);
      dst[k * 64 + q] = acc[n][r];
    }
}

// softmax over k (per q column), scores/8; writes w row-major: Wb[bh][k][q]
__global__ __launch_bounds__(64) void softmax_Wb(
    const float* __restrict__ part, const int* __restrict__ mask,
    unsigned short* __restrict__ Wb) {
  __shared__ float lt[64][65];
  int bh = blockIdx.x, q = threadIdx.x;
  int b = bh >> 4;
  const float* p0 = part + (long)bh * 4 * 4096;
  float s[64];
#pragma unroll
  for (int k = 0; k < 64; ++k)
    s[k] = p0[k * 64 + q] + p0[4096 + k * 64 + q] + p0[8192 + k * 64 + q] + p0[12288 + k * 64 + q];
  bool live = (mask[b * 64 + q] != 0);
  float m = -1e30f;
#pragma unroll
  for (int k = 0; k < 64; ++k) m = fmaxf(m, s[k]);
  float sum = 0.0f;
#pragma unroll
  for (int k = 0; k < 64; ++k) {
    s[k] = __expf((s[k] - m) * 0.125f);
    sum += s[k];
  }
  float inv = live ? 1.0f / sum : 0.0f;
#pragma unroll
  for (int k = 0; k < 64; ++k) lt[k][q] = s[k] * inv;
  __syncthreads();
  unsigned short* o = Wb + (long)bh * 4096 + q * 64;   // thread q writes row k=q
#pragma unroll
  for (int j8 = 0; j8 < 8; ++j8) {
    short8 ov;
#pragma unroll
    for (int j = 0; j < 8; ++j) ov[j] = (short)f2b(lt[q][j8 * 8 + j]);
    *(short8*)(o + j8 * 8) = ov;
  }
}

// WPT[b][d][h*64+k] = sum_q Wo[h*64+q][d] * w_bh[k][q]
__global__ __launch_bounds__(256) void wpt_kernel(
    const unsigned short* __restrict__ WoT, const unsigned short* __restrict__ Wb,
    unsigned short* __restrict__ WPT) {
  int dblk = blockIdx.x;   // 4
  int h = blockIdx.y;      // 16
  int b = blockIdx.z;      // 8
  int tid = threadIdx.x, lane = tid & 63, wid = tid >> 6;
  int d0 = dblk * 256 + wid * 64;
  const unsigned short* wb = Wb + (long)(b * 16 + h) * 4096;
  f32x4 acc[4][4] = {};
#pragma unroll
  for (int ks = 0; ks < 2; ++ks) {
    short8 bf[4];
#pragma unroll
    for (int nt = 0; nt < 4; ++nt)
      bf[nt] = *(const short8*)(wb + (nt * 16 + (lane & 15)) * 64 + ks * 32 + (lane >> 4) * 8);
#pragma unroll
    for (int mt = 0; mt < 4; ++mt) {
      short8 af = *(const short8*)(WoT + (long)(d0 + mt * 16 + (lane & 15)) * 1024 + h * 64 + ks * 32 + (lane >> 4) * 8);
#pragma unroll
      for (int nt = 0; nt < 4; ++nt)
        acc[mt][nt] = __builtin_amdgcn_mfma_f32_16x16x32_bf16(af, bf[nt], acc[mt][nt], 0, 0, 0);
    }
  }
#pragma unroll
  for (int mt = 0; mt < 4; ++mt)
#pragma unroll
    for (int nt = 0; nt < 4; ++nt)
#pragma unroll
      for (int r = 0; r < 4; ++r) {
        long row = d0 + mt * 16 + (lane >> 4) * 4 + r;
        int col = h * 64 + nt * 16 + (lane & 15);
        WPT[(long)b * 1048576 + row * 1024 + col] = f2b(acc[mt][nt][r]);
      }
}

// rmsnorm over D=1024; one block per row. bf16 in; bf16 or f32 out.
template <int OUTF>
__global__ __launch_bounds__(256) void rmsnorm_k(
    const unsigned short* __restrict__ in, const float* __restrict__ g,
    unsigned short* __restrict__ outb, float* __restrict__ outf) {
  long row = blockIdx.x;
  int tid = threadIdx.x;
  short4v u = *(const short4v*)(in + row * 1024 + tid * 4);
  float v[4];
  float ss = 0.0f;
#pragma unroll
  for (int i = 0; i < 4; ++i) {
    v[i] = b2f((unsigned short)u[i]);
    ss += v[i] * v[i];
  }
#pragma unroll
  for (int off = 32; off > 0; off >>= 1) ss += __shfl_xor(ss, off, 64);
  __shared__ float wsum[4];
  if ((tid & 63) == 0) wsum[tid >> 6] = ss;
  __syncthreads();
  float tot = wsum[0] + wsum[1] + wsum[2] + wsum[3];
  float rs = rsqrtf(tot * (1.0f / 1024.0f) + 1e-6f);
  f32x4 gv = *(const f32x4*)(g + tid * 4);
  if (OUTF) {
    f32x4 ov;
#pragma unroll
    for (int i = 0; i < 4; ++i) ov[i] = v[i] * rs * gv[i];
    *(f32x4*)(outf + row * 1024 + tid * 4) = ov;
  } else {
    short4v ov;
#pragma unroll
    for (int i = 0; i < 4; ++i) ov[i] = (short)f2b(v[i] * rs * gv[i]);
    *(short4v*)(outb + row * 1024 + tid * 4) = ov;
  }
}

// ---------------------------------------------------------------------------
extern "C" void kernel_launch(void* const* d_in, const int* in_sizes, int n_in,
                              void* d_out, int out_size, void* d_ws, size_t ws_size,
                              hipStream_t stream) {
  const float* x  = (const float*)d_in[0];
  const int* mask = (const int*)d_in[1];
  const float* Wq = (const float*)d_in[2];
  const float* bq = (const float*)d_in[3];
  const float* Wk = (const float*)d_in[4];
  const float* bk = (const float*)d_in[5];
  const float* Wv = (const float*)d_in[6];
  const float* bv = (const float*)d_in[7];
  const float* Wo = (const float*)d_in[8];
  const float* bo = (const float*)d_in[9];
  const float* W1 = (const float*)d_in[10];
  const float* b1 = (const float*)d_in[11];
  const float* W2 = (const float*)d_in[12];
  const float* b2 = (const float*)d_in[13];
  const float* g1 = (const float*)d_in[14];
  const float* g2 = (const float*)d_in[15];

  char* ws = (char*)d_ws;
  size_t off = 0;
  auto alc = [&](size_t n) { size_t o = off; off += (n + 255) & ~(size_t)255; return o; };
  unsigned short* BqkvT = (unsigned short*)(ws + alc(3072UL * 1024 * 2));
  unsigned short* WoT   = (unsigned short*)(ws + alc(1024UL * 1024 * 2));
  unsigned short* W1T   = (unsigned short*)(ws + alc(128UL * 1024 * 2));
  unsigned short* W2T   = (unsigned short*)(ws + alc(1024UL * 128 * 2));
  float*          bqkv  = (float*)(ws + alc(3072UL * 4));
  unsigned short* R0    = (unsigned short*)(ws + alc(32768UL * 1024 * 2));  // xb -> WPT -> hf
  unsigned short* R1    = (unsigned short*)(ws + alc(32768UL * 3072 * 2));  // QKV -> h2
  unsigned short* R2    = (unsigned short*)(ws + alc(32768UL * 1024 * 2));  // h1
  unsigned short* Tb    = (unsigned short*)(ws + alc(32768UL * 128 * 2));
  float*          SP    = (float*)(ws + alc(512UL * 4096 * 4));
  unsigned short* Wbuf  = (unsigned short*)(ws + alc(128UL * 4096 * 2));
  if (ws_size < off) return;

  // Dataflow (no producer writes a region its consumer-set still reads):
  //   prep:      -> xb(R0)
  //   QKV GEMM:  xb(R0) -> QKV(R1)
  //   scores:    QKV(R1) -> SP ; softmax: SP -> Wbuf
  //   wpt:       WoT,Wbuf -> WPT(R0)          [xb dead]
  //   V GEMM:    V(R1), WPT(R0), x -> h1(R2)  [C disjoint from A,B — the fix]
  //   rms1:      h1(R2) -> h2(R1)             [QKV dead]
  //   FF1:       h2(R1) -> t(Tb)
  //   FF2:       t(Tb), h2(R1) -> hf(R0)      [WPT dead]
  //   rms2:      hf(R0) -> out
  unsigned short* xb   = R0;
  unsigned short* WPT  = R0;
  unsigned short* HFb  = R0;
  unsigned short* QKVb = R1;
  unsigned short* H2b  = R1;
  unsigned short* H1b  = R2;
  float* outp = (float*)d_out;

  prep_kernel<<<17473, 256, 0, stream>>>(x, xb, Wq, Wk, Wv, Wo, W1, W2, bq, bk, bv,
                                         BqkvT, WoT, W1T, W2T, bqkv);
  // QKV = xb @ [Wq|Wk|Wv]^T + b
  gemm8p<0, 0><<<1536, 512, 131072, stream>>>(xb, 1024, BqkvT, 1024, QKVb, 3072,
                                              bqkv, nullptr, nullptr, 0, 1024, 12);
  scores_mfma<<<dim3(128, 4), 256, 0, stream>>>(QKVb, SP);
  softmax_Wb<<<128, 64, 0, stream>>>(SP, mask, Wbuf);
  wpt_kernel<<<dim3(4, 16, 8), 256, 0, stream>>>(WoT, Wbuf, WPT);
  // h1 = x + V @ WPT_b + bo   (V from R1; C into R2 — disjoint)
  gemm8p<1, 1><<<512, 512, 131072, stream>>>(QKVb + 2048, 3072, WPT, 1024, H1b, 1024,
                                             bo, x, nullptr, 1024, 1024, 4);
  // h2 = rmsnorm(h1, g1) -> R1 (QKV dead)
  rmsnorm_k<0><<<32768, 256, 0, stream>>>(H1b, g1, H2b, nullptr);
  // t = tanh(h2@W1T + b1)
  gemm_bt<2><<<dim3(1, 256), 256, 0, stream>>>(H2b, 1024, W1T, 1024, Tb, 128, b1, 1024);
  // hf = t@W2T + b2 + h2 -> R0 (WPT dead)
  gemm8p<3, 0><<<512, 512, 131072, stream>>>(Tb, 128, W2T, 128, HFb, 1024,
                                             b2, nullptr, H2b, 1024, 128, 4);
  rmsnorm_k<1><<<32768, 256, 0, stream>>>(HFb, g2, nullptr, outp);
}

// Round 9
// 508.651 us; speedup vs baseline: 1.4138x; 1.0495x over previous
//
#include <hip/hip_runtime.h>
#include <math.h>

typedef __attribute__((ext_vector_type(4))) float f32x4;
typedef __attribute__((ext_vector_type(8))) short short8;   // 8 bf16 raw bits
typedef __attribute__((ext_vector_type(4))) short short4v;  // 4 bf16 raw bits

__device__ __forceinline__ float b2f(unsigned short u) {
  unsigned int x = ((unsigned int)u) << 16;
  return __builtin_bit_cast(float, x);
}
__device__ __forceinline__ unsigned short f2b(float f) {
  unsigned int x = __builtin_bit_cast(unsigned int, f);
  x += 0x7fffu + ((x >> 16) & 1u);   // round-to-nearest-even
  return (unsigned short)(x >> 16);
}

// async global->LDS, 16B per lane. LDS dest must be lane-contiguous (wave base + lane*16).
__device__ __forceinline__ void gload16(const unsigned short* g, unsigned short* l) {
  __builtin_amdgcn_global_load_lds(
      (__attribute__((address_space(1))) void*)(unsigned long long)(const void*)g,
      (__attribute__((address_space(3))) void*)l, 16, 0, 0);
}

#define BARR  { __builtin_amdgcn_sched_barrier(0); __builtin_amdgcn_s_barrier(); __builtin_amdgcn_sched_barrier(0); }
// phase-entry barrier: drain this wave's LDS reads, then sync.
#define LBARR { __builtin_amdgcn_sched_barrier(0); asm volatile("s_waitcnt lgkmcnt(0)" ::: "memory"); __builtin_amdgcn_s_barrier(); __builtin_amdgcn_sched_barrier(0); }
// CROSS-WAVE RULE: vmcnt gate protecting a cooperatively-staged LDS buffer sits
// BEFORE the barrier preceding the reads. BUFFER RULE (round-6/7 lesson): a
// GEMM's C region must be disjoint from its A, B, and residual regions.
#define VMW(n) { __builtin_amdgcn_sched_barrier(0); asm volatile("s_waitcnt vmcnt(" #n ")" ::: "memory"); __builtin_amdgcn_sched_barrier(0); }

// ---------------------------------------------------------------------------
// prep_kernel: x->bf16 convert + all weight repacks (64x64 LDS-transpose,
// +1 pad) + QKV bias concat. W1 gets g1 folded in: W1g[f][d] = W1[d][f]*g1[d].
// Grid: [0,16384) cvt ; [16384,16384+1089).
// ---------------------------------------------------------------------------
__global__ __launch_bounds__(256) void prep_kernel(
    const float* __restrict__ x, unsigned short* __restrict__ xb,
    const float* __restrict__ Wq, const float* __restrict__ Wk,
    const float* __restrict__ Wv, const float* __restrict__ Wo,
    const float* __restrict__ W1, const float* __restrict__ W2,
    const float* __restrict__ bq, const float* __restrict__ bk, const float* __restrict__ bv,
    const float* __restrict__ g1,
    unsigned short* __restrict__ BqkvT, unsigned short* __restrict__ WoT,
    unsigned short* __restrict__ W1T, unsigned short* __restrict__ W2T,
    float* __restrict__ bqkv) {
  __shared__ float tile[64][65];
  int nb = blockIdx.x, t = threadIdx.x;
  if (nb < 16384) {
    long i = (long)nb * 256 + t;
    f32x4 a = ((const f32x4*)x)[i * 2];
    f32x4 b = ((const f32x4*)x)[i * 2 + 1];
    short8 o;
#pragma unroll
    for (int j = 0; j < 4; ++j) { o[j] = (short)f2b(a[j]); o[4 + j] = (short)f2b(b[j]); }
    ((short8*)xb)[i] = o;
    return;
  }
  int n0 = nb - 16384;
  if (n0 == 1088) {
#pragma unroll
    for (int it = 0; it < 12; ++it) {
      int idx = it * 256 + t;
      float v = (idx < 1024) ? bq[idx] : (idx < 2048 ? bk[idx - 1024] : bv[idx - 2048]);
      bqkv[idx] = v;
    }
    return;
  }
  const float* src; unsigned short* dst; int sld, dld;
  bool foldg = false; int dbase = 0;
  if (n0 < 768) {
    int w = n0 >> 8, rem = n0 & 255, h = rem >> 4, dc = rem & 15;
    const float* W = (w == 0) ? Wq : (w == 1 ? Wk : Wv);
    src = W + ((long)h * 1024 + dc * 64) * 64;                 sld = 64;
    dst = BqkvT + (long)(w * 1024 + h * 64) * 1024 + dc * 64;  dld = 1024;
  } else if (n0 < 1024) {
    int rem = n0 - 768, dr = rem >> 4, jc = rem & 15;
    src = Wo + (long)dr * 64 * 1024 + jc * 64;                 sld = 1024;
    dst = WoT + (long)jc * 64 * 1024 + dr * 64;                dld = 1024;
  } else if (n0 < 1056) {
    int rem = n0 - 1024, dr = rem >> 1, fc = rem & 1;
    src = W1 + (long)dr * 64 * 128 + fc * 64;                  sld = 128;
    dst = W1T + (long)fc * 64 * 1024 + dr * 64;                dld = 1024;
    foldg = true; dbase = dr * 64;                              // d = dbase + col
  } else {
    int rem = n0 - 1056, fr = rem >> 4, jc = rem & 15;
    src = W2 + (long)fr * 64 * 1024 + jc * 64;                 sld = 1024;
    dst = W2T + (long)jc * 64 * 128 + fr * 64;                 dld = 128;
  }
  int r = t >> 2, c0 = (t & 3) * 16;
#pragma unroll
  for (int j4 = 0; j4 < 4; ++j4) {
    f32x4 v = *(const f32x4*)(src + (long)r * sld + c0 + j4 * 4);
    tile[c0 + j4 * 4 + 0][r] = v[0];
    tile[c0 + j4 * 4 + 1][r] = v[1];
    tile[c0 + j4 * 4 + 2][r] = v[2];
    tile[c0 + j4 * 4 + 3][r] = v[3];
  }
  __syncthreads();
  short8 o0, o1;
#pragma unroll
  for (int j = 0; j < 8; ++j) {
    float v0 = tile[r][c0 + j], v1 = tile[r][c0 + 8 + j];
    if (foldg) { v0 *= g1[dbase + c0 + j]; v1 *= g1[dbase + c0 + 8 + j]; }
    o0[j] = (short)f2b(v0);
    o1[j] = (short)f2b(v1);
  }
  *(short8*)(dst + (long)r * dld + c0) = o0;
  *(short8*)(dst + (long)r * dld + c0 + 8) = o1;
}

// ---------------------------------------------------------------------------
// 256x256 bf16 GEMM v2.2: v2.1 schedule (verified round 8) + L2-friendly
// 4xNBX inner tile in the per-XCD chunk. Requires M == 32768 (128 m-blocks,
// 16 per XCD) and gridDim.x == 128*NBX.
// EPI: 0 = +bias ; 1 = +bias + f32 resid ; 3 = +bias + bf16 resid ;
//      5 = +bias + h1*rs*g1 resid (h2-free FF2).
// BSEL: 1 = per-batch B (Bt += (m0>>12)*1M).
// ---------------------------------------------------------------------------
__device__ __forceinline__ void rdA2(short8 (&dst)[4][2], const char* paK0,
                                     const char* paK1, int off) {
#pragma unroll
  for (int fr = 0; fr < 4; ++fr) {
    dst[fr][0] = *(const short8*)(paK0 + off + fr * 2048);
    dst[fr][1] = *(const short8*)(paK1 + off + fr * 2048);
  }
}
__device__ __forceinline__ void rdB2(short8 (&dst)[2][2], const char* pbK0,
                                     const char* pbK1, int off) {
#pragma unroll
  for (int gr = 0; gr < 2; ++gr) {
    dst[gr][0] = *(const short8*)(pbK0 + off + gr * 2048);
    dst[gr][1] = *(const short8*)(pbK1 + off + gr * 2048);
  }
}
template <int BPH>
__device__ __forceinline__ void mfmaq_f(const short8 (&afr)[4][2], const short8 (&bf)[2][2],
                                        f32x4 (*ac)[4]) {
  __builtin_amdgcn_s_setprio(1);
#pragma unroll
  for (int fi = 0; fi < 4; ++fi)
#pragma unroll
    for (int gj = 0; gj < 2; ++gj)
#pragma unroll
      for (int ks = 0; ks < 2; ++ks)
        ac[fi][BPH * 2 + gj] = __builtin_amdgcn_mfma_f32_16x16x32_bf16(
            afr[fi][ks], bf[gj][ks], ac[fi][BPH * 2 + gj], 0, 0, 0);
  __builtin_amdgcn_s_setprio(0);
}

template <int EPI, int BSEL>
__global__ __launch_bounds__(512, 2) void gemm8p(
    const unsigned short* __restrict__ A, int lda,
    const unsigned short* __restrict__ Bt, int ldb,
    unsigned short* __restrict__ C, int ldc,
    const float* __restrict__ bias,
    const float* __restrict__ residf,
    const unsigned short* __restrict__ residb, int ldr,
    const float* __restrict__ rs, const float* __restrict__ g1f,
    int K, int NBX) {
  extern __shared__ char smb[];
  const int tid = threadIdx.x;
  const int lane = tid & 63, wid = tid >> 6;
  const int wm = wid >> 2, wn = wid & 3;

  // XCD chunking: xcd gets contiguous j-range; inner 4xNBX tile so ~4 A-tiles
  // and <=NBX B-tiles are concurrently hot per XCD L2.
  int orig = blockIdx.x;
  int xcd = orig & 7, j = orig >> 3;
  int ms = j / (4 * NBX), nb = (j >> 2) % NBX, mq = j & 3;
  const long m0 = (long)(xcd * 16 + ms * 4 + mq) * 256;
  const long n0 = (long)nb * 256;
  const unsigned short* bt = BSEL ? (Bt + (m0 >> 12) * 1048576) : Bt;

  const int NT = K >> 6, NI = NT >> 1;   // NT even for all our shapes

  const int lr = lane & 15, lc = (lane >> 4) * 16;
  const int eA = lc ^ ((lr & 7) << 4);
  const char* paK0 = smb + wm * 8192 + lr * 128 + eA;
  const char* paK1 = smb + wm * 8192 + lr * 128 + (eA ^ 64);
  const char* pbK0 = smb + 65536 + wn * 4096 + lr * 128 + eA;
  const char* pbK1 = smb + 65536 + wn * 4096 + lr * 128 + (eA ^ 64);

  short8 afr0[4][2], afr1[4][2];
  short8 bfr0[2][2], bfr1[2][2];
  f32x4 acc[8][4] = {};

  auto stA = [&](int buf, int ph, int kt) {
#pragma unroll
    for (int rnd = 0; rnd < 2; ++rnd) {
      int o = rnd * 8192 + tid * 16;
      int wms = o >> 13, rsw = (o >> 7) & 63, cb = o & 127;
      int pcb = cb ^ ((rsw & 7) << 4);
      const unsigned short* src = A + (m0 + wms * 128 + ph * 64 + rsw) * (long)lda + kt * 64 + (pcb >> 1);
      gload16(src, (unsigned short*)(smb + buf * 32768 + ph * 16384 + o));
    }
  };
  auto stB = [&](int buf, int ph, int kt) {
#pragma unroll
    for (int rnd = 0; rnd < 2; ++rnd) {
      int o = rnd * 8192 + tid * 16;
      int wns = (o >> 12) & 3, rsw = (o >> 7) & 31, cb = o & 127;
      int pcb = cb ^ ((rsw & 7) << 4);
      const unsigned short* src = bt + (n0 + wns * 64 + ph * 32 + rsw) * (long)ldb + kt * 64 + (pcb >> 1);
      gload16(src, (unsigned short*)(smb + 65536 + buf * 32768 + ph * 16384 + o));
    }
  };

  stA(0, 0, 0); stA(0, 1, 0); stB(0, 0, 0); stB(0, 1, 0);
  stA(1, 0, 1); stA(1, 1, 1); stB(1, 0, 1); stB(1, 1, 1);
  VMW(8);
  BARR;
  rdA2(afr0, paK0, paK1, 0);
  rdB2(bfr0, pbK0, pbK1, 0);

  for (int i = 0; i < NI; ++i) {
    int t2 = 2 * i + 2, t3 = 2 * i + 3;
    bool more = t2 < NT;
    // ---- tile 2i (buf0) ----
    LBARR;
    rdB2(bfr1, pbK0, pbK1, 16384);
    mfmaq_f<0>(afr0, bfr0, &acc[0]);
    LBARR;
    rdA2(afr1, paK0, paK1, 16384);
    mfmaq_f<1>(afr0, bfr1, &acc[0]);
    LBARR;
    if (more) { stA(0, 0, t2); stA(0, 1, t2); }
    mfmaq_f<0>(afr1, bfr0, &acc[4]);
    if (more) { VMW(4); } else { VMW(0); }
    LBARR;
    rdA2(afr0, paK0, paK1, 32768);
    rdB2(bfr0, pbK0, pbK1, 32768);
    if (more) { stB(0, 0, t2); stB(0, 1, t2); }
    mfmaq_f<1>(afr1, bfr1, &acc[4]);
    // ---- tile 2i+1 (buf1) ----
    LBARR;
    rdB2(bfr1, pbK0, pbK1, 32768 + 16384);
    mfmaq_f<0>(afr0, bfr0, &acc[0]);
    LBARR;
    rdA2(afr1, paK0, paK1, 32768 + 16384);
    mfmaq_f<1>(afr0, bfr1, &acc[0]);
    LBARR;
    if (more) { stA(1, 0, t3); stA(1, 1, t3); }
    mfmaq_f<0>(afr1, bfr0, &acc[4]);
    if (more) { VMW(4); } else { VMW(0); }
    LBARR;
    if (more) { rdA2(afr0, paK0, paK1, 0); rdB2(bfr0, pbK0, pbK1, 0); }
    if (more) { stB(1, 0, t3); stB(1, 1, t3); }
    mfmaq_f<1>(afr1, bfr1, &acc[4]);
  }

#pragma unroll
  for (int f = 0; f < 8; ++f) {
#pragma unroll
    for (int g = 0; g < 4; ++g) {
      long col = n0 + wn * 64 + g * 16 + (lane & 15);
      float bv = bias[col];
      float gv = (EPI == 5) ? g1f[col] : 0.0f;
#pragma unroll
      for (int r = 0; r < 4; ++r) {
        long row = m0 + wm * 128 + f * 16 + (lane >> 4) * 4 + r;
        float o = acc[f][g][r] + bv;
        if (EPI == 1) o += residf[row * (long)ldr + col];
        if (EPI == 3) o += b2f(residb[row * (long)ldr + col]);
        if (EPI == 5) o += b2f(residb[row * (long)ldr + col]) * rs[row] * gv;
        C[row * (long)ldc + col] = f2b(o);
      }
    }
  }
}

// ---------------------------------------------------------------------------
// m97-structure GEMM for FF1 (N=128). EPI 4: o = tanh(rs[row]*acc + bias).
// ---------------------------------------------------------------------------
template <int EPI>
__global__ __launch_bounds__(256, 2) void gemm_bt(
    const unsigned short* __restrict__ A, int lda,
    const unsigned short* __restrict__ Bt, int ldb,
    unsigned short* __restrict__ C, int ldc,
    const float* __restrict__ bias, const float* __restrict__ rs, int K) {
  __shared__ __align__(16) unsigned short Asm[128 * 32];
  __shared__ __align__(16) unsigned short Bsm[128 * 32];
  const int tid = threadIdx.x;
  const int lane = tid & 63, wid = tid >> 6;
  const int wr = wid >> 1, wc = wid & 1;
  const long m0 = (long)blockIdx.y * 128;
  const long n0 = (long)blockIdx.x * 128;

  f32x4 acc[4][4] = {};

  for (int kk = 0; kk < K; kk += 32) {
    __syncthreads();
#pragma unroll
    for (int i = 0; i < 2; ++i) {
      int slot = i * 256 + tid;
      int r = slot >> 2, cg = (slot & 3) * 8;
      gload16(A + (m0 + r) * (long)lda + kk + cg, &Asm[slot * 8]);
      gload16(Bt + (n0 + r) * (long)ldb + kk + cg, &Bsm[slot * 8]);
    }
    __syncthreads();
    short8 af[4], bfr[4];
#pragma unroll
    for (int mt = 0; mt < 4; ++mt)
      af[mt] = *(const short8*)&Asm[(wr * 64 + mt * 16 + (lane & 15)) * 32 + (lane >> 4) * 8];
#pragma unroll
    for (int nt = 0; nt < 4; ++nt)
      bfr[nt] = *(const short8*)&Bsm[(wc * 64 + nt * 16 + (lane & 15)) * 32 + (lane >> 4) * 8];
#pragma unroll
    for (int mt = 0; mt < 4; ++mt)
#pragma unroll
      for (int nt = 0; nt < 4; ++nt)
        acc[mt][nt] = __builtin_amdgcn_mfma_f32_16x16x32_bf16(af[mt], bfr[nt], acc[mt][nt], 0, 0, 0);
  }

  const long row0 = m0 + wr * 64 + ((lane >> 4) * 4);
  const long col0 = n0 + wc * 64 + (lane & 15);
#pragma unroll
  for (int mt = 0; mt < 4; ++mt) {
#pragma unroll
    for (int nt = 0; nt < 4; ++nt) {
      long col = col0 + nt * 16;
      float bv = bias[col];
      f32x4 v = acc[mt][nt];
#pragma unroll
      for (int r = 0; r < 4; ++r) {
        long row = row0 + mt * 16 + r;
        float o = v[r];
        if (EPI == 4) o = tanhf(o * rs[row] + bv);
        else o += bv;
        C[row * (long)ldc + col] = f2b(o);
      }
    }
  }
}

// ---------------------------------------------------------------------------
// scores via MFMA (verified rounds 5-8).
// ---------------------------------------------------------------------------
__device__ __forceinline__ int sperm(int e) { return ((e + (e >> 3)) & 7) << 4; }

__global__ __launch_bounds__(256) void scores_mfma(
    const unsigned short* __restrict__ QKV, float* __restrict__ part) {
  __shared__ __align__(16) char lds[32768];
  int bh = blockIdx.x, seg = blockIdx.y;
  int b = bh >> 4, h = bh & 15;
  int tid = threadIdx.x, lane = tid & 63, wid = tid >> 6;
  int e0 = (tid & 7) * 8;
  int sl0 = (tid >> 3) * 4;
  const unsigned short* Qg = QKV + h * 64;
  const unsigned short* Kg = QKV + 1024 + h * 64;
  f32x4 acc[4] = {};

  for (int ch = 0; ch < 8; ++ch) {
    long S0 = (long)b * 4096 + seg * 1024 + ch * 128;
    __syncthreads();
    short8 kv0 = *(const short8*)(Kg + (S0 + sl0 + 0) * 3072 + e0);
    short8 kv1 = *(const short8*)(Kg + (S0 + sl0 + 1) * 3072 + e0);
    short8 kv2 = *(const short8*)(Kg + (S0 + sl0 + 2) * 3072 + e0);
    short8 kv3 = *(const short8*)(Kg + (S0 + sl0 + 3) * 3072 + e0);
    short8 qv0 = *(const short8*)(Qg + (S0 + sl0 + 0) * 3072 + e0);
    short8 qv1 = *(const short8*)(Qg + (S0 + sl0 + 1) * 3072 + e0);
    short8 qv2 = *(const short8*)(Qg + (S0 + sl0 + 2) * 3072 + e0);
    short8 qv3 = *(const short8*)(Qg + (S0 + sl0 + 3) * 3072 + e0);
#pragma unroll
    for (int je = 0; je < 8; ++je) {
      int e = e0 + je;
      int sw = sperm(e);
      char* rowK = lds + e * 256;
      char* rowQ = lds + 16384 + e * 256;
      unsigned int klo = (unsigned short)kv0[je] | ((unsigned int)(unsigned short)kv1[je] << 16);
      unsigned int khi = (unsigned short)kv2[je] | ((unsigned int)(unsigned short)kv3[je] << 16);
      unsigned int qlo = (unsigned short)qv0[je] | ((unsigned int)(unsigned short)qv1[je] << 16);
      unsigned int qhi = (unsigned short)qv2[je] | ((unsigned int)(unsigned short)qv3[je] << 16);
      *(unsigned int*)(rowK + ((sl0 * 2) ^ sw)) = klo;
      *(unsigned int*)(rowK + ((sl0 * 2 + 4) ^ sw)) = khi;
      *(unsigned int*)(rowQ + ((sl0 * 2) ^ sw)) = qlo;
      *(unsigned int*)(rowQ + ((sl0 * 2 + 4) ^ sw)) = qhi;
    }
    __syncthreads();
#pragma unroll
    for (int ksi = 0; ksi < 4; ++ksi) {
      int colb = ksi * 64 + (lane >> 4) * 16;
      int erA = wid * 16 + (lane & 15);
      short8 af = *(const short8*)(lds + erA * 256 + (colb ^ sperm(erA)));
#pragma unroll
      for (int n = 0; n < 4; ++n) {
        int erB = n * 16 + (lane & 15);
        short8 bf = *(const short8*)(lds + 16384 + erB * 256 + (colb ^ sperm(erB)));
        acc[n] = __builtin_amdgcn_mfma_f32_16x16x32_bf16(af, bf, acc[n], 0, 0, 0);
      }
    }
  }
  float* dst = part + ((long)bh * 4 + seg) * 4096;
#pragma unroll
  for (int n = 0; n < 4; ++n)
#pragma unroll
    for (int r = 0; r < 4; ++r) {
      int k = wid * 16 + (lane >> 4) * 4 + r;
      int q = n * 16 + (lane & 15);
      dst[k * 64 + q] = acc[n][r];
    }
}

// softmax over k (per q column), scores/8; writes w row-major: Wb[bh][k][q]
__global__ __launch_bounds__(64) void softmax_Wb(
    const float* __restrict__ part, const int* __restrict__ mask,
    unsigned short* __restrict__ Wb) {
  __shared__ float lt[64][65];
  int bh = blockIdx.x, q = threadIdx.x;
  int b = bh >> 4;
  const float* p0 = part + (long)bh * 4 * 4096;
  float s[64];
#pragma unroll
  for (int k = 0; k < 64; ++k)
    s[k] = p0[k * 64 + q] + p0[4096 + k * 64 + q] + p0[8192 + k * 64 + q] + p0[12288 + k * 64 + q];
  bool live = (mask[b * 64 + q] != 0);
  float m = -1e30f;
#pragma unroll
  for (int k = 0; k < 64; ++k) m = fmaxf(m, s[k]);
  float sum = 0.0f;
#pragma unroll
  for (int k = 0; k < 64; ++k) {
    s[k] = __expf((s[k] - m) * 0.125f);
    sum += s[k];
  }
  float inv = live ? 1.0f / sum : 0.0f;
#pragma unroll
  for (int k = 0; k < 64; ++k) lt[k][q] = s[k] * inv;
  __syncthreads();
  unsigned short* o = Wb + (long)bh * 4096 + q * 64;   // thread q writes row k=q
#pragma unroll
  for (int j8 = 0; j8 < 8; ++j8) {
    short8 ov;
#pragma unroll
    for (int j = 0; j < 8; ++j) ov[j] = (short)f2b(lt[q][j8 * 8 + j]);
    *(short8*)(o + j8 * 8) = ov;
  }
}

// WPT[b][d][h*64+k] = sum_q Wo[h*64+q][d] * w_bh[k][q]
__global__ __launch_bounds__(256) void wpt_kernel(
    const unsigned short* __restrict__ WoT, const unsigned short* __restrict__ Wb,
    unsigned short* __restrict__ WPT) {
  int dblk = blockIdx.x;   // 4
  int h = blockIdx.y;      // 16
  int b = blockIdx.z;      // 8
  int tid = threadIdx.x, lane = tid & 63, wid = tid >> 6;
  int d0 = dblk * 256 + wid * 64;
  const unsigned short* wb = Wb + (long)(b * 16 + h) * 4096;
  f32x4 acc[4][4] = {};
#pragma unroll
  for (int ks = 0; ks < 2; ++ks) {
    short8 bf[4];
#pragma unroll
    for (int nt = 0; nt < 4; ++nt)
      bf[nt] = *(const short8*)(wb + (nt * 16 + (lane & 15)) * 64 + ks * 32 + (lane >> 4) * 8);
#pragma unroll
    for (int mt = 0; mt < 4; ++mt) {
      short8 af = *(const short8*)(WoT + (long)(d0 + mt * 16 + (lane & 15)) * 1024 + h * 64 + ks * 32 + (lane >> 4) * 8);
#pragma unroll
      for (int nt = 0; nt < 4; ++nt)
        acc[mt][nt] = __builtin_amdgcn_mfma_f32_16x16x32_bf16(af, bf[nt], acc[mt][nt], 0, 0, 0);
    }
  }
#pragma unroll
  for (int mt = 0; mt < 4; ++mt)
#pragma unroll
    for (int nt = 0; nt < 4; ++nt)
#pragma unroll
      for (int r = 0; r < 4; ++r) {
        long row = d0 + mt * 16 + (lane >> 4) * 4 + r;
        int col = h * 64 + nt * 16 + (lane & 15);
        WPT[(long)b * 1048576 + row * 1024 + col] = f2b(acc[mt][nt][r]);
      }
}

// rowscale: rs[row] = rsqrt(mean(h1[row]^2) + eps). Replaces rms1 write.
__global__ __launch_bounds__(256) void rowscale_k(
    const unsigned short* __restrict__ in, float* __restrict__ rs) {
  long row = blockIdx.x;
  int tid = threadIdx.x;
  short4v u = *(const short4v*)(in + row * 1024 + tid * 4);
  float ss = 0.0f;
#pragma unroll
  for (int i = 0; i < 4; ++i) {
    float v = b2f((unsigned short)u[i]);
    ss += v * v;
  }
#pragma unroll
  for (int off = 32; off > 0; off >>= 1) ss += __shfl_xor(ss, off, 64);
  __shared__ float wsum[4];
  if ((tid & 63) == 0) wsum[tid >> 6] = ss;
  __syncthreads();
  if (tid == 0) {
    float tot = wsum[0] + wsum[1] + wsum[2] + wsum[3];
    rs[row] = rsqrtf(tot * (1.0f / 1024.0f) + 1e-6f);
  }
}

// rmsnorm over D=1024; one block per row. bf16 in; f32 out.
__global__ __launch_bounds__(256) void rmsnorm_k(
    const unsigned short* __restrict__ in, const float* __restrict__ g,
    float* __restrict__ outf) {
  long row = blockIdx.x;
  int tid = threadIdx.x;
  short4v u = *(const short4v*)(in + row * 1024 + tid * 4);
  float v[4];
  float ss = 0.0f;
#pragma unroll
  for (int i = 0; i < 4; ++i) {
    v[i] = b2f((unsigned short)u[i]);
    ss += v[i] * v[i];
  }
#pragma unroll
  for (int off = 32; off > 0; off >>= 1) ss += __shfl_xor(ss, off, 64);
  __shared__ float wsum[4];
  if ((tid & 63) == 0) wsum[tid >> 6] = ss;
  __syncthreads();
  float tot = wsum[0] + wsum[1] + wsum[2] + wsum[3];
  float rsv = rsqrtf(tot * (1.0f / 1024.0f) + 1e-6f);
  f32x4 gv = *(const f32x4*)(g + tid * 4);
  f32x4 ov;
#pragma unroll
  for (int i = 0; i < 4; ++i) ov[i] = v[i] * rsv * gv[i];
  *(f32x4*)(outf + row * 1024 + tid * 4) = ov;
}

// ---------------------------------------------------------------------------
extern "C" void kernel_launch(void* const* d_in, const int* in_sizes, int n_in,
                              void* d_out, int out_size, void* d_ws, size_t ws_size,
                              hipStream_t stream) {
  const float* x  = (const float*)d_in[0];
  const int* mask = (const int*)d_in[1];
  const float* Wq = (const float*)d_in[2];
  const float* bq = (const float*)d_in[3];
  const float* Wk = (const float*)d_in[4];
  const float* bk = (const float*)d_in[5];
  const float* Wv = (const float*)d_in[6];
  const float* bv = (const float*)d_in[7];
  const float* Wo = (const float*)d_in[8];
  const float* bo = (const float*)d_in[9];
  const float* W1 = (const float*)d_in[10];
  const float* b1 = (const float*)d_in[11];
  const float* W2 = (const float*)d_in[12];
  const float* b2 = (const float*)d_in[13];
  const float* g1 = (const float*)d_in[14];
  const float* g2 = (const float*)d_in[15];

  char* ws = (char*)d_ws;
  size_t off = 0;
  auto alc = [&](size_t n) { size_t o = off; off += (n + 255) & ~(size_t)255; return o; };
  unsigned short* BqkvT = (unsigned short*)(ws + alc(3072UL * 1024 * 2));
  unsigned short* WoT   = (unsigned short*)(ws + alc(1024UL * 1024 * 2));
  unsigned short* W1T   = (unsigned short*)(ws + alc(128UL * 1024 * 2));   // g1-folded
  unsigned short* W2T   = (unsigned short*)(ws + alc(1024UL * 128 * 2));
  float*          bqkv  = (float*)(ws + alc(3072UL * 4));
  unsigned short* R0    = (unsigned short*)(ws + alc(32768UL * 1024 * 2));  // xb -> hf
  unsigned short* R1    = (unsigned short*)(ws + alc(32768UL * 3072 * 2));  // QKV
  unsigned short* R2    = (unsigned short*)(ws + alc(32768UL * 1024 * 2));  // h1
  unsigned short* WPb   = (unsigned short*)(ws + alc(8UL * 1024 * 1024 * 2)); // WPT
  unsigned short* Tb    = (unsigned short*)(ws + alc(32768UL * 128 * 2));
  float*          SP    = (float*)(ws + alc(512UL * 4096 * 4));
  unsigned short* Wbuf  = (unsigned short*)(ws + alc(128UL * 4096 * 2));
  float*          RSb   = (float*)(ws + alc(32768UL * 4));
  if (ws_size < off) return;

  // Dataflow (C always disjoint from A/B/resid):
  //   prep:      -> xb(R0), weights
  //   QKV GEMM:  xb(R0) -> QKV(R1)
  //   scores:    QKV(R1) -> SP ; softmax: SP -> Wbuf ; wpt: -> WPT(WPb)
  //   V GEMM:    V(R1), WPT(WPb), resid xb(R0) -> h1(R2)
  //   rowscale:  h1(R2) -> rs
  //   FF1:       h1(R2), W1g -> t(Tb)   [tanh(rs*acc+b1)]
  //   FF2:       t(Tb), W2T, resid h1(R2)*rs*g1 -> hf(R0)  [xb dead]
  //   rms2:      hf(R0) -> out
  unsigned short* xb   = R0;
  unsigned short* HFb  = R0;
  unsigned short* QKVb = R1;
  unsigned short* H1b  = R2;
  float* outp = (float*)d_out;

  prep_kernel<<<17473, 256, 0, stream>>>(x, xb, Wq, Wk, Wv, Wo, W1, W2, bq, bk, bv, g1,
                                         BqkvT, WoT, W1T, W2T, bqkv);
  // QKV = xb @ [Wq|Wk|Wv]^T + b
  gemm8p<0, 0><<<1536, 512, 131072, stream>>>(xb, 1024, BqkvT, 1024, QKVb, 3072,
                                              bqkv, nullptr, nullptr, 0, nullptr, nullptr,
                                              1024, 12);
  scores_mfma<<<dim3(128, 4), 256, 0, stream>>>(QKVb, SP);
  softmax_Wb<<<128, 64, 0, stream>>>(SP, mask, Wbuf);
  wpt_kernel<<<dim3(4, 16, 8), 256, 0, stream>>>(WoT, Wbuf, WPb);
  // h1 = xb + V @ WPT_b + bo  (bf16 residual; C into R2, disjoint)
  gemm8p<3, 1><<<512, 512, 131072, stream>>>(QKVb + 2048, 3072, WPb, 1024, H1b, 1024,
                                             bo, nullptr, xb, 1024, nullptr, nullptr,
                                             1024, 4);
  rowscale_k<<<32768, 256, 0, stream>>>(H1b, RSb);
  // t = tanh(rs * (h1 @ W1g^T) + b1)
  gemm_bt<4><<<dim3(1, 256), 256, 0, stream>>>(H1b, 1024, W1T, 1024, Tb, 128, b1, RSb, 1024);
  // hf = t@W2T + b2 + h1*rs*g1
  gemm8p<5, 0><<<512, 512, 131072, stream>>>(Tb, 128, W2T, 128, HFb, 1024,
                                             b2, nullptr, H1b, 1024, RSb, g1,
                                             128, 4);
  rmsnorm_k<<<32768, 256, 0, stream>>>(HFb, g2, outp);
}

// Round 10
// 467.853 us; speedup vs baseline: 1.5371x; 1.0872x over previous
//
#include <hip/hip_runtime.h>
#include <math.h>

typedef __attribute__((ext_vector_type(4))) float f32x4;
typedef __attribute__((ext_vector_type(8))) short short8;   // 8 bf16 raw bits
typedef __attribute__((ext_vector_type(4))) short short4v;  // 4 bf16 raw bits

__device__ __forceinline__ float b2f(unsigned short u) {
  unsigned int x = ((unsigned int)u) << 16;
  return __builtin_bit_cast(float, x);
}
__device__ __forceinline__ unsigned short f2b(float f) {
  unsigned int x = __builtin_bit_cast(unsigned int, f);
  x += 0x7fffu + ((x >> 16) & 1u);   // round-to-nearest-even
  return (unsigned short)(x >> 16);
}

// async global->LDS, 16B per lane. LDS dest must be lane-contiguous (wave base + lane*16).
__device__ __forceinline__ void gload16(const unsigned short* g, unsigned short* l) {
  __builtin_amdgcn_global_load_lds(
      (__attribute__((address_space(1))) void*)(unsigned long long)(const void*)g,
      (__attribute__((address_space(3))) void*)l, 16, 0, 0);
}

#define BARR  { __builtin_amdgcn_sched_barrier(0); __builtin_amdgcn_s_barrier(); __builtin_amdgcn_sched_barrier(0); }
#define LBARR { __builtin_amdgcn_sched_barrier(0); asm volatile("s_waitcnt lgkmcnt(0)" ::: "memory"); __builtin_amdgcn_s_barrier(); __builtin_amdgcn_sched_barrier(0); }
// CROSS-WAVE RULE: vmcnt gate protecting a cooperatively-staged LDS buffer sits
// BEFORE the barrier preceding the reads. BUFFER RULE: a GEMM's C region must
// be disjoint from its A, B, and residual regions.
#define VMW(n) { __builtin_amdgcn_sched_barrier(0); asm volatile("s_waitcnt vmcnt(" #n ")" ::: "memory"); __builtin_amdgcn_sched_barrier(0); }

// ---------------------------------------------------------------------------
// prep_kernel: x->bf16 + weight repacks + bias concat.
// Grid: [0,16384) cvt x ; then 1089 weight blocks:
//   [0,512) Wq/Wk -> BqkT (transpose) ; [512,768) Wo -> WoT ; [768,800) W1*g1
//   [800,832) W2 ; [832,1088) Wv -> WvR[d][h*64+e] (copy) ; 1088: bias concat.
// ---------------------------------------------------------------------------
__global__ __launch_bounds__(256) void prep_kernel(
    const float* __restrict__ x, unsigned short* __restrict__ xb,
    const float* __restrict__ Wq, const float* __restrict__ Wk,
    const float* __restrict__ Wv, const float* __restrict__ Wo,
    const float* __restrict__ W1, const float* __restrict__ W2,
    const float* __restrict__ bq, const float* __restrict__ bk, const float* __restrict__ bv,
    const float* __restrict__ g1,
    unsigned short* __restrict__ BqkT, unsigned short* __restrict__ WoT,
    unsigned short* __restrict__ W1T, unsigned short* __restrict__ W2T,
    unsigned short* __restrict__ WvR,
    float* __restrict__ bqkv) {
  __shared__ float tile[64][65];
  int nb = blockIdx.x, t = threadIdx.x;
  if (nb < 16384) {
    long i = (long)nb * 256 + t;
    f32x4 a = ((const f32x4*)x)[i * 2];
    f32x4 b = ((const f32x4*)x)[i * 2 + 1];
    short8 o;
#pragma unroll
    for (int j = 0; j < 4; ++j) { o[j] = (short)f2b(a[j]); o[4 + j] = (short)f2b(b[j]); }
    ((short8*)xb)[i] = o;
    return;
  }
  int n0 = nb - 16384;
  if (n0 == 1088) {
#pragma unroll
    for (int it = 0; it < 12; ++it) {
      int idx = it * 256 + t;
      float v = (idx < 1024) ? bq[idx] : (idx < 2048 ? bk[idx - 1024] : bv[idx - 2048]);
      bqkv[idx] = v;
    }
    return;
  }
  if (n0 >= 832) {                        // WvR[d][h*64+e] = Wv[h][d][e] (copy+cvt)
    int rem = n0 - 832, h = rem >> 4, dc = rem & 15;
    int r = t >> 2, c0 = (t & 3) * 16;
    const float* s = Wv + ((long)h * 1024 + dc * 64 + r) * 64 + c0;
    unsigned short* d = WvR + (long)(dc * 64 + r) * 1024 + h * 64 + c0;
#pragma unroll
    for (int j4 = 0; j4 < 4; ++j4) {
      f32x4 v = *(const f32x4*)(s + j4 * 4);
      short4v o;
#pragma unroll
      for (int j = 0; j < 4; ++j) o[j] = (short)f2b(v[j]);
      *(short4v*)(d + j4 * 4) = o;
    }
    return;
  }
  const float* src; unsigned short* dst; int sld, dld;
  bool foldg = false; int dbase = 0;
  if (n0 < 512) {                         // Wq/Wk -> BqkT rows [w*1024 + h*64 + e]
    int w = n0 >> 8, rem = n0 & 255, h = rem >> 4, dc = rem & 15;
    const float* W = (w == 0) ? Wq : Wk;
    src = W + ((long)h * 1024 + dc * 64) * 64;                 sld = 64;
    dst = BqkT + (long)(w * 1024 + h * 64) * 1024 + dc * 64;   dld = 1024;
  } else if (n0 < 768) {
    int rem = n0 - 512, dr = rem >> 4, jc = rem & 15;
    src = Wo + (long)dr * 64 * 1024 + jc * 64;                 sld = 1024;
    dst = WoT + (long)jc * 64 * 1024 + dr * 64;                dld = 1024;
  } else if (n0 < 800) {
    int rem = n0 - 768, dr = rem >> 1, fc = rem & 1;
    src = W1 + (long)dr * 64 * 128 + fc * 64;                  sld = 128;
    dst = W1T + (long)fc * 64 * 1024 + dr * 64;                dld = 1024;
    foldg = true; dbase = dr * 64;
  } else {
    int rem = n0 - 800, fr = rem >> 4, jc = rem & 15;
    src = W2 + (long)fr * 64 * 1024 + jc * 64;                 sld = 1024;
    dst = W2T + (long)jc * 64 * 128 + fr * 64;                 dld = 128;
  }
  int r = t >> 2, c0 = (t & 3) * 16;
#pragma unroll
  for (int j4 = 0; j4 < 4; ++j4) {
    f32x4 v = *(const f32x4*)(src + (long)r * sld + c0 + j4 * 4);
    tile[c0 + j4 * 4 + 0][r] = v[0];
    tile[c0 + j4 * 4 + 1][r] = v[1];
    tile[c0 + j4 * 4 + 2][r] = v[2];
    tile[c0 + j4 * 4 + 3][r] = v[3];
  }
  __syncthreads();
  short8 o0, o1;
#pragma unroll
  for (int j = 0; j < 8; ++j) {
    float v0 = tile[r][c0 + j], v1 = tile[r][c0 + 8 + j];
    if (foldg) { v0 *= g1[dbase + c0 + j]; v1 *= g1[dbase + c0 + 8 + j]; }
    o0[j] = (short)f2b(v0);
    o1[j] = (short)f2b(v1);
  }
  *(short8*)(dst + (long)r * dld + c0) = o0;
  *(short8*)(dst + (long)r * dld + c0 + 8) = o1;
}

// ---------------------------------------------------------------------------
// 256x256 bf16 GEMM v2.3: verified v2.2 schedule; generalized grid mapping
// (mpx = gridDim.x/(8*NBX) m-blocks per XCD; requires mpx%4==0 or mpx<=4).
// EPI: 0 = +bias ; 3 = +bias + bf16 resid ; 5 = +bias + h1*rs*g1 resid ;
//      6 = no bias. BSEL: per-batch B (+(m0>>12)*1M). BBIAS: per-batch bias.
// ---------------------------------------------------------------------------
__device__ __forceinline__ void rdA2(short8 (&dst)[4][2], const char* paK0,
                                     const char* paK1, int off) {
#pragma unroll
  for (int fr = 0; fr < 4; ++fr) {
    dst[fr][0] = *(const short8*)(paK0 + off + fr * 2048);
    dst[fr][1] = *(const short8*)(paK1 + off + fr * 2048);
  }
}
__device__ __forceinline__ void rdB2(short8 (&dst)[2][2], const char* pbK0,
                                     const char* pbK1, int off) {
#pragma unroll
  for (int gr = 0; gr < 2; ++gr) {
    dst[gr][0] = *(const short8*)(pbK0 + off + gr * 2048);
    dst[gr][1] = *(const short8*)(pbK1 + off + gr * 2048);
  }
}
template <int BPH>
__device__ __forceinline__ void mfmaq_f(const short8 (&afr)[4][2], const short8 (&bf)[2][2],
                                        f32x4 (*ac)[4]) {
  __builtin_amdgcn_s_setprio(1);
#pragma unroll
  for (int fi = 0; fi < 4; ++fi)
#pragma unroll
    for (int gj = 0; gj < 2; ++gj)
#pragma unroll
      for (int ks = 0; ks < 2; ++ks)
        ac[fi][BPH * 2 + gj] = __builtin_amdgcn_mfma_f32_16x16x32_bf16(
            afr[fi][ks], bf[gj][ks], ac[fi][BPH * 2 + gj], 0, 0, 0);
  __builtin_amdgcn_s_setprio(0);
}

template <int EPI, int BSEL, int BBIAS>
__global__ __launch_bounds__(512, 2) void gemm8p(
    const unsigned short* __restrict__ A, int lda,
    const unsigned short* __restrict__ Bt, int ldb,
    unsigned short* __restrict__ C, int ldc,
    const float* __restrict__ bias,
    const unsigned short* __restrict__ residb, int ldr,
    const float* __restrict__ rs, const float* __restrict__ g1f,
    int K, int NBX) {
  extern __shared__ char smb[];
  const int tid = threadIdx.x;
  const int lane = tid & 63, wid = tid >> 6;
  const int wm = wid >> 2, wn = wid & 3;

  // XCD chunking with generalized M: mpx m-blocks per XCD, inner 4xNBX tile.
  int orig = blockIdx.x;
  int xcd = orig & 7, j = orig >> 3;
  int perx = gridDim.x >> 3;
  int mpx = perx / NBX;
  int ms = j / (4 * NBX), nb = (j >> 2) % NBX, mq = j & 3;
  const long m0 = (long)(xcd * mpx + ms * 4 + mq) * 256;
  const long n0 = (long)nb * 256;
  const unsigned short* bt = BSEL ? (Bt + (m0 >> 12) * 1048576) : Bt;
  const float* biasp = BBIAS ? (bias + (m0 >> 12) * 1024) : bias;

  const int NT = K >> 6, NI = NT >> 1;   // NT even for all our shapes

  const int lr = lane & 15, lc = (lane >> 4) * 16;
  const int eA = lc ^ ((lr & 7) << 4);
  const char* paK0 = smb + wm * 8192 + lr * 128 + eA;
  const char* paK1 = smb + wm * 8192 + lr * 128 + (eA ^ 64);
  const char* pbK0 = smb + 65536 + wn * 4096 + lr * 128 + eA;
  const char* pbK1 = smb + 65536 + wn * 4096 + lr * 128 + (eA ^ 64);

  short8 afr0[4][2], afr1[4][2];
  short8 bfr0[2][2], bfr1[2][2];
  f32x4 acc[8][4] = {};

  auto stA = [&](int buf, int ph, int kt) {
#pragma unroll
    for (int rnd = 0; rnd < 2; ++rnd) {
      int o = rnd * 8192 + tid * 16;
      int wms = o >> 13, rsw = (o >> 7) & 63, cb = o & 127;
      int pcb = cb ^ ((rsw & 7) << 4);
      const unsigned short* src = A + (m0 + wms * 128 + ph * 64 + rsw) * (long)lda + kt * 64 + (pcb >> 1);
      gload16(src, (unsigned short*)(smb + buf * 32768 + ph * 16384 + o));
    }
  };
  auto stB = [&](int buf, int ph, int kt) {
#pragma unroll
    for (int rnd = 0; rnd < 2; ++rnd) {
      int o = rnd * 8192 + tid * 16;
      int wns = (o >> 12) & 3, rsw = (o >> 7) & 31, cb = o & 127;
      int pcb = cb ^ ((rsw & 7) << 4);
      const unsigned short* src = bt + (n0 + wns * 64 + ph * 32 + rsw) * (long)ldb + kt * 64 + (pcb >> 1);
      gload16(src, (unsigned short*)(smb + 65536 + buf * 32768 + ph * 16384 + o));
    }
  };

  stA(0, 0, 0); stA(0, 1, 0); stB(0, 0, 0); stB(0, 1, 0);
  stA(1, 0, 1); stA(1, 1, 1); stB(1, 0, 1); stB(1, 1, 1);
  VMW(8);
  BARR;
  rdA2(afr0, paK0, paK1, 0);
  rdB2(bfr0, pbK0, pbK1, 0);

  for (int i = 0; i < NI; ++i) {
    int t2 = 2 * i + 2, t3 = 2 * i + 3;
    bool more = t2 < NT;
    // ---- tile 2i (buf0) ----
    LBARR;
    rdB2(bfr1, pbK0, pbK1, 16384);
    mfmaq_f<0>(afr0, bfr0, &acc[0]);
    LBARR;
    rdA2(afr1, paK0, paK1, 16384);
    mfmaq_f<1>(afr0, bfr1, &acc[0]);
    LBARR;
    if (more) { stA(0, 0, t2); stA(0, 1, t2); }
    mfmaq_f<0>(afr1, bfr0, &acc[4]);
    if (more) { VMW(4); } else { VMW(0); }
    LBARR;
    rdA2(afr0, paK0, paK1, 32768);
    rdB2(bfr0, pbK0, pbK1, 32768);
    if (more) { stB(0, 0, t2); stB(0, 1, t2); }
    mfmaq_f<1>(afr1, bfr1, &acc[4]);
    // ---- tile 2i+1 (buf1) ----
    LBARR;
    rdB2(bfr1, pbK0, pbK1, 32768 + 16384);
    mfmaq_f<0>(afr0, bfr0, &acc[0]);
    LBARR;
    rdA2(afr1, paK0, paK1, 32768 + 16384);
    mfmaq_f<1>(afr0, bfr1, &acc[0]);
    LBARR;
    if (more) { stA(1, 0, t3); stA(1, 1, t3); }
    mfmaq_f<0>(afr1, bfr0, &acc[4]);
    if (more) { VMW(4); } else { VMW(0); }
    LBARR;
    if (more) { rdA2(afr0, paK0, paK1, 0); rdB2(bfr0, pbK0, pbK1, 0); }
    if (more) { stB(1, 0, t3); stB(1, 1, t3); }
    mfmaq_f<1>(afr1, bfr1, &acc[4]);
  }

#pragma unroll
  for (int f = 0; f < 8; ++f) {
#pragma unroll
    for (int g = 0; g < 4; ++g) {
      long col = n0 + wn * 64 + g * 16 + (lane & 15);
      float bv = (EPI == 6) ? 0.0f : biasp[col];
      float gv = (EPI == 5) ? g1f[col] : 0.0f;
#pragma unroll
      for (int r = 0; r < 4; ++r) {
        long row = m0 + wm * 128 + f * 16 + (lane >> 4) * 4 + r;
        float o = acc[f][g][r] + bv;
        if (EPI == 3) o += b2f(residb[row * (long)ldr + col]);
        if (EPI == 5) o += b2f(residb[row * (long)ldr + col]) * rs[row] * gv;
        C[row * (long)ldc + col] = f2b(o);
      }
    }
  }
}

// ---------------------------------------------------------------------------
// m97-structure GEMM for FF1 (N=128). EPI 4: o = tanh(rs[row]*acc + bias).
// ---------------------------------------------------------------------------
template <int EPI>
__global__ __launch_bounds__(256, 2) void gemm_bt(
    const unsigned short* __restrict__ A, int lda,
    const unsigned short* __restrict__ Bt, int ldb,
    unsigned short* __restrict__ C, int ldc,
    const float* __restrict__ bias, const float* __restrict__ rs, int K) {
  __shared__ __align__(16) unsigned short Asm[128 * 32];
  __shared__ __align__(16) unsigned short Bsm[128 * 32];
  const int tid = threadIdx.x;
  const int lane = tid & 63, wid = tid >> 6;
  const int wr = wid >> 1, wc = wid & 1;
  const long m0 = (long)blockIdx.y * 128;
  const long n0 = (long)blockIdx.x * 128;

  f32x4 acc[4][4] = {};

  for (int kk = 0; kk < K; kk += 32) {
    __syncthreads();
#pragma unroll
    for (int i = 0; i < 2; ++i) {
      int slot = i * 256 + tid;
      int r = slot >> 2, cg = (slot & 3) * 8;
      gload16(A + (m0 + r) * (long)lda + kk + cg, &Asm[slot * 8]);
      gload16(Bt + (n0 + r) * (long)ldb + kk + cg, &Bsm[slot * 8]);
    }
    __syncthreads();
    short8 af[4], bfr[4];
#pragma unroll
    for (int mt = 0; mt < 4; ++mt)
      af[mt] = *(const short8*)&Asm[(wr * 64 + mt * 16 + (lane & 15)) * 32 + (lane >> 4) * 8];
#pragma unroll
    for (int nt = 0; nt < 4; ++nt)
      bfr[nt] = *(const short8*)&Bsm[(wc * 64 + nt * 16 + (lane & 15)) * 32 + (lane >> 4) * 8];
#pragma unroll
    for (int mt = 0; mt < 4; ++mt)
#pragma unroll
      for (int nt = 0; nt < 4; ++nt)
        acc[mt][nt] = __builtin_amdgcn_mfma_f32_16x16x32_bf16(af[mt], bfr[nt], acc[mt][nt], 0, 0, 0);
  }

  const long row0 = m0 + wr * 64 + ((lane >> 4) * 4);
  const long col0 = n0 + wc * 64 + (lane & 15);
#pragma unroll
  for (int mt = 0; mt < 4; ++mt) {
#pragma unroll
    for (int nt = 0; nt < 4; ++nt) {
      long col = col0 + nt * 16;
      float bv = bias[col];
      f32x4 v = acc[mt][nt];
#pragma unroll
      for (int r = 0; r < 4; ++r) {
        long row = row0 + mt * 16 + r;
        float o = v[r];
        if (EPI == 4) o = tanhf(o * rs[row] + bv);
        else o += bv;
        C[row * (long)ldc + col] = f2b(o);
      }
    }
  }
}

// ---------------------------------------------------------------------------
// scores via MFMA (verified rounds 5-9); QK buffer stride 2048.
// ---------------------------------------------------------------------------
__device__ __forceinline__ int sperm(int e) { return ((e + (e >> 3)) & 7) << 4; }

__global__ __launch_bounds__(256) void scores_mfma(
    const unsigned short* __restrict__ QK, float* __restrict__ part) {
  __shared__ __align__(16) char lds[32768];
  int bh = blockIdx.x, seg = blockIdx.y;
  int b = bh >> 4, h = bh & 15;
  int tid = threadIdx.x, lane = tid & 63, wid = tid >> 6;
  int e0 = (tid & 7) * 8;
  int sl0 = (tid >> 3) * 4;
  const unsigned short* Qg = QK + h * 64;
  const unsigned short* Kg = QK + 1024 + h * 64;
  f32x4 acc[4] = {};

  for (int ch = 0; ch < 8; ++ch) {
    long S0 = (long)b * 4096 + seg * 1024 + ch * 128;
    __syncthreads();
    short8 kv0 = *(const short8*)(Kg + (S0 + sl0 + 0) * 2048 + e0);
    short8 kv1 = *(const short8*)(Kg + (S0 + sl0 + 1) * 2048 + e0);
    short8 kv2 = *(const short8*)(Kg + (S0 + sl0 + 2) * 2048 + e0);
    short8 kv3 = *(const short8*)(Kg + (S0 + sl0 + 3) * 2048 + e0);
    short8 qv0 = *(const short8*)(Qg + (S0 + sl0 + 0) * 2048 + e0);
    short8 qv1 = *(const short8*)(Qg + (S0 + sl0 + 1) * 2048 + e0);
    short8 qv2 = *(const short8*)(Qg + (S0 + sl0 + 2) * 2048 + e0);
    short8 qv3 = *(const short8*)(Qg + (S0 + sl0 + 3) * 2048 + e0);
#pragma unroll
    for (int je = 0; je < 8; ++je) {
      int e = e0 + je;
      int sw = sperm(e);
      char* rowK = lds + e * 256;
      char* rowQ = lds + 16384 + e * 256;
      unsigned int klo = (unsigned short)kv0[je] | ((unsigned int)(unsigned short)kv1[je] << 16);
      unsigned int khi = (unsigned short)kv2[je] | ((unsigned int)(unsigned short)kv3[je] << 16);
      unsigned int qlo = (unsigned short)qv0[je] | ((unsigned int)(unsigned short)qv1[je] << 16);
      unsigned int qhi = (unsigned short)qv2[je] | ((unsigned int)(unsigned short)qv3[je] << 16);
      *(unsigned int*)(rowK + ((sl0 * 2) ^ sw)) = klo;
      *(unsigned int*)(rowK + ((sl0 * 2 + 4) ^ sw)) = khi;
      *(unsigned int*)(rowQ + ((sl0 * 2) ^ sw)) = qlo;
      *(unsigned int*)(rowQ + ((sl0 * 2 + 4) ^ sw)) = qhi;
    }
    __syncthreads();
#pragma unroll
    for (int ksi = 0; ksi < 4; ++ksi) {
      int colb = ksi * 64 + (lane >> 4) * 16;
      int erA = wid * 16 + (lane & 15);
      short8 af = *(const short8*)(lds + erA * 256 + (colb ^ sperm(erA)));
#pragma unroll
      for (int n = 0; n < 4; ++n) {
        int erB = n * 16 + (lane & 15);
        short8 bf = *(const short8*)(lds + 16384 + erB * 256 + (colb ^ sperm(erB)));
        acc[n] = __builtin_amdgcn_mfma_f32_16x16x32_bf16(af, bf, acc[n], 0, 0, 0);
      }
    }
  }
  float* dst = part + ((long)bh * 4 + seg) * 4096;
#pragma unroll
  for (int n = 0; n < 4; ++n)
#pragma unroll
    for (int r = 0; r < 4; ++r) {
      int k = wid * 16 + (lane >> 4) * 4 + r;
      int q = n * 16 + (lane & 15);
      dst[k * 64 + q] = acc[n][r];
    }
}

// softmax over k (per q column), scores/8; writes w row-major: Wb[bh][k][q]
__global__ __launch_bounds__(64) void softmax_Wb(
    const float* __restrict__ part, const int* __restrict__ mask,
    unsigned short* __restrict__ Wb) {
  __shared__ float lt[64][65];
  int bh = blockIdx.x, q = threadIdx.x;
  int b = bh >> 4;
  const float* p0 = part + (long)bh * 4 * 4096;
  float s[64];
#pragma unroll
  for (int k = 0; k < 64; ++k)
    s[k] = p0[k * 64 + q] + p0[4096 + k * 64 + q] + p0[8192 + k * 64 + q] + p0[12288 + k * 64 + q];
  bool live = (mask[b * 64 + q] != 0);
  float m = -1e30f;
#pragma unroll
  for (int k = 0; k < 64; ++k) m = fmaxf(m, s[k]);
  float sum = 0.0f;
#pragma unroll
  for (int k = 0; k < 64; ++k) {
    s[k] = __expf((s[k] - m) * 0.125f);
    sum += s[k];
  }
  float inv = live ? 1.0f / sum : 0.0f;
#pragma unroll
  for (int k = 0; k < 64; ++k) lt[k][q] = s[k] * inv;
  __syncthreads();
  unsigned short* o = Wb + (long)bh * 4096 + q * 64;
#pragma unroll
  for (int j8 = 0; j8 < 8; ++j8) {
    short8 ov;
#pragma unroll
    for (int j = 0; j < 8; ++j) ov[j] = (short)f2b(lt[q][j8 * 8 + j]);
    *(short8*)(o + j8 * 8) = ov;
  }
}

// WPT[b][d][h*64+k] = sum_q Wo[h*64+q][d] * w_bh[k][q]
__global__ __launch_bounds__(256) void wpt_kernel(
    const unsigned short* __restrict__ WoT, const unsigned short* __restrict__ Wb,
    unsigned short* __restrict__ WPT) {
  int dblk = blockIdx.x;   // 4
  int h = blockIdx.y;      // 16
  int b = blockIdx.z;      // 8
  int tid = threadIdx.x, lane = tid & 63, wid = tid >> 6;
  int d0 = dblk * 256 + wid * 64;
  const unsigned short* wb = Wb + (long)(b * 16 + h) * 4096;
  f32x4 acc[4][4] = {};
#pragma unroll
  for (int ks = 0; ks < 2; ++ks) {
    short8 bf[4];
#pragma unroll
    for (int nt = 0; nt < 4; ++nt)
      bf[nt] = *(const short8*)(wb + (nt * 16 + (lane & 15)) * 64 + ks * 32 + (lane >> 4) * 8);
#pragma unroll
    for (int mt = 0; mt < 4; ++mt) {
      short8 af = *(const short8*)(WoT + (long)(d0 + mt * 16 + (lane & 15)) * 1024 + h * 64 + ks * 32 + (lane >> 4) * 8);
#pragma unroll
      for (int nt = 0; nt < 4; ++nt)
        acc[mt][nt] = __builtin_amdgcn_mfma_f32_16x16x32_bf16(af, bf[nt], acc[mt][nt], 0, 0, 0);
    }
  }
#pragma unroll
  for (int mt = 0; mt < 4; ++mt)
#pragma unroll
    for (int nt = 0; nt < 4; ++nt)
#pragma unroll
      for (int r = 0; r < 4; ++r) {
        long row = d0 + mt * 16 + (lane >> 4) * 4 + r;
        int col = h * 64 + nt * 16 + (lane & 15);
        WPT[(long)b * 1048576 + row * 1024 + col] = f2b(acc[mt][nt][r]);
      }
}

// hb[b][d'] = bo[d'] + sum_col WPT_b[d'][col] * bv[col]
__global__ __launch_bounds__(256) void bvdot_kernel(
    const unsigned short* __restrict__ WPT, const float* __restrict__ bv,
    const float* __restrict__ bo, float* __restrict__ hb) {
  int b = blockIdx.y;
  int dp = blockIdx.x * 256 + threadIdx.x;
  const unsigned short* row = WPT + (long)b * 1048576 + (long)dp * 1024;
  float acc = 0.0f;
#pragma unroll 4
  for (int c = 0; c < 1024; c += 8) {
    short8 v = *(const short8*)(row + c);
#pragma unroll
    for (int j = 0; j < 8; ++j) acc += b2f((unsigned short)v[j]) * bv[c + j];
  }
  hb[b * 1024 + dp] = bo[dp] + acc;
}

// rowscale: rs[row] = rsqrt(mean(h1[row]^2) + eps).
__global__ __launch_bounds__(256) void rowscale_k(
    const unsigned short* __restrict__ in, float* __restrict__ rs) {
  long row = blockIdx.x;
  int tid = threadIdx.x;
  short4v u = *(const short4v*)(in + row * 1024 + tid * 4);
  float ss = 0.0f;
#pragma unroll
  for (int i = 0; i < 4; ++i) {
    float v = b2f((unsigned short)u[i]);
    ss += v * v;
  }
#pragma unroll
  for (int off = 32; off > 0; off >>= 1) ss += __shfl_xor(ss, off, 64);
  __shared__ float wsum[4];
  if ((tid & 63) == 0) wsum[tid >> 6] = ss;
  __syncthreads();
  if (tid == 0) {
    float tot = wsum[0] + wsum[1] + wsum[2] + wsum[3];
    rs[row] = rsqrtf(tot * (1.0f / 1024.0f) + 1e-6f);
  }
}

// rmsnorm over D=1024; one block per row. bf16 in; f32 out.
__global__ __launch_bounds__(256) void rmsnorm_k(
    const unsigned short* __restrict__ in, const float* __restrict__ g,
    float* __restrict__ outf) {
  long row = blockIdx.x;
  int tid = threadIdx.x;
  short4v u = *(const short4v*)(in + row * 1024 + tid * 4);
  float v[4];
  float ss = 0.0f;
#pragma unroll
  for (int i = 0; i < 4; ++i) {
    v[i] = b2f((unsigned short)u[i]);
    ss += v[i] * v[i];
  }
#pragma unroll
  for (int off = 32; off > 0; off >>= 1) ss += __shfl_xor(ss, off, 64);
  __shared__ float wsum[4];
  if ((tid & 63) == 0) wsum[tid >> 6] = ss;
  __syncthreads();
  float tot = wsum[0] + wsum[1] + wsum[2] + wsum[3];
  float rsv = rsqrtf(tot * (1.0f / 1024.0f) + 1e-6f);
  f32x4 gv = *(const f32x4*)(g + tid * 4);
  f32x4 ov;
#pragma unroll
  for (int i = 0; i < 4; ++i) ov[i] = v[i] * rsv * gv[i];
  *(f32x4*)(outf + row * 1024 + tid * 4) = ov;
}

// ---------------------------------------------------------------------------
extern "C" void kernel_launch(void* const* d_in, const int* in_sizes, int n_in,
                              void* d_out, int out_size, void* d_ws, size_t ws_size,
                              hipStream_t stream) {
  const float* x  = (const float*)d_in[0];
  const int* mask = (const int*)d_in[1];
  const float* Wq = (const float*)d_in[2];
  const float* bq = (const float*)d_in[3];
  const float* Wk = (const float*)d_in[4];
  const float* bk = (const float*)d_in[5];
  const float* Wv = (const float*)d_in[6];
  const float* bv = (const float*)d_in[7];
  const float* Wo = (const float*)d_in[8];
  const float* bo = (const float*)d_in[9];
  const float* W1 = (const float*)d_in[10];
  const float* b1 = (const float*)d_in[11];
  const float* W2 = (const float*)d_in[12];
  const float* b2 = (const float*)d_in[13];
  const float* g1 = (const float*)d_in[14];
  const float* g2 = (const float*)d_in[15];

  char* ws = (char*)d_ws;
  size_t off = 0;
  auto alc = [&](size_t n) { size_t o = off; off += (n + 255) & ~(size_t)255; return o; };
  unsigned short* BqkT  = (unsigned short*)(ws + alc(2048UL * 1024 * 2));
  unsigned short* WoT   = (unsigned short*)(ws + alc(1024UL * 1024 * 2));
  unsigned short* W1T   = (unsigned short*)(ws + alc(128UL * 1024 * 2));    // g1-folded
  unsigned short* W2T   = (unsigned short*)(ws + alc(1024UL * 128 * 2));
  unsigned short* WvR   = (unsigned short*)(ws + alc(1024UL * 1024 * 2));
  float*          bqkv  = (float*)(ws + alc(3072UL * 4));
  float*          HBb   = (float*)(ws + alc(8192UL * 4));
  unsigned short* R0    = (unsigned short*)(ws + alc(32768UL * 1024 * 2));  // xb -> hf
  unsigned short* R1    = (unsigned short*)(ws + alc(32768UL * 2048 * 2));  // QK
  unsigned short* R2    = (unsigned short*)(ws + alc(32768UL * 1024 * 2));  // h1
  unsigned short* WPb   = (unsigned short*)(ws + alc(8UL * 1048576 * 2));   // WPT
  unsigned short* WVPb  = (unsigned short*)(ws + alc(8UL * 1048576 * 2));   // WVP
  unsigned short* Tb    = (unsigned short*)(ws + alc(32768UL * 128 * 2));
  float*          SP    = (float*)(ws + alc(512UL * 4096 * 4));
  unsigned short* Wbuf  = (unsigned short*)(ws + alc(128UL * 4096 * 2));
  float*          RSb   = (float*)(ws + alc(32768UL * 4));
  if (ws_size < off) return;

  // Dataflow (C always disjoint from A/B/resid):
  //   prep:   x -> xb(R0); weights -> BqkT/WoT/W1T/W2T/WvR; bqkv
  //   QK:     xb(R0) @ BqkT -> QK(R1)           [EPI0]
  //   scores: QK(R1) -> SP ; softmax -> Wbuf ; wpt -> WPT(WPb)
  //   WVP:    WPT(WPb) @ WvR -> WVP(WVPb)       [EPI6, M=8192]
  //   bvdot:  WPT, bv, bo -> hb(HBb)
  //   h1:     xb(R0) @ WVP_b + hb_b + xb -> h1(R2)  [EPI3+BSEL+BBIAS]
  //   rowscale: h1(R2) -> rs
  //   FF1:    h1(R2) @ W1g, tanh(rs*acc+b1) -> t(Tb)
  //   FF2:    t(Tb) @ W2T + b2 + h1*rs*g1 -> hf(R0)  [xb dead]
  //   rms2:   hf(R0) -> out
  unsigned short* xb   = R0;
  unsigned short* HFb  = R0;
  unsigned short* QKb  = R1;
  unsigned short* H1b  = R2;
  float* outp = (float*)d_out;

  prep_kernel<<<17473, 256, 0, stream>>>(x, xb, Wq, Wk, Wv, Wo, W1, W2, bq, bk, bv, g1,
                                         BqkT, WoT, W1T, W2T, WvR, bqkv);
  // QK = xb @ [Wq|Wk]^T + b  (N=2048; grid 128x8 = 1024)
  gemm8p<0, 0, 0><<<1024, 512, 131072, stream>>>(xb, 1024, BqkT, 1024, QKb, 2048,
                                                 bqkv, nullptr, 0, nullptr, nullptr,
                                                 1024, 8);
  scores_mfma<<<dim3(128, 4), 256, 0, stream>>>(QKb, SP);
  softmax_Wb<<<128, 64, 0, stream>>>(SP, mask, Wbuf);
  wpt_kernel<<<dim3(4, 16, 8), 256, 0, stream>>>(WoT, Wbuf, WPb);
  // WVP_b = WPT_b @ WvR^T  (M=8192; grid 32x4 = 128)
  gemm8p<6, 0, 0><<<128, 512, 131072, stream>>>(WPb, 1024, WvR, 1024, WVPb, 1024,
                                                nullptr, nullptr, 0, nullptr, nullptr,
                                                1024, 4);
  bvdot_kernel<<<dim3(4, 8), 256, 0, stream>>>(WPb, bqkv + 2048, bo, HBb);
  // h1 = xb + xb @ WVP_b^T + hb_b  (grid 128x4 = 512)
  gemm8p<3, 1, 1><<<512, 512, 131072, stream>>>(xb, 1024, WVPb, 1024, H1b, 1024,
                                                HBb, xb, 1024, nullptr, nullptr,
                                                1024, 4);
  rowscale_k<<<32768, 256, 0, stream>>>(H1b, RSb);
  // t = tanh(rs * (h1 @ W1g^T) + b1)
  gemm_bt<4><<<dim3(1, 256), 256, 0, stream>>>(H1b, 1024, W1T, 1024, Tb, 128, b1, RSb, 1024);
  // hf = t@W2T + b2 + h1*rs*g1
  gemm8p<5, 0, 0><<<512, 512, 131072, stream>>>(Tb, 128, W2T, 128, HFb, 1024,
                                                b2, H1b, 1024, RSb, g1,
                                                128, 4);
  rmsnorm_k<<<32768, 256, 0, stream>>>(HFb, g2, outp);
}